// Round 3
// baseline (660.746 us; speedup 1.0000x reference)
//
#include <hip/hip_runtime.h>

#define NNODE 2048
#define NBATCH 32

typedef __attribute__((ext_vector_type(4))) float f32x4;
typedef __attribute__((ext_vector_type(8))) __bf16 bf16x8;

__device__ __forceinline__ void gload16(const void* g, void* lds) {
  __builtin_amdgcn_global_load_lds(
      (const __attribute__((address_space(1))) unsigned int*)g,
      (__attribute__((address_space(3))) unsigned int*)lds, 16, 0, 0);
}

// ---------------------------------------------------------------------------
// Convert f32 -> bf16 (4 elems/thread, exact grid)
__global__ __launch_bounds__(256) void conv_bf16(const float* __restrict__ in,
                                                 __bf16* __restrict__ outp) {
  int i = blockIdx.x * 256 + threadIdx.x;
  float4 q = ((const float4*)in)[i];
  outp[4 * (size_t)i + 0] = (__bf16)q.x;
  outp[4 * (size_t)i + 1] = (__bf16)q.y;
  outp[4 * (size_t)i + 2] = (__bf16)q.z;
  outp[4 * (size_t)i + 3] = (__bf16)q.w;
}

// ---------------------------------------------------------------------------
// Repack E1,E2 [N,H,16] f32 -> [H][N][32] bf16 (K zero-padded 16->32)
__global__ __launch_bounds__(256) void prep_e(const float* __restrict__ E1,
                                              const float* __restrict__ E2,
                                              __bf16* __restrict__ E1p,
                                              __bf16* __restrict__ E2p) {
  int idx = blockIdx.x * 256 + threadIdx.x;  // 0..32767
  int cq = idx & 3;
  int n = (idx >> 2) & 2047;
  int h = idx >> 13;
  const float4 q1 = *(const float4*)(E1 + (size_t)(n * 4 + h) * 16 + cq * 4);
  const float4 q2 = *(const float4*)(E2 + (size_t)(n * 4 + h) * 16 + cq * 4);
  size_t o = ((size_t)h * NNODE + n) * 32 + cq * 4;
  E1p[o + 0] = (__bf16)q1.x; E1p[o + 1] = (__bf16)q1.y;
  E1p[o + 2] = (__bf16)q1.z; E1p[o + 3] = (__bf16)q1.w;
  E2p[o + 0] = (__bf16)q2.x; E2p[o + 1] = (__bf16)q2.y;
  E2p[o + 2] = (__bf16)q2.z; E2p[o + 3] = (__bf16)q2.w;
  size_t oz = o + 16;
  E1p[oz + 0] = (__bf16)0.f; E1p[oz + 1] = (__bf16)0.f;
  E1p[oz + 2] = (__bf16)0.f; E1p[oz + 3] = (__bf16)0.f;
  E2p[oz + 0] = (__bf16)0.f; E2p[oz + 1] = (__bf16)0.f;
  E2p[oz + 2] = (__bf16)0.f; E2p[oz + 3] = (__bf16)0.f;
}

// ---------------------------------------------------------------------------
// SC[h][w][v] = relu(E1p_h @ E2p_h^T)/4, bf16. Single K=32 MFMA step.
__global__ __launch_bounds__(256) void score_gemm(const __bf16* __restrict__ E1p,
                                                  const __bf16* __restrict__ E2p,
                                                  __bf16* __restrict__ SC) {
  __shared__ __bf16 As[128 * 32];
  __shared__ __bf16 Bs[128 * 32];
  const int tid = threadIdx.x;
  const int wave = tid >> 6, lane = tid & 63;
  const int wr = wave >> 1, wc = wave & 1;
  const int h = blockIdx.z;
  const int m0 = blockIdx.x * 128, n0 = blockIdx.y * 128;
  const __bf16* A = E1p + (size_t)h * NNODE * 32;
  const __bf16* Bt = E2p + (size_t)h * NNODE * 32;
  const int rowA = tid >> 2;
  const int colb = (tid & 3) * 16;
  gload16((const char*)(A + (size_t)(m0 + rowA) * 32) + colb, (char*)As + wave * 1024);
  gload16((const char*)(A + (size_t)(m0 + rowA + 64) * 32) + colb, (char*)As + 4096 + wave * 1024);
  gload16((const char*)(Bt + (size_t)(n0 + rowA) * 32) + colb, (char*)Bs + wave * 1024);
  gload16((const char*)(Bt + (size_t)(n0 + rowA + 64) * 32) + colb, (char*)Bs + 4096 + wave * 1024);
  __syncthreads();

  f32x4 acc[4][4] = {};
  bf16x8 af[4], bfr[4];
#pragma unroll
  for (int mi = 0; mi < 4; ++mi)
    af[mi] = *(const bf16x8*)((const char*)As +
             ((wr * 64 + mi * 16 + (lane & 15)) * 64 + (lane >> 4) * 16));
#pragma unroll
  for (int ni = 0; ni < 4; ++ni)
    bfr[ni] = *(const bf16x8*)((const char*)Bs +
             ((wc * 64 + ni * 16 + (lane & 15)) * 64 + (lane >> 4) * 16));
#pragma unroll
  for (int mi = 0; mi < 4; ++mi)
#pragma unroll
    for (int ni = 0; ni < 4; ++ni)
      acc[mi][ni] = __builtin_amdgcn_mfma_f32_16x16x32_bf16(af[mi], bfr[ni],
                                                            acc[mi][ni], 0, 0, 0);

  const int crow = (lane >> 4) * 4;
  const int ccol = lane & 15;
#pragma unroll
  for (int mi = 0; mi < 4; ++mi)
#pragma unroll
    for (int ni = 0; ni < 4; ++ni) {
      int r0 = m0 + wr * 64 + mi * 16 + crow;
      int cc = n0 + wc * 64 + ni * 16 + ccol;
#pragma unroll
      for (int r = 0; r < 4; ++r) {
        float val = fmaxf(acc[mi][ni][r], 0.f) * 0.25f;
        SC[((size_t)h * NNODE + r0 + r) * NNODE + cc] = (__bf16)val;
      }
    }
}

// ---------------------------------------------------------------------------
// Row softmax over v: one wave per row of SC [8192 x 2048] bf16 -> adjh bf16
__global__ __launch_bounds__(256) void softmax_rows(const __bf16* __restrict__ SC,
                                                    __bf16* __restrict__ adjh) {
  const int tid = threadIdx.x;
  const int wave = tid >> 6, lane = tid & 63;
  const size_t row = (size_t)blockIdx.x * 4 + wave;
  const __bf16* src = SC + row * NNODE;
  __bf16* dst = adjh + row * NNODE;
  float v[32];
  float mx = 0.f;
#pragma unroll
  for (int j = 0; j < 4; ++j) {
    bf16x8 q = *(const bf16x8*)(src + j * 512 + lane * 8);
#pragma unroll
    for (int i = 0; i < 8; ++i) {
      float f = (float)q[i];
      v[j * 8 + i] = f;
      mx = fmaxf(mx, f);
    }
  }
#pragma unroll
  for (int o = 32; o > 0; o >>= 1) mx = fmaxf(mx, __shfl_xor(mx, o));
  float s = 0.f;
#pragma unroll
  for (int i = 0; i < 32; ++i) {
    v[i] = __expf(v[i] - mx);
    s += v[i];
  }
#pragma unroll
  for (int o = 32; o > 0; o >>= 1) s += __shfl_xor(s, o);
  float inv = 1.f / s;
#pragma unroll
  for (int j = 0; j < 4; ++j) {
    bf16x8 q;
#pragma unroll
    for (int i = 0; i < 8; ++i) q[i] = (__bf16)(v[j * 8 + i] * inv);
    *(bf16x8*)(dst + j * 512 + lane * 8) = q;
  }
}

// ---------------------------------------------------------------------------
// Wzrt[c][k]=Wz[k][c]*(k<64?s:1); Wzrt[64+c][k]=Wr[k][c]*...; Wct rows 64..127 = 0
__global__ __launch_bounds__(256) void prep_w(const float* __restrict__ Wz,
                                              const float* __restrict__ Wr,
                                              const float* __restrict__ Wc,
                                              const float* __restrict__ wpre,
                                              const float* __restrict__ wadp,
                                              __bf16* __restrict__ Wzrt,
                                              __bf16* __restrict__ Wct) {
  int idx = blockIdx.x * 256 + threadIdx.x;  // 0 .. 128*192-1
  int rr = idx / 192, k = idx % 192;
  float s = 2.f * (*wpre) + (*wadp);
  float sc = (k < 64) ? s : 1.f;
  float vz = (rr < 64) ? Wz[(size_t)k * 64 + rr] : Wr[(size_t)k * 64 + rr - 64];
  Wzrt[idx] = (__bf16)(vz * sc);
  float vc = (rr < 64) ? Wc[(size_t)k * 64 + rr] * sc : 0.f;
  Wct[idx] = (__bf16)vc;
}

// ---------------------------------------------------------------------------
// x f32 [B,N,64] -> XT bf16 [B*64, N] (XT[b*64+c][v]=x[b,v,c]) and xbf bf16 [B*N,64]
__global__ __launch_bounds__(256) void transpose_x(const float* __restrict__ x,
                                                   __bf16* __restrict__ XT,
                                                   __bf16* __restrict__ xbf) {
  const int b = blockIdx.y, v0 = blockIdx.x * 64;
  const int tid = threadIdx.x;
  __shared__ float t[64][65];
  const int vr = tid >> 2, c0 = (tid & 3) * 16;
  const float* src = x + ((size_t)b * NNODE + v0 + vr) * 64 + c0;
  __bf16* xb = xbf + ((size_t)b * NNODE + v0 + vr) * 64 + c0;
#pragma unroll
  for (int j = 0; j < 4; ++j) {
    float4 q = ((const float4*)src)[j];
    t[vr][c0 + j * 4 + 0] = q.x;
    t[vr][c0 + j * 4 + 1] = q.y;
    t[vr][c0 + j * 4 + 2] = q.z;
    t[vr][c0 + j * 4 + 3] = q.w;
    xb[j * 4 + 0] = (__bf16)q.x;
    xb[j * 4 + 1] = (__bf16)q.y;
    xb[j * 4 + 2] = (__bf16)q.z;
    xb[j * 4 + 3] = (__bf16)q.w;
  }
  __syncthreads();
#pragma unroll
  for (int jr = 0; jr < 16; ++jr) {
    int c = jr * 4 + (tid >> 6);
    int v = tid & 63;
    XT[((size_t)b * 64 + c) * NNODE + v0 + v] = (__bf16)t[v][c];
  }
}

// rx bf16 [B*N,64] -> XT bf16 [B*64, N]
__global__ __launch_bounds__(256) void transpose_rx(const __bf16* __restrict__ rx,
                                                    __bf16* __restrict__ XT) {
  const int b = blockIdx.y, v0 = blockIdx.x * 64;
  const int tid = threadIdx.x;
  __shared__ float t[64][65];
  const int vr = tid >> 2, c0 = (tid & 3) * 16;
  const __bf16* src = rx + ((size_t)b * NNODE + v0 + vr) * 64 + c0;
  bf16x8 q0 = ((const bf16x8*)src)[0];
  bf16x8 q1 = ((const bf16x8*)src)[1];
#pragma unroll
  for (int i = 0; i < 8; ++i) {
    t[vr][c0 + i] = (float)q0[i];
    t[vr][c0 + 8 + i] = (float)q1[i];
  }
  __syncthreads();
#pragma unroll
  for (int jr = 0; jr < 16; ++jr) {
    int c = jr * 4 + (tid >> 6);
    int v = tid & 63;
    XT[((size_t)b * 64 + c) * NNODE + v0 + v] = (__bf16)t[v][c];
  }
}

// ---------------------------------------------------------------------------
// 8-phase 256x256 GEMM (m201-style), batched over z:
//   C_z[m][n] = sum_k A_z[m][k] * Bt_z[n][k]   (2048x2048 bf16 row-major)
// 8 waves (2M x 4N), BK=64, 128 KiB LDS double-buffer, st_16x32 swizzle,
// counted vmcnt(4), raw barriers, setprio around MFMA quadrants.
#define VMCNT4() asm volatile("s_waitcnt vmcnt(4)" ::: "memory")
#define BARRIER() asm volatile("s_barrier" ::: "memory")

__global__ __launch_bounds__(512, 2) void gemm_hop8(const __bf16* __restrict__ Abase,
                                                    size_t aStrideZ,
                                                    const __bf16* __restrict__ BtBase,
                                                    __bf16* __restrict__ Cbase) {
  extern __shared__ char smem[];  // 131072 B
  const int tid = threadIdx.x;
  const int w = tid >> 6, l = tid & 63;
  const int wr = w >> 2, wc = w & 3;  // 2 M-waves x 4 N-waves
  const size_t z = blockIdx.z;
  const int m0 = blockIdx.x * 256, n0 = blockIdx.y * 256;
  const __bf16* A = Abase + z * aStrideZ;
  const __bf16* Bt = BtBase + z * (size_t)(NNODE * NNODE);
  __bf16* C = Cbase + z * (size_t)(NNODE * NNODE);
  const int NT = NNODE / 64;  // 32 K-tiles

  // region bases: A: d*32K + h*16K ; B: 64K + d*32K + h*16K
  // swizzled read offsets within a 16 KiB half-region ([128 rows][128 B])
  int aoff[4][2], boff[2][2];
#pragma unroll
  for (int m = 0; m < 4; ++m)
#pragma unroll
    for (int ks = 0; ks < 2; ++ks) {
      int rh = m * 32 + wr * 16 + (l & 15);
      int lo = rh * 128 + ks * 64 + ((l >> 4) * 16);
      aoff[m][ks] = lo ^ (((rh >> 2) & 1) << 5);
    }
#pragma unroll
  for (int n = 0; n < 2; ++n)
#pragma unroll
    for (int ks = 0; ks < 2; ++ks) {
      int rh = n * 64 + wc * 16 + (l & 15);
      int lo = rh * 128 + ks * 64 + ((l >> 4) * 16);
      boff[n][ks] = lo ^ (((rh >> 2) & 1) << 5);
    }

  // staging source geometry (inverse-swizzle on the GLOBAL side, LDS linear)
  // per load j: lds o = j*8192 + w*1024 + l*16 ; bit9(o) = l>=32
  const int sg_row[2] = {w * 8 + (l >> 3), 64 + w * 8 + (l >> 3)};
  const int sg_col = ((l & 7) * 16) ^ (((l >> 5) & 1) << 5);

#define STAGE(gbase, row0, kt, region)                                        \
  do {                                                                        \
    const char* _g0 = (const char*)(gbase) +                                  \
        (size_t)((row0) + sg_row[0]) * 4096 + (size_t)(kt) * 128 + sg_col;    \
    const char* _g1 = (const char*)(gbase) +                                  \
        (size_t)((row0) + sg_row[1]) * 4096 + (size_t)(kt) * 128 + sg_col;    \
    gload16(_g0, (region) + w * 1024);                                        \
    gload16(_g1, (region) + 8192 + w * 1024);                                 \
  } while (0)

#define AREG(d, h) (smem + (d) * 32768 + (h) * 16384)
#define BREG(d, h) (smem + 65536 + (d) * 32768 + (h) * 16384)

  f32x4 acc[8][4] = {};
  bf16x8 af[4][2], bf[2][2];

  // ---- prologue: tile0 {A0,B0,B1,A1}, tile1 {A0,B0}
  STAGE(A, m0, 0, AREG(0, 0));
  STAGE(Bt, n0, 0, BREG(0, 0));
  STAGE(Bt, n0 + 128, 0, BREG(0, 1));
  STAGE(A, m0 + 128, 0, AREG(0, 1));
  STAGE(A, m0, 1, AREG(1, 0));
  STAGE(Bt, n0, 1, BREG(1, 0));
  VMCNT4();
  BARRIER();

  for (int t = 0; t < NT; ++t) {
    const int d = t & 1;
    // ---------- phase 1: quadrant (A-half0, B-half0); stage (t+1).B1
#pragma unroll
    for (int m = 0; m < 4; ++m) {
      af[m][0] = *(const bf16x8*)(AREG(d, 0) + aoff[m][0]);
      af[m][1] = *(const bf16x8*)(AREG(d, 0) + aoff[m][1]);
    }
#pragma unroll
    for (int n = 0; n < 2; ++n) {
      bf[n][0] = *(const bf16x8*)(BREG(d, 0) + boff[n][0]);
      bf[n][1] = *(const bf16x8*)(BREG(d, 0) + boff[n][1]);
    }
    if (t + 1 < NT) STAGE(Bt, n0 + 128, t + 1, BREG(d ^ 1, 1));
    BARRIER();
    __builtin_amdgcn_s_setprio(1);
#pragma unroll
    for (int m = 0; m < 4; ++m)
#pragma unroll
      for (int n = 0; n < 2; ++n)
#pragma unroll
        for (int ks = 0; ks < 2; ++ks)
          acc[m][n] = __builtin_amdgcn_mfma_f32_16x16x32_bf16(af[m][ks], bf[n][ks],
                                                              acc[m][n], 0, 0, 0);
    __builtin_amdgcn_s_setprio(0);
    BARRIER();

    // ---------- phase 2: quadrant (A-half0, B-half1); stage (t+1).A1
#pragma unroll
    for (int n = 0; n < 2; ++n) {
      bf[n][0] = *(const bf16x8*)(BREG(d, 1) + boff[n][0]);
      bf[n][1] = *(const bf16x8*)(BREG(d, 1) + boff[n][1]);
    }
    if (t + 1 < NT) STAGE(A, m0 + 128, t + 1, AREG(d ^ 1, 1));
    BARRIER();
    __builtin_amdgcn_s_setprio(1);
#pragma unroll
    for (int m = 0; m < 4; ++m)
#pragma unroll
      for (int n = 0; n < 2; ++n)
#pragma unroll
        for (int ks = 0; ks < 2; ++ks)
          acc[m][n + 2] = __builtin_amdgcn_mfma_f32_16x16x32_bf16(af[m][ks], bf[n][ks],
                                                                  acc[m][n + 2], 0, 0, 0);
    __builtin_amdgcn_s_setprio(0);
    BARRIER();

    // ---------- phase 3: quadrant (A-half1, B-half0); stage (t+2).A0
#pragma unroll
    for (int m = 0; m < 4; ++m) {
      af[m][0] = *(const bf16x8*)(AREG(d, 1) + aoff[m][0]);
      af[m][1] = *(const bf16x8*)(AREG(d, 1) + aoff[m][1]);
    }
#pragma unroll
    for (int n = 0; n < 2; ++n) {
      bf[n][0] = *(const bf16x8*)(BREG(d, 0) + boff[n][0]);
      bf[n][1] = *(const bf16x8*)(BREG(d, 0) + boff[n][1]);
    }
    if (t + 2 < NT) STAGE(A, m0, t + 2, AREG(d, 0));
    BARRIER();
    __builtin_amdgcn_s_setprio(1);
#pragma unroll
    for (int m = 0; m < 4; ++m)
#pragma unroll
      for (int n = 0; n < 2; ++n)
#pragma unroll
        for (int ks = 0; ks < 2; ++ks)
          acc[m + 4][n] = __builtin_amdgcn_mfma_f32_16x16x32_bf16(af[m][ks], bf[n][ks],
                                                                  acc[m + 4][n], 0, 0, 0);
    __builtin_amdgcn_s_setprio(0);
    BARRIER();

    // ---------- phase 4: quadrant (A-half1, B-half1); stage (t+2).B0; vmcnt
#pragma unroll
    for (int n = 0; n < 2; ++n) {
      bf[n][0] = *(const bf16x8*)(BREG(d, 1) + boff[n][0]);
      bf[n][1] = *(const bf16x8*)(BREG(d, 1) + boff[n][1]);
    }
    if (t + 2 < NT) STAGE(Bt, n0, t + 2, BREG(d, 0));
    VMCNT4();
    BARRIER();
    __builtin_amdgcn_s_setprio(1);
#pragma unroll
    for (int m = 0; m < 4; ++m)
#pragma unroll
      for (int n = 0; n < 2; ++n)
#pragma unroll
        for (int ks = 0; ks < 2; ++ks)
          acc[m + 4][n + 2] = __builtin_amdgcn_mfma_f32_16x16x32_bf16(af[m][ks], bf[n][ks],
                                                                      acc[m + 4][n + 2], 0, 0, 0);
    __builtin_amdgcn_s_setprio(0);
    BARRIER();
  }

  // ---- epilogue: C write. frag (mi,ni): row = m0+(mi>>2)*128+(mi&3)*32+wr*16,
  // col = n0+(ni>>1)*128+(ni&1)*64+wc*16 ; lane mapping col=lane&15, row+=(l>>4)*4+r
  const int crow = (l >> 4) * 4;
  const int ccol = l & 15;
#pragma unroll
  for (int mi = 0; mi < 8; ++mi)
#pragma unroll
    for (int ni = 0; ni < 4; ++ni) {
      int r0 = m0 + (mi >> 2) * 128 + (mi & 3) * 32 + wr * 16 + crow;
      int cc = n0 + (ni >> 1) * 128 + (ni & 1) * 64 + wc * 16 + ccol;
#pragma unroll
      for (int r = 0; r < 4; ++r)
        C[(size_t)(r0 + r) * NNODE + cc] = (__bf16)acc[mi][ni][r];
    }
#undef STAGE
#undef AREG
#undef BREG
}

// ---------------------------------------------------------------------------
// S1[(b,w),c] = sum_z wz * H1[z][b*64+c][w] ;  same for S2/H2.  bf16 out [B*N,64]
__global__ __launch_bounds__(256) void combine_s(const __bf16* __restrict__ H1,
                                                 const __bf16* __restrict__ H2,
                                                 __bf16* __restrict__ S1,
                                                 __bf16* __restrict__ S2,
                                                 const float* __restrict__ wpre,
                                                 const float* __restrict__ wadp) {
  const int b = blockIdx.y;
  const int w0 = blockIdx.x * 64;
  const int tid = threadIdx.x;
  const float wp = *wpre, wa = *wadp * 0.25f;
  __shared__ float t1[64][65];
  __shared__ float t2[64][65];
  const int cr = tid >> 2;
  const int wg = (tid & 3) * 16;
  float a1[16] = {}, a2[16] = {};
  const size_t NN2 = (size_t)NNODE * NNODE;
#pragma unroll
  for (int z = 0; z < 6; ++z) {
    float wz = (z < 2) ? wp : wa;
    const __bf16* p1 = H1 + z * NN2 + (size_t)(b * 64 + cr) * NNODE + w0 + wg;
    const __bf16* p2 = H2 + z * NN2 + (size_t)(b * 64 + cr) * NNODE + w0 + wg;
    bf16x8 q10 = ((const bf16x8*)p1)[0], q11 = ((const bf16x8*)p1)[1];
    bf16x8 q20 = ((const bf16x8*)p2)[0], q21 = ((const bf16x8*)p2)[1];
#pragma unroll
    for (int i = 0; i < 8; ++i) {
      a1[i] += wz * (float)q10[i];
      a1[8 + i] += wz * (float)q11[i];
      a2[i] += wz * (float)q20[i];
      a2[8 + i] += wz * (float)q21[i];
    }
  }
#pragma unroll
  for (int i = 0; i < 16; ++i) {
    t1[cr][wg + i] = a1[i];
    t2[cr][wg + i] = a2[i];
  }
  __syncthreads();
#pragma unroll
  for (int jr = 0; jr < 16; ++jr) {
    int wl = jr * 4 + (tid >> 6);
    int c = tid & 63;
    size_t o = ((size_t)b * NNODE + w0 + wl) * 64 + c;
    S1[o] = (__bf16)t1[c][wl];
    S2[o] = (__bf16)t2[c][wl];
  }
}

// ---------------------------------------------------------------------------
// Gate linear GEMM: [65536 x 192] @ Wt^T, K=192, N=128, fused epilogues.
// MODE 0: cols 0-63 -> z=sigmoid -> zbuf(f32); cols 64-127 -> r -> rx=(bf16)(r*hid)
// MODE 1: cols 0-63 -> c=tanh   -> out=(1-z)*hid+z*c (f32)
template <int MODE>
__global__ __launch_bounds__(256) void gemm_lin(const __bf16* __restrict__ Xp,
                                                const __bf16* __restrict__ S1,
                                                const __bf16* __restrict__ S2,
                                                const __bf16* __restrict__ Wt,
                                                const float* __restrict__ b0,
                                                const float* __restrict__ b1,
                                                const float* __restrict__ wpre,
                                                const float* __restrict__ wadp,
                                                const float* __restrict__ hid,
                                                float* __restrict__ zbuf,
                                                __bf16* __restrict__ rxout,
                                                float* __restrict__ outp) {
  __shared__ __bf16 As[128 * 32];
  __shared__ __bf16 Bs[128 * 32];
  const int tid = threadIdx.x;
  const int wave = tid >> 6, lane = tid & 63;
  const int wr = wave >> 1, wc = wave & 1;
  const int m0 = blockIdx.x * 128;
  const int rowA = tid >> 2;
  const int colb = (tid & 3) * 16;
  const __bf16* srcs[3] = {Xp, S1, S2};
  char* asD0 = (char*)As + wave * 1024;
  char* asD1 = (char*)As + 4096 + wave * 1024;
  char* bsD0 = (char*)Bs + wave * 1024;
  char* bsD1 = (char*)Bs + 4096 + wave * 1024;

  f32x4 acc[4][4] = {};

#pragma unroll
  for (int kt = 0; kt < 6; ++kt) {
    const __bf16* Ab = srcs[kt >> 1];
    const char* aS0 = (const char*)(Ab + (size_t)(m0 + rowA) * 64) + (kt & 1) * 64 + colb;
    const char* aS1 = (const char*)(Ab + (size_t)(m0 + rowA + 64) * 64) + (kt & 1) * 64 + colb;
    const char* bS0 = (const char*)(Wt + (size_t)rowA * 192) + kt * 64 + colb;
    const char* bS1 = (const char*)(Wt + (size_t)(rowA + 64) * 192) + kt * 64 + colb;
    gload16(aS0, asD0);
    gload16(aS1, asD1);
    gload16(bS0, bsD0);
    gload16(bS1, bsD1);
    __syncthreads();
    bf16x8 af[4], bfr[4];
#pragma unroll
    for (int mi = 0; mi < 4; ++mi)
      af[mi] = *(const bf16x8*)((const char*)As +
               ((wr * 64 + mi * 16 + (lane & 15)) * 64 + (lane >> 4) * 16));
#pragma unroll
    for (int ni = 0; ni < 4; ++ni)
      bfr[ni] = *(const bf16x8*)((const char*)Bs +
               ((wc * 64 + ni * 16 + (lane & 15)) * 64 + (lane >> 4) * 16));
#pragma unroll
    for (int mi = 0; mi < 4; ++mi)
#pragma unroll
      for (int ni = 0; ni < 4; ++ni)
        acc[mi][ni] = __builtin_amdgcn_mfma_f32_16x16x32_bf16(af[mi], bfr[ni],
                                                              acc[mi][ni], 0, 0, 0);
    __syncthreads();
  }

  const float wp = *wpre, wa = *wadp;
  const float s = 2.f * wp + wa;
  const int crow = (lane >> 4) * 4;
  const int ccol = lane & 15;
#pragma unroll
  for (int mi = 0; mi < 4; ++mi)
#pragma unroll
    for (int ni = 0; ni < 4; ++ni) {
      int r0 = m0 + wr * 64 + mi * 16 + crow;
      int col = wc * 64 + ni * 16 + ccol;
      int cf = col & 63;
#pragma unroll
      for (int r = 0; r < 4; ++r) {
        int row = r0 + r;
        float g = acc[mi][ni][r];
        if (MODE == 0) {
          if (col < 64) {
            g += s * b0[cf];
            zbuf[(size_t)row * 64 + cf] = 1.f / (1.f + __expf(-g));
          } else {
            g += s * b1[cf];
            float rv = 1.f / (1.f + __expf(-g));
            rxout[(size_t)row * 64 + cf] = (__bf16)(rv * hid[(size_t)row * 64 + cf]);
          }
        } else {
          if (col < 64) {
            g += s * b0[cf];
            float cv = 1.f - 2.f / (1.f + __expf(2.f * g));
            float zv = zbuf[(size_t)row * 64 + cf];
            float hv = hid[(size_t)row * 64 + cf];
            outp[(size_t)row * 64 + cf] = (1.f - zv) * hv + zv * cv;
          }
        }
      }
    }
}

// ---------------------------------------------------------------------------
extern "C" void kernel_launch(void* const* d_in, const int* in_sizes, int n_in,
                              void* d_out, int out_size, void* d_ws, size_t ws_size,
                              hipStream_t stream) {
  (void)in_sizes; (void)n_in; (void)out_size;
  const float* x    = (const float*)d_in[0];
  const float* A1   = (const float*)d_in[1];
  const float* A2   = (const float*)d_in[2];
  const float* E1   = (const float*)d_in[3];
  const float* E2   = (const float*)d_in[4];
  const float* Wz   = (const float*)d_in[5];
  const float* bz   = (const float*)d_in[6];
  const float* Wr   = (const float*)d_in[7];
  const float* br   = (const float*)d_in[8];
  const float* Wc   = (const float*)d_in[9];
  const float* bc   = (const float*)d_in[10];
  const float* wpre = (const float*)d_in[11];
  const float* wadp = (const float*)d_in[12];
  float* out = (float*)d_out;

  char* ws = (char*)d_ws;
  const size_t NN2 = (size_t)NNODE * NNODE;  // 4,194,304 (= B*N*D too)
  __bf16* ADJ  = (__bf16*)(ws);                    // 6*NN2 bf16
  __bf16* XT   = (__bf16*)(ws + 6  * NN2 * 2);     // NN2
  __bf16* H1   = (__bf16*)(ws + 7  * NN2 * 2);     // 6*NN2
  __bf16* H2   = (__bf16*)(ws + 13 * NN2 * 2);     // 6*NN2
  __bf16* xbf  = (__bf16*)(ws + 19 * NN2 * 2);     // NN2
  __bf16* rx   = (__bf16*)(ws + 20 * NN2 * 2);     // NN2
  __bf16* S1   = (__bf16*)(ws + 21 * NN2 * 2);     // NN2
  __bf16* S2   = (__bf16*)(ws + 22 * NN2 * 2);     // NN2
  float*  zbuf = (float*)(ws + 23 * NN2 * 2);      // NN2 f32
  __bf16* Wzrt = (__bf16*)(ws + 23 * NN2 * 2 + NN2 * 4);
  __bf16* Wct  = (__bf16*)(ws + 23 * NN2 * 2 + NN2 * 4 + 128 * 192 * 2);
  if (ws_size < 23 * NN2 * 2 + NN2 * 4 + 2 * 128 * 192 * 2) return;

  // scratch reuse: SC lives in the (not-yet-used) H1 region, E1p/E2p in H2.
  __bf16* SC  = H1;                      // 4*NN2 bf16 scores
  __bf16* E1p = H2;                      // 4*2048*32 bf16
  __bf16* E2p = H2 + 4 * NNODE * 32;

  conv_bf16<<<4096, 256, 0, stream>>>(A1, ADJ);
  conv_bf16<<<4096, 256, 0, stream>>>(A2, ADJ + NN2);
  prep_e<<<128, 256, 0, stream>>>(E1, E2, E1p, E2p);
  score_gemm<<<dim3(16, 16, 4), 256, 0, stream>>>(E1p, E2p, SC);
  softmax_rows<<<2048, 256, 0, stream>>>(SC, ADJ + 2 * NN2);
  prep_w<<<96, 256, 0, stream>>>(Wz, Wr, Wc, wpre, wadp, Wzrt, Wct);
  transpose_x<<<dim3(32, 32), 256, 0, stream>>>(x, XT, xbf);

  // stage 1: hops on x (shared by z and r gates)
  gemm_hop8<<<dim3(8, 8, 6), 512, 131072, stream>>>(XT, 0, ADJ, H1);
  gemm_hop8<<<dim3(8, 8, 6), 512, 131072, stream>>>(H1, NN2, ADJ, H2);
  combine_s<<<dim3(32, 32), 256, 0, stream>>>(H1, H2, S1, S2, wpre, wadp);
  gemm_lin<0><<<512, 256, 0, stream>>>(xbf, S1, S2, Wzrt, bz, br, wpre, wadp,
                                       x, zbuf, rx, nullptr);

  // stage 2: hops on r*x
  transpose_rx<<<dim3(32, 32), 256, 0, stream>>>(rx, XT);
  gemm_hop8<<<dim3(8, 8, 6), 512, 131072, stream>>>(XT, 0, ADJ, H1);
  gemm_hop8<<<dim3(8, 8, 6), 512, 131072, stream>>>(H1, NN2, ADJ, H2);
  combine_s<<<dim3(32, 32), 256, 0, stream>>>(H1, H2, S1, S2, wpre, wadp);
  gemm_lin<1><<<512, 256, 0, stream>>>(rx, S1, S2, Wct, bc, nullptr, wpre, wadp,
                                       x, zbuf, nullptr, out);
}

// Round 4
// 587.133 us; speedup vs baseline: 1.1254x; 1.1254x over previous
//
#include <hip/hip_runtime.h>

#define NNODE 2048
#define NBATCH 32

typedef __attribute__((ext_vector_type(4))) float f32x4;
typedef __attribute__((ext_vector_type(8))) __bf16 bf16x8;

__device__ __forceinline__ void gload16(const void* g, void* lds) {
  __builtin_amdgcn_global_load_lds(
      (const __attribute__((address_space(1))) unsigned int*)g,
      (__attribute__((address_space(3))) unsigned int*)lds, 16, 0, 0);
}

// ---------------------------------------------------------------------------
// Convert f32 -> bf16 (4 elems/thread, exact grid)
__global__ __launch_bounds__(256) void conv_bf16(const float* __restrict__ in,
                                                 __bf16* __restrict__ outp) {
  int i = blockIdx.x * 256 + threadIdx.x;
  float4 q = ((const float4*)in)[i];
  outp[4 * (size_t)i + 0] = (__bf16)q.x;
  outp[4 * (size_t)i + 1] = (__bf16)q.y;
  outp[4 * (size_t)i + 2] = (__bf16)q.z;
  outp[4 * (size_t)i + 3] = (__bf16)q.w;
}

// ---------------------------------------------------------------------------
// Repack E1,E2 [N,H,16] f32 -> [H][N][32] bf16 (K zero-padded 16->32)
__global__ __launch_bounds__(256) void prep_e(const float* __restrict__ E1,
                                              const float* __restrict__ E2,
                                              __bf16* __restrict__ E1p,
                                              __bf16* __restrict__ E2p) {
  int idx = blockIdx.x * 256 + threadIdx.x;  // 0..32767
  int cq = idx & 3;
  int n = (idx >> 2) & 2047;
  int h = idx >> 13;
  const float4 q1 = *(const float4*)(E1 + (size_t)(n * 4 + h) * 16 + cq * 4);
  const float4 q2 = *(const float4*)(E2 + (size_t)(n * 4 + h) * 16 + cq * 4);
  size_t o = ((size_t)h * NNODE + n) * 32 + cq * 4;
  E1p[o + 0] = (__bf16)q1.x; E1p[o + 1] = (__bf16)q1.y;
  E1p[o + 2] = (__bf16)q1.z; E1p[o + 3] = (__bf16)q1.w;
  E2p[o + 0] = (__bf16)q2.x; E2p[o + 1] = (__bf16)q2.y;
  E2p[o + 2] = (__bf16)q2.z; E2p[o + 3] = (__bf16)q2.w;
  size_t oz = o + 16;
  E1p[oz + 0] = (__bf16)0.f; E1p[oz + 1] = (__bf16)0.f;
  E1p[oz + 2] = (__bf16)0.f; E1p[oz + 3] = (__bf16)0.f;
  E2p[oz + 0] = (__bf16)0.f; E2p[oz + 1] = (__bf16)0.f;
  E2p[oz + 2] = (__bf16)0.f; E2p[oz + 3] = (__bf16)0.f;
}

// ---------------------------------------------------------------------------
// SC[h][w][v] = relu(E1p_h @ E2p_h^T)/4, bf16. Single K=32 MFMA step.
__global__ __launch_bounds__(256) void score_gemm(const __bf16* __restrict__ E1p,
                                                  const __bf16* __restrict__ E2p,
                                                  __bf16* __restrict__ SC) {
  __shared__ __bf16 As[128 * 32];
  __shared__ __bf16 Bs[128 * 32];
  const int tid = threadIdx.x;
  const int wave = tid >> 6, lane = tid & 63;
  const int wr = wave >> 1, wc = wave & 1;
  const int h = blockIdx.z;
  const int m0 = blockIdx.x * 128, n0 = blockIdx.y * 128;
  const __bf16* A = E1p + (size_t)h * NNODE * 32;
  const __bf16* Bt = E2p + (size_t)h * NNODE * 32;
  const int rowA = tid >> 2;
  const int colb = (tid & 3) * 16;
  gload16((const char*)(A + (size_t)(m0 + rowA) * 32) + colb, (char*)As + wave * 1024);
  gload16((const char*)(A + (size_t)(m0 + rowA + 64) * 32) + colb, (char*)As + 4096 + wave * 1024);
  gload16((const char*)(Bt + (size_t)(n0 + rowA) * 32) + colb, (char*)Bs + wave * 1024);
  gload16((const char*)(Bt + (size_t)(n0 + rowA + 64) * 32) + colb, (char*)Bs + 4096 + wave * 1024);
  __syncthreads();

  f32x4 acc[4][4] = {};
  bf16x8 af[4], bfr[4];
#pragma unroll
  for (int mi = 0; mi < 4; ++mi)
    af[mi] = *(const bf16x8*)((const char*)As +
             ((wr * 64 + mi * 16 + (lane & 15)) * 64 + (lane >> 4) * 16));
#pragma unroll
  for (int ni = 0; ni < 4; ++ni)
    bfr[ni] = *(const bf16x8*)((const char*)Bs +
             ((wc * 64 + ni * 16 + (lane & 15)) * 64 + (lane >> 4) * 16));
#pragma unroll
  for (int mi = 0; mi < 4; ++mi)
#pragma unroll
    for (int ni = 0; ni < 4; ++ni)
      acc[mi][ni] = __builtin_amdgcn_mfma_f32_16x16x32_bf16(af[mi], bfr[ni],
                                                            acc[mi][ni], 0, 0, 0);

  const int crow = (lane >> 4) * 4;
  const int ccol = lane & 15;
#pragma unroll
  for (int mi = 0; mi < 4; ++mi)
#pragma unroll
    for (int ni = 0; ni < 4; ++ni) {
      int r0 = m0 + wr * 64 + mi * 16 + crow;
      int cc = n0 + wc * 64 + ni * 16 + ccol;
#pragma unroll
      for (int r = 0; r < 4; ++r) {
        float val = fmaxf(acc[mi][ni][r], 0.f) * 0.25f;
        SC[((size_t)h * NNODE + r0 + r) * NNODE + cc] = (__bf16)val;
      }
    }
}

// ---------------------------------------------------------------------------
// Row softmax over v: one wave per row of SC [8192 x 2048] bf16 -> adjh bf16
__global__ __launch_bounds__(256) void softmax_rows(const __bf16* __restrict__ SC,
                                                    __bf16* __restrict__ adjh) {
  const int tid = threadIdx.x;
  const int wave = tid >> 6, lane = tid & 63;
  const size_t row = (size_t)blockIdx.x * 4 + wave;
  const __bf16* src = SC + row * NNODE;
  __bf16* dst = adjh + row * NNODE;
  float v[32];
  float mx = 0.f;
#pragma unroll
  for (int j = 0; j < 4; ++j) {
    bf16x8 q = *(const bf16x8*)(src + j * 512 + lane * 8);
#pragma unroll
    for (int i = 0; i < 8; ++i) {
      float f = (float)q[i];
      v[j * 8 + i] = f;
      mx = fmaxf(mx, f);
    }
  }
#pragma unroll
  for (int o = 32; o > 0; o >>= 1) mx = fmaxf(mx, __shfl_xor(mx, o));
  float s = 0.f;
#pragma unroll
  for (int i = 0; i < 32; ++i) {
    v[i] = __expf(v[i] - mx);
    s += v[i];
  }
#pragma unroll
  for (int o = 32; o > 0; o >>= 1) s += __shfl_xor(s, o);
  float inv = 1.f / s;
#pragma unroll
  for (int j = 0; j < 4; ++j) {
    bf16x8 q;
#pragma unroll
    for (int i = 0; i < 8; ++i) q[i] = (__bf16)(v[j * 8 + i] * inv);
    *(bf16x8*)(dst + j * 512 + lane * 8) = q;
  }
}

// ---------------------------------------------------------------------------
// Wzrt[c][k]=Wz[k][c]*(k<64?s:1); Wzrt[64+c][k]=Wr[k][c]*...; Wct rows 64..127 = 0
__global__ __launch_bounds__(256) void prep_w(const float* __restrict__ Wz,
                                              const float* __restrict__ Wr,
                                              const float* __restrict__ Wc,
                                              const float* __restrict__ wpre,
                                              const float* __restrict__ wadp,
                                              __bf16* __restrict__ Wzrt,
                                              __bf16* __restrict__ Wct) {
  int idx = blockIdx.x * 256 + threadIdx.x;  // 0 .. 128*192-1
  int rr = idx / 192, k = idx % 192;
  float s = 2.f * (*wpre) + (*wadp);
  float sc = (k < 64) ? s : 1.f;
  float vz = (rr < 64) ? Wz[(size_t)k * 64 + rr] : Wr[(size_t)k * 64 + rr - 64];
  Wzrt[idx] = (__bf16)(vz * sc);
  float vc = (rr < 64) ? Wc[(size_t)k * 64 + rr] * sc : 0.f;
  Wct[idx] = (__bf16)vc;
}

// ---------------------------------------------------------------------------
// x f32 [B,N,64] -> XT bf16 [B*64, N] (XT[b*64+c][v]=x[b,v,c]) and xbf bf16 [B*N,64]
__global__ __launch_bounds__(256) void transpose_x(const float* __restrict__ x,
                                                   __bf16* __restrict__ XT,
                                                   __bf16* __restrict__ xbf) {
  const int b = blockIdx.y, v0 = blockIdx.x * 64;
  const int tid = threadIdx.x;
  __shared__ float t[64][65];
  const int vr = tid >> 2, c0 = (tid & 3) * 16;
  const float* src = x + ((size_t)b * NNODE + v0 + vr) * 64 + c0;
  __bf16* xb = xbf + ((size_t)b * NNODE + v0 + vr) * 64 + c0;
#pragma unroll
  for (int j = 0; j < 4; ++j) {
    float4 q = ((const float4*)src)[j];
    t[vr][c0 + j * 4 + 0] = q.x;
    t[vr][c0 + j * 4 + 1] = q.y;
    t[vr][c0 + j * 4 + 2] = q.z;
    t[vr][c0 + j * 4 + 3] = q.w;
    xb[j * 4 + 0] = (__bf16)q.x;
    xb[j * 4 + 1] = (__bf16)q.y;
    xb[j * 4 + 2] = (__bf16)q.z;
    xb[j * 4 + 3] = (__bf16)q.w;
  }
  __syncthreads();
#pragma unroll
  for (int jr = 0; jr < 16; ++jr) {
    int c = jr * 4 + (tid >> 6);
    int v = tid & 63;
    XT[((size_t)b * 64 + c) * NNODE + v0 + v] = (__bf16)t[v][c];
  }
}

// rx bf16 [B*N,64] -> XT bf16 [B*64, N]
__global__ __launch_bounds__(256) void transpose_rx(const __bf16* __restrict__ rx,
                                                    __bf16* __restrict__ XT) {
  const int b = blockIdx.y, v0 = blockIdx.x * 64;
  const int tid = threadIdx.x;
  __shared__ float t[64][65];
  const int vr = tid >> 2, c0 = (tid & 3) * 16;
  const __bf16* src = rx + ((size_t)b * NNODE + v0 + vr) * 64 + c0;
  bf16x8 q0 = ((const bf16x8*)src)[0];
  bf16x8 q1 = ((const bf16x8*)src)[1];
#pragma unroll
  for (int i = 0; i < 8; ++i) {
    t[vr][c0 + i] = (float)q0[i];
    t[vr][c0 + 8 + i] = (float)q1[i];
  }
  __syncthreads();
#pragma unroll
  for (int jr = 0; jr < 16; ++jr) {
    int c = jr * 4 + (tid >> 6);
    int v = tid & 63;
    XT[((size_t)b * 64 + c) * NNODE + v0 + v] = (__bf16)t[v][c];
  }
}

// ---------------------------------------------------------------------------
// 8-phase 256x256 GEMM, batched over z. 3-bit XOR swizzle:
//   sigma(o) = o ^ ((row(o)&7)<<4), row stride 128 B. LDS linear dest +
//   inverse-swizzled GLOBAL source (rule #21); reads use sigma on the address.
#define VMCNT4() asm volatile("s_waitcnt vmcnt(4)" ::: "memory")
#define BARRIER() asm volatile("s_barrier" ::: "memory")

__global__ __launch_bounds__(512, 2) void gemm_hop8(const __bf16* __restrict__ Abase,
                                                    size_t aStrideZ,
                                                    const __bf16* __restrict__ BtBase,
                                                    __bf16* __restrict__ Cbase) {
  extern __shared__ char smem[];  // 131072 B
  const int tid = threadIdx.x;
  const int w = tid >> 6, l = tid & 63;
  const int wr = w >> 2, wc = w & 3;  // 2 M-waves x 4 N-waves
  const size_t z = blockIdx.z;
  const int m0 = blockIdx.x * 256, n0 = blockIdx.y * 256;
  const __bf16* A = Abase + z * aStrideZ;
  const __bf16* Bt = BtBase + z * (size_t)(NNODE * NNODE);
  __bf16* C = Cbase + z * (size_t)(NNODE * NNODE);
  const int NT = NNODE / 64;  // 32 K-tiles

  // swizzled read offsets within a 16 KiB half-region ([128 rows][128 B])
  int aoff[4][2], boff[2][2];
#pragma unroll
  for (int m = 0; m < 4; ++m)
#pragma unroll
    for (int ks = 0; ks < 2; ++ks) {
      int rh = m * 32 + wr * 16 + (l & 15);
      int lo = rh * 128 + ks * 64 + ((l >> 4) * 16);
      aoff[m][ks] = lo ^ ((rh & 7) << 4);
    }
#pragma unroll
  for (int n = 0; n < 2; ++n)
#pragma unroll
    for (int ks = 0; ks < 2; ++ks) {
      int rh = n * 64 + wc * 16 + (l & 15);
      int lo = rh * 128 + ks * 64 + ((l >> 4) * 16);
      boff[n][ks] = lo ^ ((rh & 7) << 4);
    }

  // staging: LDS dest linear (o = j*8192 + w*1024 + l*16); global source gets
  // sigma applied: row(o)&7 = (l>>3)&7, slot(o) = l&7 -> src slot = slot^row&7
  const int sg_row[2] = {w * 8 + (l >> 3), 64 + w * 8 + (l >> 3)};
  const int sg_col = (((l & 7) ^ ((l >> 3) & 7)) << 4);

#define STAGE(gbase, row0, kt, region)                                        \
  do {                                                                        \
    const char* _g0 = (const char*)(gbase) +                                  \
        (size_t)((row0) + sg_row[0]) * 4096 + (size_t)(kt) * 128 + sg_col;    \
    const char* _g1 = (const char*)(gbase) +                                  \
        (size_t)((row0) + sg_row[1]) * 4096 + (size_t)(kt) * 128 + sg_col;    \
    gload16(_g0, (region) + w * 1024);                                        \
    gload16(_g1, (region) + 8192 + w * 1024);                                 \
  } while (0)

#define AREG(d, h) (smem + (d) * 32768 + (h) * 16384)
#define BREG(d, h) (smem + 65536 + (d) * 32768 + (h) * 16384)

  f32x4 acc[8][4] = {};
  bf16x8 af[4][2], bf[2][2];

  // ---- prologue: tile0 {A0,B0,B1,A1}, tile1 {A0,B0}
  STAGE(A, m0, 0, AREG(0, 0));
  STAGE(Bt, n0, 0, BREG(0, 0));
  STAGE(Bt, n0 + 128, 0, BREG(0, 1));
  STAGE(A, m0 + 128, 0, AREG(0, 1));
  STAGE(A, m0, 1, AREG(1, 0));
  STAGE(Bt, n0, 1, BREG(1, 0));
  VMCNT4();
  BARRIER();

  for (int t = 0; t < NT; ++t) {
    const int d = t & 1;
    // ---------- phase 1: quadrant (A-half0, B-half0); stage (t+1).B1
#pragma unroll
    for (int m = 0; m < 4; ++m) {
      af[m][0] = *(const bf16x8*)(AREG(d, 0) + aoff[m][0]);
      af[m][1] = *(const bf16x8*)(AREG(d, 0) + aoff[m][1]);
    }
#pragma unroll
    for (int n = 0; n < 2; ++n) {
      bf[n][0] = *(const bf16x8*)(BREG(d, 0) + boff[n][0]);
      bf[n][1] = *(const bf16x8*)(BREG(d, 0) + boff[n][1]);
    }
    if (t + 1 < NT) STAGE(Bt, n0 + 128, t + 1, BREG(d ^ 1, 1));
    BARRIER();
    __builtin_amdgcn_s_setprio(1);
#pragma unroll
    for (int m = 0; m < 4; ++m)
#pragma unroll
      for (int n = 0; n < 2; ++n)
#pragma unroll
        for (int ks = 0; ks < 2; ++ks)
          acc[m][n] = __builtin_amdgcn_mfma_f32_16x16x32_bf16(af[m][ks], bf[n][ks],
                                                              acc[m][n], 0, 0, 0);
    __builtin_amdgcn_s_setprio(0);
    BARRIER();

    // ---------- phase 2: quadrant (A-half0, B-half1); stage (t+1).A1
#pragma unroll
    for (int n = 0; n < 2; ++n) {
      bf[n][0] = *(const bf16x8*)(BREG(d, 1) + boff[n][0]);
      bf[n][1] = *(const bf16x8*)(BREG(d, 1) + boff[n][1]);
    }
    if (t + 1 < NT) STAGE(A, m0 + 128, t + 1, AREG(d ^ 1, 1));
    BARRIER();
    __builtin_amdgcn_s_setprio(1);
#pragma unroll
    for (int m = 0; m < 4; ++m)
#pragma unroll
      for (int n = 0; n < 2; ++n)
#pragma unroll
        for (int ks = 0; ks < 2; ++ks)
          acc[m][n + 2] = __builtin_amdgcn_mfma_f32_16x16x32_bf16(af[m][ks], bf[n][ks],
                                                                  acc[m][n + 2], 0, 0, 0);
    __builtin_amdgcn_s_setprio(0);
    BARRIER();

    // ---------- phase 3: quadrant (A-half1, B-half0); stage (t+2).A0
#pragma unroll
    for (int m = 0; m < 4; ++m) {
      af[m][0] = *(const bf16x8*)(AREG(d, 1) + aoff[m][0]);
      af[m][1] = *(const bf16x8*)(AREG(d, 1) + aoff[m][1]);
    }
#pragma unroll
    for (int n = 0; n < 2; ++n) {
      bf[n][0] = *(const bf16x8*)(BREG(d, 0) + boff[n][0]);
      bf[n][1] = *(const bf16x8*)(BREG(d, 0) + boff[n][1]);
    }
    if (t + 2 < NT) STAGE(A, m0, t + 2, AREG(d, 0));
    BARRIER();
    __builtin_amdgcn_s_setprio(1);
#pragma unroll
    for (int m = 0; m < 4; ++m)
#pragma unroll
      for (int n = 0; n < 2; ++n)
#pragma unroll
        for (int ks = 0; ks < 2; ++ks)
          acc[m + 4][n] = __builtin_amdgcn_mfma_f32_16x16x32_bf16(af[m][ks], bf[n][ks],
                                                                  acc[m + 4][n], 0, 0, 0);
    __builtin_amdgcn_s_setprio(0);
    BARRIER();

    // ---------- phase 4: quadrant (A-half1, B-half1); stage (t+2).B0; vmcnt
#pragma unroll
    for (int n = 0; n < 2; ++n) {
      bf[n][0] = *(const bf16x8*)(BREG(d, 1) + boff[n][0]);
      bf[n][1] = *(const bf16x8*)(BREG(d, 1) + boff[n][1]);
    }
    if (t + 2 < NT) STAGE(Bt, n0, t + 2, BREG(d, 0));
    VMCNT4();
    BARRIER();
    __builtin_amdgcn_s_setprio(1);
#pragma unroll
    for (int m = 0; m < 4; ++m)
#pragma unroll
      for (int n = 0; n < 2; ++n)
#pragma unroll
        for (int ks = 0; ks < 2; ++ks)
          acc[m + 4][n + 2] = __builtin_amdgcn_mfma_f32_16x16x32_bf16(af[m][ks], bf[n][ks],
                                                                      acc[m + 4][n + 2], 0, 0, 0);
    __builtin_amdgcn_s_setprio(0);
    BARRIER();
  }

  // ---- epilogue: C write
  const int crow = (l >> 4) * 4;
  const int ccol = l & 15;
#pragma unroll
  for (int mi = 0; mi < 8; ++mi)
#pragma unroll
    for (int ni = 0; ni < 4; ++ni) {
      int r0 = m0 + (mi >> 2) * 128 + (mi & 3) * 32 + wr * 16 + crow;
      int cc = n0 + (ni >> 1) * 128 + (ni & 1) * 64 + wc * 16 + ccol;
#pragma unroll
      for (int r = 0; r < 4; ++r)
        C[(size_t)(r0 + r) * NNODE + cc] = (__bf16)acc[mi][ni][r];
    }
#undef STAGE
#undef AREG
#undef BREG
}

// ---------------------------------------------------------------------------
// S1[(b,w),c] = sum_z wz * H1[z][b*64+c][w] ;  same for S2/H2.  bf16 out [B*N,64]
__global__ __launch_bounds__(256) void combine_s(const __bf16* __restrict__ H1,
                                                 const __bf16* __restrict__ H2,
                                                 __bf16* __restrict__ S1,
                                                 __bf16* __restrict__ S2,
                                                 const float* __restrict__ wpre,
                                                 const float* __restrict__ wadp) {
  const int b = blockIdx.y;
  const int w0 = blockIdx.x * 64;
  const int tid = threadIdx.x;
  const float wp = *wpre, wa = *wadp * 0.25f;
  __shared__ float t1[64][65];
  __shared__ float t2[64][65];
  const int cr = tid >> 2;
  const int wg = (tid & 3) * 16;
  float a1[16] = {}, a2[16] = {};
  const size_t NN2 = (size_t)NNODE * NNODE;
#pragma unroll
  for (int z = 0; z < 6; ++z) {
    float wz = (z < 2) ? wp : wa;
    const __bf16* p1 = H1 + z * NN2 + (size_t)(b * 64 + cr) * NNODE + w0 + wg;
    const __bf16* p2 = H2 + z * NN2 + (size_t)(b * 64 + cr) * NNODE + w0 + wg;
    bf16x8 q10 = ((const bf16x8*)p1)[0], q11 = ((const bf16x8*)p1)[1];
    bf16x8 q20 = ((const bf16x8*)p2)[0], q21 = ((const bf16x8*)p2)[1];
#pragma unroll
    for (int i = 0; i < 8; ++i) {
      a1[i] += wz * (float)q10[i];
      a1[8 + i] += wz * (float)q11[i];
      a2[i] += wz * (float)q20[i];
      a2[8 + i] += wz * (float)q21[i];
    }
  }
#pragma unroll
  for (int i = 0; i < 16; ++i) {
    t1[cr][wg + i] = a1[i];
    t2[cr][wg + i] = a2[i];
  }
  __syncthreads();
#pragma unroll
  for (int jr = 0; jr < 16; ++jr) {
    int wl = jr * 4 + (tid >> 6);
    int c = tid & 63;
    size_t o = ((size_t)b * NNODE + w0 + wl) * 64 + c;
    S1[o] = (__bf16)t1[c][wl];
    S2[o] = (__bf16)t2[c][wl];
  }
}

// ---------------------------------------------------------------------------
// Gate linear GEMM: [65536 x 192] @ Wt^T, K=192, N=128, fused epilogues.
// MODE 0: cols 0-63 -> z=sigmoid -> zbuf(f32); cols 64-127 -> r -> rx=(bf16)(r*hid)
// MODE 1: cols 0-63 -> c=tanh   -> out=(1-z)*hid+z*c (f32)
template <int MODE>
__global__ __launch_bounds__(256) void gemm_lin(const __bf16* __restrict__ Xp,
                                                const __bf16* __restrict__ S1,
                                                const __bf16* __restrict__ S2,
                                                const __bf16* __restrict__ Wt,
                                                const float* __restrict__ b0,
                                                const float* __restrict__ b1,
                                                const float* __restrict__ wpre,
                                                const float* __restrict__ wadp,
                                                const float* __restrict__ hid,
                                                float* __restrict__ zbuf,
                                                __bf16* __restrict__ rxout,
                                                float* __restrict__ outp) {
  __shared__ __bf16 As[128 * 32];
  __shared__ __bf16 Bs[128 * 32];
  const int tid = threadIdx.x;
  const int wave = tid >> 6, lane = tid & 63;
  const int wr = wave >> 1, wc = wave & 1;
  const int m0 = blockIdx.x * 128;
  const int rowA = tid >> 2;
  const int colb = (tid & 3) * 16;
  const __bf16* srcs[3] = {Xp, S1, S2};
  char* asD0 = (char*)As + wave * 1024;
  char* asD1 = (char*)As + 4096 + wave * 1024;
  char* bsD0 = (char*)Bs + wave * 1024;
  char* bsD1 = (char*)Bs + 4096 + wave * 1024;

  f32x4 acc[4][4] = {};

#pragma unroll
  for (int kt = 0; kt < 6; ++kt) {
    const __bf16* Ab = srcs[kt >> 1];
    const char* aS0 = (const char*)(Ab + (size_t)(m0 + rowA) * 64) + (kt & 1) * 64 + colb;
    const char* aS1 = (const char*)(Ab + (size_t)(m0 + rowA + 64) * 64) + (kt & 1) * 64 + colb;
    const char* bS0 = (const char*)(Wt + (size_t)rowA * 192) + kt * 64 + colb;
    const char* bS1 = (const char*)(Wt + (size_t)(rowA + 64) * 192) + kt * 64 + colb;
    gload16(aS0, asD0);
    gload16(aS1, asD1);
    gload16(bS0, bsD0);
    gload16(bS1, bsD1);
    __syncthreads();
    bf16x8 af[4], bfr[4];
#pragma unroll
    for (int mi = 0; mi < 4; ++mi)
      af[mi] = *(const bf16x8*)((const char*)As +
               ((wr * 64 + mi * 16 + (lane & 15)) * 64 + (lane >> 4) * 16));
#pragma unroll
    for (int ni = 0; ni < 4; ++ni)
      bfr[ni] = *(const bf16x8*)((const char*)Bs +
               ((wc * 64 + ni * 16 + (lane & 15)) * 64 + (lane >> 4) * 16));
#pragma unroll
    for (int mi = 0; mi < 4; ++mi)
#pragma unroll
      for (int ni = 0; ni < 4; ++ni)
        acc[mi][ni] = __builtin_amdgcn_mfma_f32_16x16x32_bf16(af[mi], bfr[ni],
                                                              acc[mi][ni], 0, 0, 0);
    __syncthreads();
  }

  const float wp = *wpre, wa = *wadp;
  const float s = 2.f * wp + wa;
  const int crow = (lane >> 4) * 4;
  const int ccol = lane & 15;
#pragma unroll
  for (int mi = 0; mi < 4; ++mi)
#pragma unroll
    for (int ni = 0; ni < 4; ++ni) {
      int r0 = m0 + wr * 64 + mi * 16 + crow;
      int col = wc * 64 + ni * 16 + ccol;
      int cf = col & 63;
#pragma unroll
      for (int r = 0; r < 4; ++r) {
        int row = r0 + r;
        float g = acc[mi][ni][r];
        if (MODE == 0) {
          if (col < 64) {
            g += s * b0[cf];
            zbuf[(size_t)row * 64 + cf] = 1.f / (1.f + __expf(-g));
          } else {
            g += s * b1[cf];
            float rv = 1.f / (1.f + __expf(-g));
            rxout[(size_t)row * 64 + cf] = (__bf16)(rv * hid[(size_t)row * 64 + cf]);
          }
        } else {
          if (col < 64) {
            g += s * b0[cf];
            float cv = 1.f - 2.f / (1.f + __expf(2.f * g));
            float zv = zbuf[(size_t)row * 64 + cf];
            float hv = hid[(size_t)row * 64 + cf];
            outp[(size_t)row * 64 + cf] = (1.f - zv) * hv + zv * cv;
          }
        }
      }
    }
}

// ---------------------------------------------------------------------------
extern "C" void kernel_launch(void* const* d_in, const int* in_sizes, int n_in,
                              void* d_out, int out_size, void* d_ws, size_t ws_size,
                              hipStream_t stream) {
  (void)in_sizes; (void)n_in; (void)out_size;
  const float* x    = (const float*)d_in[0];
  const float* A1   = (const float*)d_in[1];
  const float* A2   = (const float*)d_in[2];
  const float* E1   = (const float*)d_in[3];
  const float* E2   = (const float*)d_in[4];
  const float* Wz   = (const float*)d_in[5];
  const float* bz   = (const float*)d_in[6];
  const float* Wr   = (const float*)d_in[7];
  const float* br   = (const float*)d_in[8];
  const float* Wc   = (const float*)d_in[9];
  const float* bc   = (const float*)d_in[10];
  const float* wpre = (const float*)d_in[11];
  const float* wadp = (const float*)d_in[12];
  float* out = (float*)d_out;

  char* ws = (char*)d_ws;
  const size_t NN2 = (size_t)NNODE * NNODE;  // 4,194,304 (= B*N*D too)
  __bf16* ADJ  = (__bf16*)(ws);                    // 6*NN2 bf16
  __bf16* XT   = (__bf16*)(ws + 6  * NN2 * 2);     // NN2
  __bf16* H1   = (__bf16*)(ws + 7  * NN2 * 2);     // 6*NN2
  __bf16* H2   = (__bf16*)(ws + 13 * NN2 * 2);     // 6*NN2
  __bf16* xbf  = (__bf16*)(ws + 19 * NN2 * 2);     // NN2
  __bf16* rx   = (__bf16*)(ws + 20 * NN2 * 2);     // NN2
  __bf16* S1   = (__bf16*)(ws + 21 * NN2 * 2);     // NN2
  __bf16* S2   = (__bf16*)(ws + 22 * NN2 * 2);     // NN2
  float*  zbuf = (float*)(ws + 23 * NN2 * 2);      // NN2 f32
  __bf16* Wzrt = (__bf16*)(ws + 23 * NN2 * 2 + NN2 * 4);
  __bf16* Wct  = (__bf16*)(ws + 23 * NN2 * 2 + NN2 * 4 + 128 * 192 * 2);
  if (ws_size < 23 * NN2 * 2 + NN2 * 4 + 2 * 128 * 192 * 2) return;

  // scratch reuse: SC lives in the (not-yet-used) H1 region, E1p/E2p in H2.
  __bf16* SC  = H1;                      // 4*NN2 bf16 scores
  __bf16* E1p = H2;                      // 4*2048*32 bf16
  __bf16* E2p = H2 + 4 * NNODE * 32;

  conv_bf16<<<4096, 256, 0, stream>>>(A1, ADJ);
  conv_bf16<<<4096, 256, 0, stream>>>(A2, ADJ + NN2);
  prep_e<<<128, 256, 0, stream>>>(E1, E2, E1p, E2p);
  score_gemm<<<dim3(16, 16, 4), 256, 0, stream>>>(E1p, E2p, SC);
  softmax_rows<<<2048, 256, 0, stream>>>(SC, ADJ + 2 * NN2);
  prep_w<<<96, 256, 0, stream>>>(Wz, Wr, Wc, wpre, wadp, Wzrt, Wct);
  transpose_x<<<dim3(32, 32), 256, 0, stream>>>(x, XT, xbf);

  // stage 1: hops on x (shared by z and r gates)
  gemm_hop8<<<dim3(8, 8, 6), 512, 131072, stream>>>(XT, 0, ADJ, H1);
  gemm_hop8<<<dim3(8, 8, 6), 512, 131072, stream>>>(H1, NN2, ADJ, H2);
  combine_s<<<dim3(32, 32), 256, 0, stream>>>(H1, H2, S1, S2, wpre, wadp);
  gemm_lin<0><<<512, 256, 0, stream>>>(xbf, S1, S2, Wzrt, bz, br, wpre, wadp,
                                       x, zbuf, rx, nullptr);

  // stage 2: hops on r*x
  transpose_rx<<<dim3(32, 32), 256, 0, stream>>>(rx, XT);
  gemm_hop8<<<dim3(8, 8, 6), 512, 131072, stream>>>(XT, 0, ADJ, H1);
  gemm_hop8<<<dim3(8, 8, 6), 512, 131072, stream>>>(H1, NN2, ADJ, H2);
  combine_s<<<dim3(32, 32), 256, 0, stream>>>(H1, H2, S1, S2, wpre, wadp);
  gemm_lin<1><<<512, 256, 0, stream>>>(rx, S1, S2, Wct, bc, nullptr, wpre, wadp,
                                       x, zbuf, nullptr, out);
}

// Round 5
// 365.425 us; speedup vs baseline: 1.8082x; 1.6067x over previous
//
#include <hip/hip_runtime.h>

#define NNODE 2048
#define NBATCH 32

typedef __attribute__((ext_vector_type(4))) float f32x4;
typedef __attribute__((ext_vector_type(8))) __bf16 bf16x8;

__device__ __forceinline__ void gload16(const void* g, void* lds) {
  __builtin_amdgcn_global_load_lds(
      (const __attribute__((address_space(1))) unsigned int*)g,
      (__attribute__((address_space(3))) unsigned int*)lds, 16, 0, 0);
}

// ---------------------------------------------------------------------------
// Convert f32 -> bf16 (4 elems/thread, exact grid)
__global__ __launch_bounds__(256) void conv_bf16(const float* __restrict__ in,
                                                 __bf16* __restrict__ outp) {
  int i = blockIdx.x * 256 + threadIdx.x;
  float4 q = ((const float4*)in)[i];
  outp[4 * (size_t)i + 0] = (__bf16)q.x;
  outp[4 * (size_t)i + 1] = (__bf16)q.y;
  outp[4 * (size_t)i + 2] = (__bf16)q.z;
  outp[4 * (size_t)i + 3] = (__bf16)q.w;
}

// ---------------------------------------------------------------------------
// Repack E1,E2 [N,H,16] f32 -> [H][N][32] bf16 (K zero-padded 16->32)
__global__ __launch_bounds__(256) void prep_e(const float* __restrict__ E1,
                                              const float* __restrict__ E2,
                                              __bf16* __restrict__ E1p,
                                              __bf16* __restrict__ E2p) {
  int idx = blockIdx.x * 256 + threadIdx.x;  // 0..32767
  int cq = idx & 3;
  int n = (idx >> 2) & 2047;
  int h = idx >> 13;
  const float4 q1 = *(const float4*)(E1 + (size_t)(n * 4 + h) * 16 + cq * 4);
  const float4 q2 = *(const float4*)(E2 + (size_t)(n * 4 + h) * 16 + cq * 4);
  size_t o = ((size_t)h * NNODE + n) * 32 + cq * 4;
  E1p[o + 0] = (__bf16)q1.x; E1p[o + 1] = (__bf16)q1.y;
  E1p[o + 2] = (__bf16)q1.z; E1p[o + 3] = (__bf16)q1.w;
  E2p[o + 0] = (__bf16)q2.x; E2p[o + 1] = (__bf16)q2.y;
  E2p[o + 2] = (__bf16)q2.z; E2p[o + 3] = (__bf16)q2.w;
  size_t oz = o + 16;
  E1p[oz + 0] = (__bf16)0.f; E1p[oz + 1] = (__bf16)0.f;
  E1p[oz + 2] = (__bf16)0.f; E1p[oz + 3] = (__bf16)0.f;
  E2p[oz + 0] = (__bf16)0.f; E2p[oz + 1] = (__bf16)0.f;
  E2p[oz + 2] = (__bf16)0.f; E2p[oz + 3] = (__bf16)0.f;
}

// ---------------------------------------------------------------------------
// SC[h][w][v] = relu(E1p_h @ E2p_h^T)/4, bf16. Single K=32 MFMA step.
__global__ __launch_bounds__(256) void score_gemm(const __bf16* __restrict__ E1p,
                                                  const __bf16* __restrict__ E2p,
                                                  __bf16* __restrict__ SC) {
  __shared__ __bf16 As[128 * 32];
  __shared__ __bf16 Bs[128 * 32];
  const int tid = threadIdx.x;
  const int wave = tid >> 6, lane = tid & 63;
  const int wr = wave >> 1, wc = wave & 1;
  const int h = blockIdx.z;
  const int m0 = blockIdx.x * 128, n0 = blockIdx.y * 128;
  const __bf16* A = E1p + (size_t)h * NNODE * 32;
  const __bf16* Bt = E2p + (size_t)h * NNODE * 32;
  const int rowA = tid >> 2;
  const int colb = (tid & 3) * 16;
  gload16((const char*)(A + (size_t)(m0 + rowA) * 32) + colb, (char*)As + wave * 1024);
  gload16((const char*)(A + (size_t)(m0 + rowA + 64) * 32) + colb, (char*)As + 4096 + wave * 1024);
  gload16((const char*)(Bt + (size_t)(n0 + rowA) * 32) + colb, (char*)Bs + wave * 1024);
  gload16((const char*)(Bt + (size_t)(n0 + rowA + 64) * 32) + colb, (char*)Bs + 4096 + wave * 1024);
  __syncthreads();

  f32x4 acc[4][4] = {};
  bf16x8 af[4], bfr[4];
#pragma unroll
  for (int mi = 0; mi < 4; ++mi)
    af[mi] = *(const bf16x8*)((const char*)As +
             ((wr * 64 + mi * 16 + (lane & 15)) * 64 + (lane >> 4) * 16));
#pragma unroll
  for (int ni = 0; ni < 4; ++ni)
    bfr[ni] = *(const bf16x8*)((const char*)Bs +
             ((wc * 64 + ni * 16 + (lane & 15)) * 64 + (lane >> 4) * 16));
#pragma unroll
  for (int mi = 0; mi < 4; ++mi)
#pragma unroll
    for (int ni = 0; ni < 4; ++ni)
      acc[mi][ni] = __builtin_amdgcn_mfma_f32_16x16x32_bf16(af[mi], bfr[ni],
                                                            acc[mi][ni], 0, 0, 0);

  const int crow = (lane >> 4) * 4;
  const int ccol = lane & 15;
#pragma unroll
  for (int mi = 0; mi < 4; ++mi)
#pragma unroll
    for (int ni = 0; ni < 4; ++ni) {
      int r0 = m0 + wr * 64 + mi * 16 + crow;
      int cc = n0 + wc * 64 + ni * 16 + ccol;
#pragma unroll
      for (int r = 0; r < 4; ++r) {
        float val = fmaxf(acc[mi][ni][r], 0.f) * 0.25f;
        SC[((size_t)h * NNODE + r0 + r) * NNODE + cc] = (__bf16)val;
      }
    }
}

// ---------------------------------------------------------------------------
// Row softmax over v: one wave per row of SC [8192 x 2048] bf16 -> adjh bf16
__global__ __launch_bounds__(256) void softmax_rows(const __bf16* __restrict__ SC,
                                                    __bf16* __restrict__ adjh) {
  const int tid = threadIdx.x;
  const int wave = tid >> 6, lane = tid & 63;
  const size_t row = (size_t)blockIdx.x * 4 + wave;
  const __bf16* src = SC + row * NNODE;
  __bf16* dst = adjh + row * NNODE;
  float v[32];
  float mx = 0.f;
#pragma unroll
  for (int j = 0; j < 4; ++j) {
    bf16x8 q = *(const bf16x8*)(src + j * 512 + lane * 8);
#pragma unroll
    for (int i = 0; i < 8; ++i) {
      float f = (float)q[i];
      v[j * 8 + i] = f;
      mx = fmaxf(mx, f);
    }
  }
#pragma unroll
  for (int o = 32; o > 0; o >>= 1) mx = fmaxf(mx, __shfl_xor(mx, o));
  float s = 0.f;
#pragma unroll
  for (int i = 0; i < 32; ++i) {
    v[i] = __expf(v[i] - mx);
    s += v[i];
  }
#pragma unroll
  for (int o = 32; o > 0; o >>= 1) s += __shfl_xor(s, o);
  float inv = 1.f / s;
#pragma unroll
  for (int j = 0; j < 4; ++j) {
    bf16x8 q;
#pragma unroll
    for (int i = 0; i < 8; ++i) q[i] = (__bf16)(v[j * 8 + i] * inv);
    *(bf16x8*)(dst + j * 512 + lane * 8) = q;
  }
}

// ---------------------------------------------------------------------------
// bf16 transpose per z-slice: dst[z][c][r] = src[z][r][c], 64x64 tiles
__global__ __launch_bounds__(256) void transpose_b(const __bf16* __restrict__ src,
                                                   __bf16* __restrict__ dst) {
  const int z = blockIdx.z;
  const int r0 = blockIdx.x * 64, c0 = blockIdx.y * 64;
  const int tid = threadIdx.x;
  const size_t NN2 = (size_t)NNODE * NNODE;
  __shared__ float t[64][65];
  const int vr = tid >> 2, cg = (tid & 3) * 16;
  const __bf16* p = src + (size_t)z * NN2 + (size_t)(r0 + vr) * NNODE + c0 + cg;
  bf16x8 q0 = ((const bf16x8*)p)[0];
  bf16x8 q1 = ((const bf16x8*)p)[1];
#pragma unroll
  for (int i = 0; i < 8; ++i) {
    t[vr][cg + i] = (float)q0[i];
    t[vr][cg + 8 + i] = (float)q1[i];
  }
  __syncthreads();
#pragma unroll
  for (int jr = 0; jr < 16; ++jr) {
    int c = jr * 4 + (tid >> 6);
    int v = tid & 63;
    dst[(size_t)z * NN2 + (size_t)(c0 + c) * NNODE + r0 + v] = (__bf16)t[v][c];
  }
}

// ---------------------------------------------------------------------------
// dst[i] = wp*(s0+s1)[i] + (wadp/4)*(s2+s3+s4+s5)[i], slices at src + z*NN2
__global__ __launch_bounds__(256) void wsum6(const __bf16* __restrict__ src,
                                             __bf16* __restrict__ dst,
                                             const float* __restrict__ wpre,
                                             const float* __restrict__ wadp) {
  const size_t NN2 = (size_t)NNODE * NNODE;
  size_t i = ((size_t)blockIdx.x * 256 + threadIdx.x) * 8;
  const float wp = *wpre, wa = *wadp * 0.25f;
  bf16x8 a0 = *(const bf16x8*)(src + i);
  bf16x8 a1 = *(const bf16x8*)(src + NN2 + i);
  bf16x8 a2 = *(const bf16x8*)(src + 2 * NN2 + i);
  bf16x8 a3 = *(const bf16x8*)(src + 3 * NN2 + i);
  bf16x8 a4 = *(const bf16x8*)(src + 4 * NN2 + i);
  bf16x8 a5 = *(const bf16x8*)(src + 5 * NN2 + i);
  bf16x8 o;
#pragma unroll
  for (int j = 0; j < 8; ++j) {
    float v = wp * ((float)a0[j] + (float)a1[j]) +
              wa * ((float)a2[j] + (float)a3[j] + (float)a4[j] + (float)a5[j]);
    o[j] = (__bf16)v;
  }
  *(bf16x8*)(dst + i) = o;
}

// ---------------------------------------------------------------------------
// Wzrt[c][k]=Wz[k][c]*(k<64?s:1); Wzrt[64+c][k]=Wr[k][c]*...; Wct rows 64..127 = 0
__global__ __launch_bounds__(256) void prep_w(const float* __restrict__ Wz,
                                              const float* __restrict__ Wr,
                                              const float* __restrict__ Wc,
                                              const float* __restrict__ wpre,
                                              const float* __restrict__ wadp,
                                              __bf16* __restrict__ Wzrt,
                                              __bf16* __restrict__ Wct) {
  int idx = blockIdx.x * 256 + threadIdx.x;  // 0 .. 128*192-1
  int rr = idx / 192, k = idx % 192;
  float s = 2.f * (*wpre) + (*wadp);
  float sc = (k < 64) ? s : 1.f;
  float vz = (rr < 64) ? Wz[(size_t)k * 64 + rr] : Wr[(size_t)k * 64 + rr - 64];
  Wzrt[idx] = (__bf16)(vz * sc);
  float vc = (rr < 64) ? Wc[(size_t)k * 64 + rr] * sc : 0.f;
  Wct[idx] = (__bf16)vc;
}

// ---------------------------------------------------------------------------
// x f32 [B,N,64] -> XT bf16 [B*64, N] (XT[b*64+c][v]=x[b,v,c]) and xbf bf16 [B*N,64]
__global__ __launch_bounds__(256) void transpose_x(const float* __restrict__ x,
                                                   __bf16* __restrict__ XT,
                                                   __bf16* __restrict__ xbf) {
  const int b = blockIdx.y, v0 = blockIdx.x * 64;
  const int tid = threadIdx.x;
  __shared__ float t[64][65];
  const int vr = tid >> 2, c0 = (tid & 3) * 16;
  const float* src = x + ((size_t)b * NNODE + v0 + vr) * 64 + c0;
  __bf16* xb = xbf + ((size_t)b * NNODE + v0 + vr) * 64 + c0;
#pragma unroll
  for (int j = 0; j < 4; ++j) {
    float4 q = ((const float4*)src)[j];
    t[vr][c0 + j * 4 + 0] = q.x;
    t[vr][c0 + j * 4 + 1] = q.y;
    t[vr][c0 + j * 4 + 2] = q.z;
    t[vr][c0 + j * 4 + 3] = q.w;
    xb[j * 4 + 0] = (__bf16)q.x;
    xb[j * 4 + 1] = (__bf16)q.y;
    xb[j * 4 + 2] = (__bf16)q.z;
    xb[j * 4 + 3] = (__bf16)q.w;
  }
  __syncthreads();
#pragma unroll
  for (int jr = 0; jr < 16; ++jr) {
    int c = jr * 4 + (tid >> 6);
    int v = tid & 63;
    XT[((size_t)b * 64 + c) * NNODE + v0 + v] = (__bf16)t[v][c];
  }
}

// rx bf16 [B*N,64] -> XT bf16 [B*64, N]
__global__ __launch_bounds__(256) void transpose_rx(const __bf16* __restrict__ rx,
                                                    __bf16* __restrict__ XT) {
  const int b = blockIdx.y, v0 = blockIdx.x * 64;
  const int tid = threadIdx.x;
  __shared__ float t[64][65];
  const int vr = tid >> 2, c0 = (tid & 3) * 16;
  const __bf16* src = rx + ((size_t)b * NNODE + v0 + vr) * 64 + c0;
  bf16x8 q0 = ((const bf16x8*)src)[0];
  bf16x8 q1 = ((const bf16x8*)src)[1];
#pragma unroll
  for (int i = 0; i < 8; ++i) {
    t[vr][c0 + i] = (float)q0[i];
    t[vr][c0 + 8 + i] = (float)q1[i];
  }
  __syncthreads();
#pragma unroll
  for (int jr = 0; jr < 16; ++jr) {
    int c = jr * 4 + (tid >> 6);
    int v = tid & 63;
    XT[((size_t)b * 64 + c) * NNODE + v0 + v] = (__bf16)t[v][c];
  }
}

// ---------------------------------------------------------------------------
// 8-phase 256x256 GEMM, batched over z. 3-bit XOR swizzle (verified R4:
// bank-conflicts == 0). C_z[m][n] = sum_k A_z[m][k] * Bt_z[n][k].
#define VMCNT4() asm volatile("s_waitcnt vmcnt(4)" ::: "memory")
#define BARRIER() asm volatile("s_barrier" ::: "memory")

__global__ __launch_bounds__(512, 2) void gemm_hop8(const __bf16* __restrict__ Abase,
                                                    size_t aStrideZ,
                                                    const __bf16* __restrict__ BtBase,
                                                    __bf16* __restrict__ Cbase) {
  extern __shared__ char smem[];  // 131072 B
  const int tid = threadIdx.x;
  const int w = tid >> 6, l = tid & 63;
  const int wr = w >> 2, wc = w & 3;  // 2 M-waves x 4 N-waves
  const size_t z = blockIdx.z;
  const int m0 = blockIdx.x * 256, n0 = blockIdx.y * 256;
  const __bf16* A = Abase + z * aStrideZ;
  const __bf16* Bt = BtBase + z * (size_t)(NNODE * NNODE);
  __bf16* C = Cbase + z * (size_t)(NNODE * NNODE);
  const int NT = NNODE / 64;  // 32 K-tiles

  // swizzled read offsets within a 16 KiB half-region ([128 rows][128 B])
  int aoff[4][2], boff[2][2];
#pragma unroll
  for (int m = 0; m < 4; ++m)
#pragma unroll
    for (int ks = 0; ks < 2; ++ks) {
      int rh = m * 32 + wr * 16 + (l & 15);
      int lo = rh * 128 + ks * 64 + ((l >> 4) * 16);
      aoff[m][ks] = lo ^ ((rh & 7) << 4);
    }
#pragma unroll
  for (int n = 0; n < 2; ++n)
#pragma unroll
    for (int ks = 0; ks < 2; ++ks) {
      int rh = n * 64 + wc * 16 + (l & 15);
      int lo = rh * 128 + ks * 64 + ((l >> 4) * 16);
      boff[n][ks] = lo ^ ((rh & 7) << 4);
    }

  // staging: LDS dest linear; inverse-swizzled global source column
  const int sg_row[2] = {w * 8 + (l >> 3), 64 + w * 8 + (l >> 3)};
  const int sg_col = (((l & 7) ^ ((l >> 3) & 7)) << 4);

#define STAGE(gbase, row0, kt, region)                                        \
  do {                                                                        \
    const char* _g0 = (const char*)(gbase) +                                  \
        (size_t)((row0) + sg_row[0]) * 4096 + (size_t)(kt) * 128 + sg_col;    \
    const char* _g1 = (const char*)(gbase) +                                  \
        (size_t)((row0) + sg_row[1]) * 4096 + (size_t)(kt) * 128 + sg_col;    \
    gload16(_g0, (region) + w * 1024);                                        \
    gload16(_g1, (region) + 8192 + w * 1024);                                 \
  } while (0)

#define AREG(d, h) (smem + (d) * 32768 + (h) * 16384)
#define BREG(d, h) (smem + 65536 + (d) * 32768 + (h) * 16384)

  f32x4 acc[8][4] = {};
  bf16x8 af[4][2], bf[2][2];

  // ---- prologue: tile0 {A0,B0,B1,A1}, tile1 {A0,B0}
  STAGE(A, m0, 0, AREG(0, 0));
  STAGE(Bt, n0, 0, BREG(0, 0));
  STAGE(Bt, n0 + 128, 0, BREG(0, 1));
  STAGE(A, m0 + 128, 0, AREG(0, 1));
  STAGE(A, m0, 1, AREG(1, 0));
  STAGE(Bt, n0, 1, BREG(1, 0));
  VMCNT4();
  BARRIER();

  for (int t = 0; t < NT; ++t) {
    const int d = t & 1;
    // ---------- phase 1: quadrant (A-half0, B-half0); stage (t+1).B1
#pragma unroll
    for (int m = 0; m < 4; ++m) {
      af[m][0] = *(const bf16x8*)(AREG(d, 0) + aoff[m][0]);
      af[m][1] = *(const bf16x8*)(AREG(d, 0) + aoff[m][1]);
    }
#pragma unroll
    for (int n = 0; n < 2; ++n) {
      bf[n][0] = *(const bf16x8*)(BREG(d, 0) + boff[n][0]);
      bf[n][1] = *(const bf16x8*)(BREG(d, 0) + boff[n][1]);
    }
    if (t + 1 < NT) STAGE(Bt, n0 + 128, t + 1, BREG(d ^ 1, 1));
    BARRIER();
    __builtin_amdgcn_s_setprio(1);
#pragma unroll
    for (int m = 0; m < 4; ++m)
#pragma unroll
      for (int n = 0; n < 2; ++n)
#pragma unroll
        for (int ks = 0; ks < 2; ++ks)
          acc[m][n] = __builtin_amdgcn_mfma_f32_16x16x32_bf16(af[m][ks], bf[n][ks],
                                                              acc[m][n], 0, 0, 0);
    __builtin_amdgcn_s_setprio(0);
    BARRIER();

    // ---------- phase 2: quadrant (A-half0, B-half1); stage (t+1).A1
#pragma unroll
    for (int n = 0; n < 2; ++n) {
      bf[n][0] = *(const bf16x8*)(BREG(d, 1) + boff[n][0]);
      bf[n][1] = *(const bf16x8*)(BREG(d, 1) + boff[n][1]);
    }
    if (t + 1 < NT) STAGE(A, m0 + 128, t + 1, AREG(d ^ 1, 1));
    BARRIER();
    __builtin_amdgcn_s_setprio(1);
#pragma unroll
    for (int m = 0; m < 4; ++m)
#pragma unroll
      for (int n = 0; n < 2; ++n)
#pragma unroll
        for (int ks = 0; ks < 2; ++ks)
          acc[m][n + 2] = __builtin_amdgcn_mfma_f32_16x16x32_bf16(af[m][ks], bf[n][ks],
                                                                  acc[m][n + 2], 0, 0, 0);
    __builtin_amdgcn_s_setprio(0);
    BARRIER();

    // ---------- phase 3: quadrant (A-half1, B-half0); stage (t+2).A0
#pragma unroll
    for (int m = 0; m < 4; ++m) {
      af[m][0] = *(const bf16x8*)(AREG(d, 1) + aoff[m][0]);
      af[m][1] = *(const bf16x8*)(AREG(d, 1) + aoff[m][1]);
    }
#pragma unroll
    for (int n = 0; n < 2; ++n) {
      bf[n][0] = *(const bf16x8*)(BREG(d, 0) + boff[n][0]);
      bf[n][1] = *(const bf16x8*)(BREG(d, 0) + boff[n][1]);
    }
    if (t + 2 < NT) STAGE(A, m0, t + 2, AREG(d, 0));
    BARRIER();
    __builtin_amdgcn_s_setprio(1);
#pragma unroll
    for (int m = 0; m < 4; ++m)
#pragma unroll
      for (int n = 0; n < 2; ++n)
#pragma unroll
        for (int ks = 0; ks < 2; ++ks)
          acc[m + 4][n] = __builtin_amdgcn_mfma_f32_16x16x32_bf16(af[m][ks], bf[n][ks],
                                                                  acc[m + 4][n], 0, 0, 0);
    __builtin_amdgcn_s_setprio(0);
    BARRIER();

    // ---------- phase 4: quadrant (A-half1, B-half1); stage (t+2).B0; vmcnt
#pragma unroll
    for (int n = 0; n < 2; ++n) {
      bf[n][0] = *(const bf16x8*)(BREG(d, 1) + boff[n][0]);
      bf[n][1] = *(const bf16x8*)(BREG(d, 1) + boff[n][1]);
    }
    if (t + 2 < NT) STAGE(Bt, n0, t + 2, BREG(d, 0));
    VMCNT4();
    BARRIER();
    __builtin_amdgcn_s_setprio(1);
#pragma unroll
    for (int m = 0; m < 4; ++m)
#pragma unroll
      for (int n = 0; n < 2; ++n)
#pragma unroll
        for (int ks = 0; ks < 2; ++ks)
          acc[m + 4][n + 2] = __builtin_amdgcn_mfma_f32_16x16x32_bf16(af[m][ks], bf[n][ks],
                                                                      acc[m + 4][n + 2], 0, 0, 0);
    __builtin_amdgcn_s_setprio(0);
    BARRIER();
  }

  // ---- epilogue: C write
  const int crow = (l >> 4) * 4;
  const int ccol = l & 15;
#pragma unroll
  for (int mi = 0; mi < 8; ++mi)
#pragma unroll
    for (int ni = 0; ni < 4; ++ni) {
      int r0 = m0 + (mi >> 2) * 128 + (mi & 3) * 32 + wr * 16 + crow;
      int cc = n0 + (ni >> 1) * 128 + (ni & 1) * 64 + wc * 16 + ccol;
#pragma unroll
      for (int r = 0; r < 4; ++r)
        C[(size_t)(r0 + r) * NNODE + cc] = (__bf16)acc[mi][ni][r];
    }
#undef STAGE
#undef AREG
#undef BREG
}

// ---------------------------------------------------------------------------
// S1[(b,w),c] = HH[0][b*64+c][w] ; S2[(b,w),c] = HH[1][b*64+c][w]
__global__ __launch_bounds__(256) void combine2(const __bf16* __restrict__ HH,
                                                __bf16* __restrict__ S1,
                                                __bf16* __restrict__ S2) {
  const int b = blockIdx.y;
  const int w0 = blockIdx.x * 64;
  const int tid = threadIdx.x;
  const size_t NN2 = (size_t)NNODE * NNODE;
  __shared__ float t1[64][65];
  __shared__ float t2[64][65];
  const int cr = tid >> 2;
  const int wg = (tid & 3) * 16;
  const __bf16* p1 = HH + (size_t)(b * 64 + cr) * NNODE + w0 + wg;
  const __bf16* p2 = HH + NN2 + (size_t)(b * 64 + cr) * NNODE + w0 + wg;
  bf16x8 q10 = ((const bf16x8*)p1)[0], q11 = ((const bf16x8*)p1)[1];
  bf16x8 q20 = ((const bf16x8*)p2)[0], q21 = ((const bf16x8*)p2)[1];
#pragma unroll
  for (int i = 0; i < 8; ++i) {
    t1[cr][wg + i] = (float)q10[i];
    t1[cr][wg + 8 + i] = (float)q11[i];
    t2[cr][wg + i] = (float)q20[i];
    t2[cr][wg + 8 + i] = (float)q21[i];
  }
  __syncthreads();
#pragma unroll
  for (int jr = 0; jr < 16; ++jr) {
    int wl = jr * 4 + (tid >> 6);
    int c = tid & 63;
    size_t o = ((size_t)b * NNODE + w0 + wl) * 64 + c;
    S1[o] = (__bf16)t1[c][wl];
    S2[o] = (__bf16)t2[c][wl];
  }
}

// ---------------------------------------------------------------------------
// Gate linear GEMM: [65536 x 192] @ Wt^T, K=192, N=128, fused epilogues.
// MODE 0: cols 0-63 -> z=sigmoid -> zbuf(f32); cols 64-127 -> r -> rx=(bf16)(r*hid)
// MODE 1: cols 0-63 -> c=tanh   -> out=(1-z)*hid+z*c (f32)
template <int MODE>
__global__ __launch_bounds__(256) void gemm_lin(const __bf16* __restrict__ Xp,
                                                const __bf16* __restrict__ S1,
                                                const __bf16* __restrict__ S2,
                                                const __bf16* __restrict__ Wt,
                                                const float* __restrict__ b0,
                                                const float* __restrict__ b1,
                                                const float* __restrict__ wpre,
                                                const float* __restrict__ wadp,
                                                const float* __restrict__ hid,
                                                float* __restrict__ zbuf,
                                                __bf16* __restrict__ rxout,
                                                float* __restrict__ outp) {
  __shared__ __bf16 As[128 * 32];
  __shared__ __bf16 Bs[128 * 32];
  const int tid = threadIdx.x;
  const int wave = tid >> 6, lane = tid & 63;
  const int wr = wave >> 1, wc = wave & 1;
  const int m0 = blockIdx.x * 128;
  const int rowA = tid >> 2;
  const int colb = (tid & 3) * 16;
  const __bf16* srcs[3] = {Xp, S1, S2};
  char* asD0 = (char*)As + wave * 1024;
  char* asD1 = (char*)As + 4096 + wave * 1024;
  char* bsD0 = (char*)Bs + wave * 1024;
  char* bsD1 = (char*)Bs + 4096 + wave * 1024;

  f32x4 acc[4][4] = {};

#pragma unroll
  for (int kt = 0; kt < 6; ++kt) {
    const __bf16* Ab = srcs[kt >> 1];
    const char* aS0 = (const char*)(Ab + (size_t)(m0 + rowA) * 64) + (kt & 1) * 64 + colb;
    const char* aS1 = (const char*)(Ab + (size_t)(m0 + rowA + 64) * 64) + (kt & 1) * 64 + colb;
    const char* bS0 = (const char*)(Wt + (size_t)rowA * 192) + kt * 64 + colb;
    const char* bS1 = (const char*)(Wt + (size_t)(rowA + 64) * 192) + kt * 64 + colb;
    gload16(aS0, asD0);
    gload16(aS1, asD1);
    gload16(bS0, bsD0);
    gload16(bS1, bsD1);
    __syncthreads();
    bf16x8 af[4], bfr[4];
#pragma unroll
    for (int mi = 0; mi < 4; ++mi)
      af[mi] = *(const bf16x8*)((const char*)As +
               ((wr * 64 + mi * 16 + (lane & 15)) * 64 + (lane >> 4) * 16));
#pragma unroll
    for (int ni = 0; ni < 4; ++ni)
      bfr[ni] = *(const bf16x8*)((const char*)Bs +
               ((wc * 64 + ni * 16 + (lane & 15)) * 64 + (lane >> 4) * 16));
#pragma unroll
    for (int mi = 0; mi < 4; ++mi)
#pragma unroll
      for (int ni = 0; ni < 4; ++ni)
        acc[mi][ni] = __builtin_amdgcn_mfma_f32_16x16x32_bf16(af[mi], bfr[ni],
                                                              acc[mi][ni], 0, 0, 0);
    __syncthreads();
  }

  const float wp = *wpre, wa = *wadp;
  const float s = 2.f * wp + wa;
  const int crow = (lane >> 4) * 4;
  const int ccol = lane & 15;
#pragma unroll
  for (int mi = 0; mi < 4; ++mi)
#pragma unroll
    for (int ni = 0; ni < 4; ++ni) {
      int r0 = m0 + wr * 64 + mi * 16 + crow;
      int col = wc * 64 + ni * 16 + ccol;
      int cf = col & 63;
#pragma unroll
      for (int r = 0; r < 4; ++r) {
        int row = r0 + r;
        float g = acc[mi][ni][r];
        if (MODE == 0) {
          if (col < 64) {
            g += s * b0[cf];
            zbuf[(size_t)row * 64 + cf] = 1.f / (1.f + __expf(-g));
          } else {
            g += s * b1[cf];
            float rv = 1.f / (1.f + __expf(-g));
            rxout[(size_t)row * 64 + cf] = (__bf16)(rv * hid[(size_t)row * 64 + cf]);
          }
        } else {
          if (col < 64) {
            g += s * b0[cf];
            float cv = 1.f - 2.f / (1.f + __expf(2.f * g));
            float zv = zbuf[(size_t)row * 64 + cf];
            float hv = hid[(size_t)row * 64 + cf];
            outp[(size_t)row * 64 + cf] = (1.f - zv) * hv + zv * cv;
          }
        }
      }
    }
}

// ---------------------------------------------------------------------------
extern "C" void kernel_launch(void* const* d_in, const int* in_sizes, int n_in,
                              void* d_out, int out_size, void* d_ws, size_t ws_size,
                              hipStream_t stream) {
  (void)in_sizes; (void)n_in; (void)out_size;
  const float* x    = (const float*)d_in[0];
  const float* A1   = (const float*)d_in[1];
  const float* A2   = (const float*)d_in[2];
  const float* E1   = (const float*)d_in[3];
  const float* E2   = (const float*)d_in[4];
  const float* Wz   = (const float*)d_in[5];
  const float* bz   = (const float*)d_in[6];
  const float* Wr   = (const float*)d_in[7];
  const float* br   = (const float*)d_in[8];
  const float* Wc   = (const float*)d_in[9];
  const float* bc   = (const float*)d_in[10];
  const float* wpre = (const float*)d_in[11];
  const float* wadp = (const float*)d_in[12];
  float* out = (float*)d_out;

  char* ws = (char*)d_ws;
  const size_t NN2 = (size_t)NNODE * NNODE;  // 4,194,304 (= B*N*D too)
  const size_t NN2B = NN2 * 2;               // bytes per bf16 slice
  // R1 [0,6): ADJ[6] -> reused later as HH[2] @0, S1 @2, S2 @3, zbuf(f32) @4-5
  // R2 [6,12): ADJT[6]
  // R3 [12,18): SQ[6]   (SC scores use first 4 slices pre-square)
  // R4 [18,20): MM[2] = {M1, M2}
  // R5 [20,23): XT, xbf, rx
  __bf16* ADJ  = (__bf16*)(ws);
  __bf16* ADJT = (__bf16*)(ws + 6 * NN2B);
  __bf16* SQ   = (__bf16*)(ws + 12 * NN2B);
  __bf16* MM   = (__bf16*)(ws + 18 * NN2B);
  __bf16* XT   = (__bf16*)(ws + 20 * NN2B);
  __bf16* xbf  = (__bf16*)(ws + 21 * NN2B);
  __bf16* rx   = (__bf16*)(ws + 22 * NN2B);
  __bf16* HH   = (__bf16*)(ws);                 // over ADJ[0..1] (dead)
  __bf16* S1   = (__bf16*)(ws + 2 * NN2B);      // over ADJ[2]
  __bf16* S2   = (__bf16*)(ws + 3 * NN2B);      // over ADJ[3]
  float*  zbuf = (float*)(ws + 4 * NN2B);       // over ADJ[4..5]
  __bf16* E1p  = (__bf16*)(ws + 23 * NN2B);     // 4*2048*32
  __bf16* E2p  = E1p + 4 * NNODE * 32;
  __bf16* Wzrt = E2p + 4 * NNODE * 32;
  __bf16* Wct  = Wzrt + 128 * 192;
  if (ws_size < 23 * NN2B + 2 * 4 * NNODE * 32 * 2 + 2 * 128 * 192 * 2) return;

  __bf16* SC = SQ;  // scores live in SQ region until softmax consumes them

  // --- adjacency construction
  conv_bf16<<<4096, 256, 0, stream>>>(A1, ADJ);
  conv_bf16<<<4096, 256, 0, stream>>>(A2, ADJ + NN2);
  prep_e<<<128, 256, 0, stream>>>(E1, E2, E1p, E2p);
  score_gemm<<<dim3(16, 16, 4), 256, 0, stream>>>(E1p, E2p, SC);
  softmax_rows<<<2048, 256, 0, stream>>>(SC, ADJ + 2 * NN2);
  transpose_b<<<dim3(32, 32, 6), 256, 0, stream>>>(ADJ, ADJT);
  wsum6<<<2048, 256, 0, stream>>>(ADJ, MM, wpre, wadp);            // M1
  prep_w<<<96, 256, 0, stream>>>(Wz, Wr, Wc, wpre, wadp, Wzrt, Wct);
  transpose_x<<<dim3(32, 32), 256, 0, stream>>>(x, XT, xbf);

  // --- M2 = sum_z w_z * A_z^2  (6 squaring GEMMs, once)
  gemm_hop8<<<dim3(8, 8, 6), 512, 131072, stream>>>(ADJ, NN2, ADJT, SQ);
  wsum6<<<2048, 256, 0, stream>>>(SQ, MM + NN2, wpre, wadp);       // M2

  // --- stage 1: S1 = M1 x, S2 = M2 x  (z=2, single-round grid)
  gemm_hop8<<<dim3(8, 8, 2), 512, 131072, stream>>>(XT, 0, MM, HH);
  combine2<<<dim3(32, 32), 256, 0, stream>>>(HH, S1, S2);
  gemm_lin<0><<<512, 256, 0, stream>>>(xbf, S1, S2, Wzrt, bz, br, wpre, wadp,
                                       x, zbuf, rx, nullptr);

  // --- stage 2: hops on r*x
  transpose_rx<<<dim3(32, 32), 256, 0, stream>>>(rx, XT);
  gemm_hop8<<<dim3(8, 8, 2), 512, 131072, stream>>>(XT, 0, MM, HH);
  combine2<<<dim3(32, 32), 256, 0, stream>>>(HH, S1, S2);
  gemm_lin<1><<<512, 256, 0, stream>>>(rx, S1, S2, Wct, bc, nullptr, wpre, wadp,
                                       x, zbuf, nullptr, out);
}

// Round 6
// 330.175 us; speedup vs baseline: 2.0012x; 1.1068x over previous
//
#include <hip/hip_runtime.h>

#define NNODE 2048
#define NBATCH 32

typedef __attribute__((ext_vector_type(4))) float f32x4;
typedef __attribute__((ext_vector_type(8))) __bf16 bf16x8;

__device__ __forceinline__ void gload16(const void* g, void* lds) {
  __builtin_amdgcn_global_load_lds(
      (const __attribute__((address_space(1))) unsigned int*)g,
      (__attribute__((address_space(3))) unsigned int*)lds, 16, 0, 0);
}

// ---------------------------------------------------------------------------
// Convert f32 -> bf16 (4 elems/thread, exact grid)
__global__ __launch_bounds__(256) void conv_bf16(const float* __restrict__ in,
                                                 __bf16* __restrict__ outp) {
  int i = blockIdx.x * 256 + threadIdx.x;
  float4 q = ((const float4*)in)[i];
  outp[4 * (size_t)i + 0] = (__bf16)q.x;
  outp[4 * (size_t)i + 1] = (__bf16)q.y;
  outp[4 * (size_t)i + 2] = (__bf16)q.z;
  outp[4 * (size_t)i + 3] = (__bf16)q.w;
}

// ---------------------------------------------------------------------------
// Repack E1,E2 [N,H,16] f32 -> [H][N][32] bf16 (K zero-padded 16->32)
__global__ __launch_bounds__(256) void prep_e(const float* __restrict__ E1,
                                              const float* __restrict__ E2,
                                              __bf16* __restrict__ E1p,
                                              __bf16* __restrict__ E2p) {
  int idx = blockIdx.x * 256 + threadIdx.x;  // 0..32767
  int cq = idx & 3;
  int n = (idx >> 2) & 2047;
  int h = idx >> 13;
  const float4 q1 = *(const float4*)(E1 + (size_t)(n * 4 + h) * 16 + cq * 4);
  const float4 q2 = *(const float4*)(E2 + (size_t)(n * 4 + h) * 16 + cq * 4);
  size_t o = ((size_t)h * NNODE + n) * 32 + cq * 4;
  E1p[o + 0] = (__bf16)q1.x; E1p[o + 1] = (__bf16)q1.y;
  E1p[o + 2] = (__bf16)q1.z; E1p[o + 3] = (__bf16)q1.w;
  E2p[o + 0] = (__bf16)q2.x; E2p[o + 1] = (__bf16)q2.y;
  E2p[o + 2] = (__bf16)q2.z; E2p[o + 3] = (__bf16)q2.w;
  size_t oz = o + 16;
  E1p[oz + 0] = (__bf16)0.f; E1p[oz + 1] = (__bf16)0.f;
  E1p[oz + 2] = (__bf16)0.f; E1p[oz + 3] = (__bf16)0.f;
  E2p[oz + 0] = (__bf16)0.f; E2p[oz + 1] = (__bf16)0.f;
  E2p[oz + 2] = (__bf16)0.f; E2p[oz + 3] = (__bf16)0.f;
}

// ---------------------------------------------------------------------------
// SC[h][w][v] = relu(E1p_h @ E2p_h^T)/4, bf16. Single K=32 MFMA step.
__global__ __launch_bounds__(256) void score_gemm(const __bf16* __restrict__ E1p,
                                                  const __bf16* __restrict__ E2p,
                                                  __bf16* __restrict__ SC) {
  __shared__ __bf16 As[128 * 32];
  __shared__ __bf16 Bs[128 * 32];
  const int tid = threadIdx.x;
  const int wave = tid >> 6, lane = tid & 63;
  const int wr = wave >> 1, wc = wave & 1;
  const int h = blockIdx.z;
  const int m0 = blockIdx.x * 128, n0 = blockIdx.y * 128;
  const __bf16* A = E1p + (size_t)h * NNODE * 32;
  const __bf16* Bt = E2p + (size_t)h * NNODE * 32;
  const int rowA = tid >> 2;
  const int colb = (tid & 3) * 16;
  gload16((const char*)(A + (size_t)(m0 + rowA) * 32) + colb, (char*)As + wave * 1024);
  gload16((const char*)(A + (size_t)(m0 + rowA + 64) * 32) + colb, (char*)As + 4096 + wave * 1024);
  gload16((const char*)(Bt + (size_t)(n0 + rowA) * 32) + colb, (char*)Bs + wave * 1024);
  gload16((const char*)(Bt + (size_t)(n0 + rowA + 64) * 32) + colb, (char*)Bs + 4096 + wave * 1024);
  __syncthreads();

  f32x4 acc[4][4] = {};
  bf16x8 af[4], bfr[4];
#pragma unroll
  for (int mi = 0; mi < 4; ++mi)
    af[mi] = *(const bf16x8*)((const char*)As +
             ((wr * 64 + mi * 16 + (lane & 15)) * 64 + (lane >> 4) * 16));
#pragma unroll
  for (int ni = 0; ni < 4; ++ni)
    bfr[ni] = *(const bf16x8*)((const char*)Bs +
             ((wc * 64 + ni * 16 + (lane & 15)) * 64 + (lane >> 4) * 16));
#pragma unroll
  for (int mi = 0; mi < 4; ++mi)
#pragma unroll
    for (int ni = 0; ni < 4; ++ni)
      acc[mi][ni] = __builtin_amdgcn_mfma_f32_16x16x32_bf16(af[mi], bfr[ni],
                                                            acc[mi][ni], 0, 0, 0);

  const int crow = (lane >> 4) * 4;
  const int ccol = lane & 15;
#pragma unroll
  for (int mi = 0; mi < 4; ++mi)
#pragma unroll
    for (int ni = 0; ni < 4; ++ni) {
      int r0 = m0 + wr * 64 + mi * 16 + crow;
      int cc = n0 + wc * 64 + ni * 16 + ccol;
#pragma unroll
      for (int r = 0; r < 4; ++r) {
        float val = fmaxf(acc[mi][ni][r], 0.f) * 0.25f;
        SC[((size_t)h * NNODE + r0 + r) * NNODE + cc] = (__bf16)val;
      }
    }
}

// ---------------------------------------------------------------------------
// Row softmax over v: one wave per row of SC [8192 x 2048] bf16 -> adjh bf16
__global__ __launch_bounds__(256) void softmax_rows(const __bf16* __restrict__ SC,
                                                    __bf16* __restrict__ adjh) {
  const int tid = threadIdx.x;
  const int wave = tid >> 6, lane = tid & 63;
  const size_t row = (size_t)blockIdx.x * 4 + wave;
  const __bf16* src = SC + row * NNODE;
  __bf16* dst = adjh + row * NNODE;
  float v[32];
  float mx = 0.f;
#pragma unroll
  for (int j = 0; j < 4; ++j) {
    bf16x8 q = *(const bf16x8*)(src + j * 512 + lane * 8);
#pragma unroll
    for (int i = 0; i < 8; ++i) {
      float f = (float)q[i];
      v[j * 8 + i] = f;
      mx = fmaxf(mx, f);
    }
  }
#pragma unroll
  for (int o = 32; o > 0; o >>= 1) mx = fmaxf(mx, __shfl_xor(mx, o));
  float s = 0.f;
#pragma unroll
  for (int i = 0; i < 32; ++i) {
    v[i] = __expf(v[i] - mx);
    s += v[i];
  }
#pragma unroll
  for (int o = 32; o > 0; o >>= 1) s += __shfl_xor(s, o);
  float inv = 1.f / s;
#pragma unroll
  for (int j = 0; j < 4; ++j) {
    bf16x8 q;
#pragma unroll
    for (int i = 0; i < 8; ++i) q[i] = (__bf16)(v[j * 8 + i] * inv);
    *(bf16x8*)(dst + j * 512 + lane * 8) = q;
  }
}

// ---------------------------------------------------------------------------
// bf16 transpose per z-slice: dst[z][c][r] = src[z][r][c], 64x64 tiles
__global__ __launch_bounds__(256) void transpose_b(const __bf16* __restrict__ src,
                                                   __bf16* __restrict__ dst) {
  const int z = blockIdx.z;
  const int r0 = blockIdx.x * 64, c0 = blockIdx.y * 64;
  const int tid = threadIdx.x;
  const size_t NN2 = (size_t)NNODE * NNODE;
  __shared__ float t[64][65];
  const int vr = tid >> 2, cg = (tid & 3) * 16;
  const __bf16* p = src + (size_t)z * NN2 + (size_t)(r0 + vr) * NNODE + c0 + cg;
  bf16x8 q0 = ((const bf16x8*)p)[0];
  bf16x8 q1 = ((const bf16x8*)p)[1];
#pragma unroll
  for (int i = 0; i < 8; ++i) {
    t[vr][cg + i] = (float)q0[i];
    t[vr][cg + 8 + i] = (float)q1[i];
  }
  __syncthreads();
#pragma unroll
  for (int jr = 0; jr < 16; ++jr) {
    int c = jr * 4 + (tid >> 6);
    int v = tid & 63;
    dst[(size_t)z * NN2 + (size_t)(c0 + c) * NNODE + r0 + v] = (__bf16)t[v][c];
  }
}

// ---------------------------------------------------------------------------
// dst[i] = wp*(s0+s1)[i] + (wadp/4)*(s2+s3+s4+s5)[i], slices at src + z*NN2
__global__ __launch_bounds__(256) void wsum6(const __bf16* __restrict__ src,
                                             __bf16* __restrict__ dst,
                                             const float* __restrict__ wpre,
                                             const float* __restrict__ wadp) {
  const size_t NN2 = (size_t)NNODE * NNODE;
  size_t i = ((size_t)blockIdx.x * 256 + threadIdx.x) * 8;
  const float wp = *wpre, wa = *wadp * 0.25f;
  bf16x8 a0 = *(const bf16x8*)(src + i);
  bf16x8 a1 = *(const bf16x8*)(src + NN2 + i);
  bf16x8 a2 = *(const bf16x8*)(src + 2 * NN2 + i);
  bf16x8 a3 = *(const bf16x8*)(src + 3 * NN2 + i);
  bf16x8 a4 = *(const bf16x8*)(src + 4 * NN2 + i);
  bf16x8 a5 = *(const bf16x8*)(src + 5 * NN2 + i);
  bf16x8 o;
#pragma unroll
  for (int j = 0; j < 8; ++j) {
    float v = wp * ((float)a0[j] + (float)a1[j]) +
              wa * ((float)a2[j] + (float)a3[j] + (float)a4[j] + (float)a5[j]);
    o[j] = (__bf16)v;
  }
  *(bf16x8*)(dst + i) = o;
}

// ---------------------------------------------------------------------------
// Wzrt[c][k]=Wz[k][c]*(k<64?s:1); Wzrt[64+c][k]=Wr[k][c]*...; Wct rows 64..127 = 0
__global__ __launch_bounds__(256) void prep_w(const float* __restrict__ Wz,
                                              const float* __restrict__ Wr,
                                              const float* __restrict__ Wc,
                                              const float* __restrict__ wpre,
                                              const float* __restrict__ wadp,
                                              __bf16* __restrict__ Wzrt,
                                              __bf16* __restrict__ Wct) {
  int idx = blockIdx.x * 256 + threadIdx.x;  // 0 .. 128*192-1
  int rr = idx / 192, k = idx % 192;
  float s = 2.f * (*wpre) + (*wadp);
  float sc = (k < 64) ? s : 1.f;
  float vz = (rr < 64) ? Wz[(size_t)k * 64 + rr] : Wr[(size_t)k * 64 + rr - 64];
  Wzrt[idx] = (__bf16)(vz * sc);
  float vc = (rr < 64) ? Wc[(size_t)k * 64 + rr] * sc : 0.f;
  Wct[idx] = (__bf16)vc;
}

// ---------------------------------------------------------------------------
// x f32 [B,N,64] -> XT bf16 [B*64, N] (XT[b*64+c][v]=x[b,v,c]) and xbf bf16 [B*N,64]
__global__ __launch_bounds__(256) void transpose_x(const float* __restrict__ x,
                                                   __bf16* __restrict__ XT,
                                                   __bf16* __restrict__ xbf) {
  const int b = blockIdx.y, v0 = blockIdx.x * 64;
  const int tid = threadIdx.x;
  __shared__ float t[64][65];
  const int vr = tid >> 2, c0 = (tid & 3) * 16;
  const float* src = x + ((size_t)b * NNODE + v0 + vr) * 64 + c0;
  __bf16* xb = xbf + ((size_t)b * NNODE + v0 + vr) * 64 + c0;
#pragma unroll
  for (int j = 0; j < 4; ++j) {
    float4 q = ((const float4*)src)[j];
    t[vr][c0 + j * 4 + 0] = q.x;
    t[vr][c0 + j * 4 + 1] = q.y;
    t[vr][c0 + j * 4 + 2] = q.z;
    t[vr][c0 + j * 4 + 3] = q.w;
    xb[j * 4 + 0] = (__bf16)q.x;
    xb[j * 4 + 1] = (__bf16)q.y;
    xb[j * 4 + 2] = (__bf16)q.z;
    xb[j * 4 + 3] = (__bf16)q.w;
  }
  __syncthreads();
#pragma unroll
  for (int jr = 0; jr < 16; ++jr) {
    int c = jr * 4 + (tid >> 6);
    int v = tid & 63;
    XT[((size_t)b * 64 + c) * NNODE + v0 + v] = (__bf16)t[v][c];
  }
}

// rx bf16 [B*N,64] -> XT bf16 [B*64, N]
__global__ __launch_bounds__(256) void transpose_rx(const __bf16* __restrict__ rx,
                                                    __bf16* __restrict__ XT) {
  const int b = blockIdx.y, v0 = blockIdx.x * 64;
  const int tid = threadIdx.x;
  __shared__ float t[64][65];
  const int vr = tid >> 2, c0 = (tid & 3) * 16;
  const __bf16* src = rx + ((size_t)b * NNODE + v0 + vr) * 64 + c0;
  bf16x8 q0 = ((const bf16x8*)src)[0];
  bf16x8 q1 = ((const bf16x8*)src)[1];
#pragma unroll
  for (int i = 0; i < 8; ++i) {
    t[vr][c0 + i] = (float)q0[i];
    t[vr][c0 + 8 + i] = (float)q1[i];
  }
  __syncthreads();
#pragma unroll
  for (int jr = 0; jr < 16; ++jr) {
    int c = jr * 4 + (tid >> 6);
    int v = tid & 63;
    XT[((size_t)b * 64 + c) * NNODE + v0 + v] = (__bf16)t[v][c];
  }
}

// ---------------------------------------------------------------------------
// 2-phase 128x256 GEMM (BK=64), batched over z. Grid fills the machine
// exactly: z6 -> 768 blocks = 3 rounds; z2 -> 256 blocks = 1 round.
// 8 waves (2M x 4N, 64x64/wave). A-frags read once/K-tile, reused in ph2.
// 3-bit XOR swizzle (verified R4: conflicts==0). LDS 96 KiB.
#define VMCNT0() asm volatile("s_waitcnt vmcnt(0)" ::: "memory")
#define VMCNT2() asm volatile("s_waitcnt vmcnt(2)" ::: "memory")
#define VMCNT4() asm volatile("s_waitcnt vmcnt(4)" ::: "memory")
#define BARRIER() asm volatile("s_barrier" ::: "memory")

__global__ __launch_bounds__(512, 2) void gemm_hop2(const __bf16* __restrict__ Abase,
                                                    size_t aStrideZ,
                                                    const __bf16* __restrict__ BtBase,
                                                    __bf16* __restrict__ Cbase) {
  extern __shared__ char smem[];  // 98304 B
  const int tid = threadIdx.x;
  const int w = tid >> 6, l = tid & 63;
  const int wr = w >> 2, wc = w & 3;  // 2 M-waves x 4 N-waves
  const size_t z = blockIdx.z;
  const int m0 = blockIdx.x * 128, n0 = blockIdx.y * 256;
  const __bf16* A = Abase + z * aStrideZ;
  const __bf16* Bt = BtBase + z * (size_t)(NNODE * NNODE);
  __bf16* C = Cbase + z * (size_t)(NNODE * NNODE);
  const int NT = NNODE / 64;  // 32 K-tiles

  // regions ([128 rows][128 B] each, 16 KiB):
  //   A[d]    @ d*16384
  //   B[d][h] @ 32768 + d*32768 + h*16384
#define AREG(d) (smem + (d) * 16384)
#define BREG(d, h) (smem + 32768 + (d) * 32768 + (h) * 16384)

  // swizzled read offsets. A frag mi: row = mi*32 + wr*16 + (l&15).
  // B frag j (j=0..3, col = j*64+wc*16): region h=j>>1, row = (j&1)*64+wc*16+(l&15).
  int aoff[4][2], boff[4][2];
#pragma unroll
  for (int mi = 0; mi < 4; ++mi)
#pragma unroll
    for (int ks = 0; ks < 2; ++ks) {
      int rh = mi * 32 + wr * 16 + (l & 15);
      int lo = rh * 128 + ks * 64 + ((l >> 4) * 16);
      aoff[mi][ks] = lo ^ ((rh & 7) << 4);
    }
#pragma unroll
  for (int j = 0; j < 4; ++j)
#pragma unroll
    for (int ks = 0; ks < 2; ++ks) {
      int rh = (j & 1) * 64 + wc * 16 + (l & 15);
      int lo = rh * 128 + ks * 64 + ((l >> 4) * 16);
      boff[j][ks] = lo ^ ((rh & 7) << 4);
    }

  // staging: LDS dest linear; inverse-swizzled global source column
  const int sg_row[2] = {w * 8 + (l >> 3), 64 + w * 8 + (l >> 3)};
  const int sg_col = (((l & 7) ^ ((l >> 3) & 7)) << 4);

#define STAGE(gbase, row0, kt, region)                                        \
  do {                                                                        \
    const char* _g0 = (const char*)(gbase) +                                  \
        (size_t)((row0) + sg_row[0]) * 4096 + (size_t)(kt) * 128 + sg_col;    \
    const char* _g1 = (const char*)(gbase) +                                  \
        (size_t)((row0) + sg_row[1]) * 4096 + (size_t)(kt) * 128 + sg_col;    \
    gload16(_g0, (region) + w * 1024);                                        \
    gload16(_g1, (region) + 8192 + w * 1024);                                 \
  } while (0)

  f32x4 acc[4][4] = {};
  bf16x8 af[4][2], bf[2][2];

  // ---- prologue: tile0 {A, B0, B1}
  STAGE(A, m0, 0, AREG(0));
  STAGE(Bt, n0, 0, BREG(0, 0));
  STAGE(Bt, n0 + 128, 0, BREG(0, 1));
  VMCNT2();   // A,B0 landed (B1 may still fly; forced down by ph1's vmcnt(4))
  BARRIER();

  for (int t = 0; t < NT; ++t) {
    const int d = t & 1;
    // ---------- phase 1: B-cols half0 (frags j=0,1); stage (t+1).{A,B0}
#pragma unroll
    for (int mi = 0; mi < 4; ++mi) {
      af[mi][0] = *(const bf16x8*)(AREG(d) + aoff[mi][0]);
      af[mi][1] = *(const bf16x8*)(AREG(d) + aoff[mi][1]);
    }
#pragma unroll
    for (int j = 0; j < 2; ++j) {
      bf[j][0] = *(const bf16x8*)(BREG(d, 0) + boff[j][0]);
      bf[j][1] = *(const bf16x8*)(BREG(d, 0) + boff[j][1]);
    }
    if (t + 1 < NT) {
      STAGE(A, m0, t + 1, AREG(d ^ 1));
      STAGE(Bt, n0, t + 1, BREG(d ^ 1, 0));
      VMCNT4();  // forces (t).B1 landed; leaves the 4 new loads in flight
    } else {
      VMCNT0();  // tail: force (t).B1 landed
    }
    BARRIER();
    __builtin_amdgcn_s_setprio(1);
#pragma unroll
    for (int mi = 0; mi < 4; ++mi)
#pragma unroll
      for (int j = 0; j < 2; ++j)
#pragma unroll
        for (int ks = 0; ks < 2; ++ks)
          acc[mi][j] = __builtin_amdgcn_mfma_f32_16x16x32_bf16(af[mi][ks], bf[j][ks],
                                                               acc[mi][j], 0, 0, 0);
    __builtin_amdgcn_s_setprio(0);
    BARRIER();

    // ---------- phase 2: B-cols half1 (frags j=2,3); stage (t+1).B1
#pragma unroll
    for (int j = 0; j < 2; ++j) {
      bf[j][0] = *(const bf16x8*)(BREG(d, 1) + boff[j + 2][0]);
      bf[j][1] = *(const bf16x8*)(BREG(d, 1) + boff[j + 2][1]);
    }
    if (t + 1 < NT) {
      STAGE(Bt, n0 + 128, t + 1, BREG(d ^ 1, 1));
      VMCNT2();  // forces (t+1).{A,B0} landed for next ph1; leaves (t+1).B1
    }
    BARRIER();
    __builtin_amdgcn_s_setprio(1);
#pragma unroll
    for (int mi = 0; mi < 4; ++mi)
#pragma unroll
      for (int j = 0; j < 2; ++j)
#pragma unroll
        for (int ks = 0; ks < 2; ++ks)
          acc[mi][j + 2] = __builtin_amdgcn_mfma_f32_16x16x32_bf16(af[mi][ks], bf[j][ks],
                                                                   acc[mi][j + 2], 0, 0, 0);
    __builtin_amdgcn_s_setprio(0);
    BARRIER();
  }

  // ---- epilogue: frag (mi,j): row = m0+mi*32+wr*16, col = n0+j*64+wc*16
  const int crow = (l >> 4) * 4;
  const int ccol = l & 15;
#pragma unroll
  for (int mi = 0; mi < 4; ++mi)
#pragma unroll
    for (int j = 0; j < 4; ++j) {
      int r0 = m0 + mi * 32 + wr * 16 + crow;
      int cc = n0 + j * 64 + wc * 16 + ccol;
#pragma unroll
      for (int r = 0; r < 4; ++r)
        C[(size_t)(r0 + r) * NNODE + cc] = (__bf16)acc[mi][j][r];
    }
#undef STAGE
#undef AREG
#undef BREG
}

// ---------------------------------------------------------------------------
// S1[(b,w),c] = HH[0][b*64+c][w] ; S2[(b,w),c] = HH[1][b*64+c][w]
__global__ __launch_bounds__(256) void combine2(const __bf16* __restrict__ HH,
                                                __bf16* __restrict__ S1,
                                                __bf16* __restrict__ S2) {
  const int b = blockIdx.y;
  const int w0 = blockIdx.x * 64;
  const int tid = threadIdx.x;
  const size_t NN2 = (size_t)NNODE * NNODE;
  __shared__ float t1[64][65];
  __shared__ float t2[64][65];
  const int cr = tid >> 2;
  const int wg = (tid & 3) * 16;
  const __bf16* p1 = HH + (size_t)(b * 64 + cr) * NNODE + w0 + wg;
  const __bf16* p2 = HH + NN2 + (size_t)(b * 64 + cr) * NNODE + w0 + wg;
  bf16x8 q10 = ((const bf16x8*)p1)[0], q11 = ((const bf16x8*)p1)[1];
  bf16x8 q20 = ((const bf16x8*)p2)[0], q21 = ((const bf16x8*)p2)[1];
#pragma unroll
  for (int i = 0; i < 8; ++i) {
    t1[cr][wg + i] = (float)q10[i];
    t1[cr][wg + 8 + i] = (float)q11[i];
    t2[cr][wg + i] = (float)q20[i];
    t2[cr][wg + 8 + i] = (float)q21[i];
  }
  __syncthreads();
#pragma unroll
  for (int jr = 0; jr < 16; ++jr) {
    int wl = jr * 4 + (tid >> 6);
    int c = tid & 63;
    size_t o = ((size_t)b * NNODE + w0 + wl) * 64 + c;
    S1[o] = (__bf16)t1[c][wl];
    S2[o] = (__bf16)t2[c][wl];
  }
}

// ---------------------------------------------------------------------------
// Gate linear GEMM: [65536 x 192] @ Wt^T, K=192, N=128, fused epilogues.
// MODE 0: cols 0-63 -> z=sigmoid -> zbuf(f32); cols 64-127 -> r -> rx=(bf16)(r*hid)
// MODE 1: cols 0-63 -> c=tanh   -> out=(1-z)*hid+z*c (f32)
template <int MODE>
__global__ __launch_bounds__(256) void gemm_lin(const __bf16* __restrict__ Xp,
                                                const __bf16* __restrict__ S1,
                                                const __bf16* __restrict__ S2,
                                                const __bf16* __restrict__ Wt,
                                                const float* __restrict__ b0,
                                                const float* __restrict__ b1,
                                                const float* __restrict__ wpre,
                                                const float* __restrict__ wadp,
                                                const float* __restrict__ hid,
                                                float* __restrict__ zbuf,
                                                __bf16* __restrict__ rxout,
                                                float* __restrict__ outp) {
  __shared__ __bf16 As[128 * 32];
  __shared__ __bf16 Bs[128 * 32];
  const int tid = threadIdx.x;
  const int wave = tid >> 6, lane = tid & 63;
  const int wr = wave >> 1, wc = wave & 1;
  const int m0 = blockIdx.x * 128;
  const int rowA = tid >> 2;
  const int colb = (tid & 3) * 16;
  const __bf16* srcs[3] = {Xp, S1, S2};
  char* asD0 = (char*)As + wave * 1024;
  char* asD1 = (char*)As + 4096 + wave * 1024;
  char* bsD0 = (char*)Bs + wave * 1024;
  char* bsD1 = (char*)Bs + 4096 + wave * 1024;

  f32x4 acc[4][4] = {};

#pragma unroll
  for (int kt = 0; kt < 6; ++kt) {
    const __bf16* Ab = srcs[kt >> 1];
    const char* aS0 = (const char*)(Ab + (size_t)(m0 + rowA) * 64) + (kt & 1) * 64 + colb;
    const char* aS1 = (const char*)(Ab + (size_t)(m0 + rowA + 64) * 64) + (kt & 1) * 64 + colb;
    const char* bS0 = (const char*)(Wt + (size_t)rowA * 192) + kt * 64 + colb;
    const char* bS1 = (const char*)(Wt + (size_t)(rowA + 64) * 192) + kt * 64 + colb;
    gload16(aS0, asD0);
    gload16(aS1, asD1);
    gload16(bS0, bsD0);
    gload16(bS1, bsD1);
    __syncthreads();
    bf16x8 af[4], bfr[4];
#pragma unroll
    for (int mi = 0; mi < 4; ++mi)
      af[mi] = *(const bf16x8*)((const char*)As +
               ((wr * 64 + mi * 16 + (lane & 15)) * 64 + (lane >> 4) * 16));
#pragma unroll
    for (int ni = 0; ni < 4; ++ni)
      bfr[ni] = *(const bf16x8*)((const char*)Bs +
               ((wc * 64 + ni * 16 + (lane & 15)) * 64 + (lane >> 4) * 16));
#pragma unroll
    for (int mi = 0; mi < 4; ++mi)
#pragma unroll
      for (int ni = 0; ni < 4; ++ni)
        acc[mi][ni] = __builtin_amdgcn_mfma_f32_16x16x32_bf16(af[mi], bfr[ni],
                                                              acc[mi][ni], 0, 0, 0);
    __syncthreads();
  }

  const float wp = *wpre, wa = *wadp;
  const float s = 2.f * wp + wa;
  const int crow = (lane >> 4) * 4;
  const int ccol = lane & 15;
#pragma unroll
  for (int mi = 0; mi < 4; ++mi)
#pragma unroll
    for (int ni = 0; ni < 4; ++ni) {
      int r0 = m0 + wr * 64 + mi * 16 + crow;
      int col = wc * 64 + ni * 16 + ccol;
      int cf = col & 63;
#pragma unroll
      for (int r = 0; r < 4; ++r) {
        int row = r0 + r;
        float g = acc[mi][ni][r];
        if (MODE == 0) {
          if (col < 64) {
            g += s * b0[cf];
            zbuf[(size_t)row * 64 + cf] = 1.f / (1.f + __expf(-g));
          } else {
            g += s * b1[cf];
            float rv = 1.f / (1.f + __expf(-g));
            rxout[(size_t)row * 64 + cf] = (__bf16)(rv * hid[(size_t)row * 64 + cf]);
          }
        } else {
          if (col < 64) {
            g += s * b0[cf];
            float cv = 1.f - 2.f / (1.f + __expf(2.f * g));
            float zv = zbuf[(size_t)row * 64 + cf];
            float hv = hid[(size_t)row * 64 + cf];
            outp[(size_t)row * 64 + cf] = (1.f - zv) * hv + zv * cv;
          }
        }
      }
    }
}

// ---------------------------------------------------------------------------
extern "C" void kernel_launch(void* const* d_in, const int* in_sizes, int n_in,
                              void* d_out, int out_size, void* d_ws, size_t ws_size,
                              hipStream_t stream) {
  (void)in_sizes; (void)n_in; (void)out_size;
  const float* x    = (const float*)d_in[0];
  const float* A1   = (const float*)d_in[1];
  const float* A2   = (const float*)d_in[2];
  const float* E1   = (const float*)d_in[3];
  const float* E2   = (const float*)d_in[4];
  const float* Wz   = (const float*)d_in[5];
  const float* bz   = (const float*)d_in[6];
  const float* Wr   = (const float*)d_in[7];
  const float* br   = (const float*)d_in[8];
  const float* Wc   = (const float*)d_in[9];
  const float* bc   = (const float*)d_in[10];
  const float* wpre = (const float*)d_in[11];
  const float* wadp = (const float*)d_in[12];
  float* out = (float*)d_out;

  char* ws = (char*)d_ws;
  const size_t NN2 = (size_t)NNODE * NNODE;  // 4,194,304 (= B*N*D too)
  const size_t NN2B = NN2 * 2;               // bytes per bf16 slice
  __bf16* ADJ  = (__bf16*)(ws);
  __bf16* ADJT = (__bf16*)(ws + 6 * NN2B);
  __bf16* SQ   = (__bf16*)(ws + 12 * NN2B);
  __bf16* MM   = (__bf16*)(ws + 18 * NN2B);
  __bf16* XT   = (__bf16*)(ws + 20 * NN2B);
  __bf16* xbf  = (__bf16*)(ws + 21 * NN2B);
  __bf16* rx   = (__bf16*)(ws + 22 * NN2B);
  __bf16* HH   = (__bf16*)(ws);                 // over ADJ[0..1] (dead)
  __bf16* S1   = (__bf16*)(ws + 2 * NN2B);      // over ADJ[2]
  __bf16* S2   = (__bf16*)(ws + 3 * NN2B);      // over ADJ[3]
  float*  zbuf = (float*)(ws + 4 * NN2B);       // over ADJ[4..5]
  __bf16* E1p  = (__bf16*)(ws + 23 * NN2B);     // 4*2048*32
  __bf16* E2p  = E1p + 4 * NNODE * 32;
  __bf16* Wzrt = E2p + 4 * NNODE * 32;
  __bf16* Wct  = Wzrt + 128 * 192;
  if (ws_size < 23 * NN2B + 2 * 4 * NNODE * 32 * 2 + 2 * 128 * 192 * 2) return;

  __bf16* SC = SQ;  // scores live in SQ region until softmax consumes them

  // --- adjacency construction
  conv_bf16<<<4096, 256, 0, stream>>>(A1, ADJ);
  conv_bf16<<<4096, 256, 0, stream>>>(A2, ADJ + NN2);
  prep_e<<<128, 256, 0, stream>>>(E1, E2, E1p, E2p);
  score_gemm<<<dim3(16, 16, 4), 256, 0, stream>>>(E1p, E2p, SC);
  softmax_rows<<<2048, 256, 0, stream>>>(SC, ADJ + 2 * NN2);
  transpose_b<<<dim3(32, 32, 6), 256, 0, stream>>>(ADJ, ADJT);
  wsum6<<<2048, 256, 0, stream>>>(ADJ, MM, wpre, wadp);            // M1
  prep_w<<<96, 256, 0, stream>>>(Wz, Wr, Wc, wpre, wadp, Wzrt, Wct);
  transpose_x<<<dim3(32, 32), 256, 0, stream>>>(x, XT, xbf);

  // --- M2 = sum_z w_z * A_z^2  (6 squaring GEMMs -> 768 blocks, 3 rounds)
  gemm_hop2<<<dim3(16, 8, 6), 512, 98304, stream>>>(ADJ, NN2, ADJT, SQ);
  wsum6<<<2048, 256, 0, stream>>>(SQ, MM + NN2, wpre, wadp);       // M2

  // --- stage 1: S1 = M1 x, S2 = M2 x  (256 blocks, 1 full round)
  gemm_hop2<<<dim3(16, 8, 2), 512, 98304, stream>>>(XT, 0, MM, HH);
  combine2<<<dim3(32, 32), 256, 0, stream>>>(HH, S1, S2);
  gemm_lin<0><<<512, 256, 0, stream>>>(xbf, S1, S2, Wzrt, bz, br, wpre, wadp,
                                       x, zbuf, rx, nullptr);

  // --- stage 2: hops on r*x
  transpose_rx<<<dim3(32, 32), 256, 0, stream>>>(rx, XT);
  gemm_hop2<<<dim3(16, 8, 2), 512, 98304, stream>>>(XT, 0, MM, HH);
  combine2<<<dim3(32, 32), 256, 0, stream>>>(HH, S1, S2);
  gemm_lin<1><<<512, 256, 0, stream>>>(rx, S1, S2, Wct, bc, nullptr, wpre, wadp,
                                       x, zbuf, nullptr, out);
}

// Round 7
// 304.033 us; speedup vs baseline: 2.1733x; 1.0860x over previous
//
#include <hip/hip_runtime.h>

#define NNODE 2048
#define NBATCH 32

typedef __attribute__((ext_vector_type(4))) float f32x4;
typedef __attribute__((ext_vector_type(8))) __bf16 bf16x8;

__device__ __forceinline__ void gload16(const void* g, void* lds) {
  __builtin_amdgcn_global_load_lds(
      (const __attribute__((address_space(1))) unsigned int*)g,
      (__attribute__((address_space(3))) unsigned int*)lds, 16, 0, 0);
}

// ---------------------------------------------------------------------------
// Convert f32 -> bf16 (4 elems/thread, exact grid)
__global__ __launch_bounds__(256) void conv_bf16(const float* __restrict__ in,
                                                 __bf16* __restrict__ outp) {
  int i = blockIdx.x * 256 + threadIdx.x;
  float4 q = ((const float4*)in)[i];
  outp[4 * (size_t)i + 0] = (__bf16)q.x;
  outp[4 * (size_t)i + 1] = (__bf16)q.y;
  outp[4 * (size_t)i + 2] = (__bf16)q.z;
  outp[4 * (size_t)i + 3] = (__bf16)q.w;
}

// ---------------------------------------------------------------------------
// Repack E1,E2 [N,H,16] f32 -> [H][N][32] bf16 (K zero-padded 16->32)
__global__ __launch_bounds__(256) void prep_e(const float* __restrict__ E1,
                                              const float* __restrict__ E2,
                                              __bf16* __restrict__ E1p,
                                              __bf16* __restrict__ E2p) {
  int idx = blockIdx.x * 256 + threadIdx.x;  // 0..32767
  int cq = idx & 3;
  int n = (idx >> 2) & 2047;
  int h = idx >> 13;
  const float4 q1 = *(const float4*)(E1 + (size_t)(n * 4 + h) * 16 + cq * 4);
  const float4 q2 = *(const float4*)(E2 + (size_t)(n * 4 + h) * 16 + cq * 4);
  size_t o = ((size_t)h * NNODE + n) * 32 + cq * 4;
  E1p[o + 0] = (__bf16)q1.x; E1p[o + 1] = (__bf16)q1.y;
  E1p[o + 2] = (__bf16)q1.z; E1p[o + 3] = (__bf16)q1.w;
  E2p[o + 0] = (__bf16)q2.x; E2p[o + 1] = (__bf16)q2.y;
  E2p[o + 2] = (__bf16)q2.z; E2p[o + 3] = (__bf16)q2.w;
  size_t oz = o + 16;
  E1p[oz + 0] = (__bf16)0.f; E1p[oz + 1] = (__bf16)0.f;
  E1p[oz + 2] = (__bf16)0.f; E1p[oz + 3] = (__bf16)0.f;
  E2p[oz + 0] = (__bf16)0.f; E2p[oz + 1] = (__bf16)0.f;
  E2p[oz + 2] = (__bf16)0.f; E2p[oz + 3] = (__bf16)0.f;
}

// ---------------------------------------------------------------------------
// SC[h][w][v] = relu(E1p_h @ E2p_h^T)/4, bf16. Single K=32 MFMA step.
__global__ __launch_bounds__(256) void score_gemm(const __bf16* __restrict__ E1p,
                                                  const __bf16* __restrict__ E2p,
                                                  __bf16* __restrict__ SC) {
  __shared__ __bf16 As[128 * 32];
  __shared__ __bf16 Bs[128 * 32];
  const int tid = threadIdx.x;
  const int wave = tid >> 6, lane = tid & 63;
  const int wr = wave >> 1, wc = wave & 1;
  const int h = blockIdx.z;
  const int m0 = blockIdx.x * 128, n0 = blockIdx.y * 128;
  const __bf16* A = E1p + (size_t)h * NNODE * 32;
  const __bf16* Bt = E2p + (size_t)h * NNODE * 32;
  const int rowA = tid >> 2;
  const int colb = (tid & 3) * 16;
  gload16((const char*)(A + (size_t)(m0 + rowA) * 32) + colb, (char*)As + wave * 1024);
  gload16((const char*)(A + (size_t)(m0 + rowA + 64) * 32) + colb, (char*)As + 4096 + wave * 1024);
  gload16((const char*)(Bt + (size_t)(n0 + rowA) * 32) + colb, (char*)Bs + wave * 1024);
  gload16((const char*)(Bt + (size_t)(n0 + rowA + 64) * 32) + colb, (char*)Bs + 4096 + wave * 1024);
  __syncthreads();

  f32x4 acc[4][4] = {};
  bf16x8 af[4], bfr[4];
#pragma unroll
  for (int mi = 0; mi < 4; ++mi)
    af[mi] = *(const bf16x8*)((const char*)As +
             ((wr * 64 + mi * 16 + (lane & 15)) * 64 + (lane >> 4) * 16));
#pragma unroll
  for (int ni = 0; ni < 4; ++ni)
    bfr[ni] = *(const bf16x8*)((const char*)Bs +
             ((wc * 64 + ni * 16 + (lane & 15)) * 64 + (lane >> 4) * 16));
#pragma unroll
  for (int mi = 0; mi < 4; ++mi)
#pragma unroll
    for (int ni = 0; ni < 4; ++ni)
      acc[mi][ni] = __builtin_amdgcn_mfma_f32_16x16x32_bf16(af[mi], bfr[ni],
                                                            acc[mi][ni], 0, 0, 0);

  const int crow = (lane >> 4) * 4;
  const int ccol = lane & 15;
#pragma unroll
  for (int mi = 0; mi < 4; ++mi)
#pragma unroll
    for (int ni = 0; ni < 4; ++ni) {
      int r0 = m0 + wr * 64 + mi * 16 + crow;
      int cc = n0 + wc * 64 + ni * 16 + ccol;
#pragma unroll
      for (int r = 0; r < 4; ++r) {
        float val = fmaxf(acc[mi][ni][r], 0.f) * 0.25f;
        SC[((size_t)h * NNODE + r0 + r) * NNODE + cc] = (__bf16)val;
      }
    }
}

// ---------------------------------------------------------------------------
// Row softmax over v: one wave per row of SC [8192 x 2048] bf16 -> adjh bf16
__global__ __launch_bounds__(256) void softmax_rows(const __bf16* __restrict__ SC,
                                                    __bf16* __restrict__ adjh) {
  const int tid = threadIdx.x;
  const int wave = tid >> 6, lane = tid & 63;
  const size_t row = (size_t)blockIdx.x * 4 + wave;
  const __bf16* src = SC + row * NNODE;
  __bf16* dst = adjh + row * NNODE;
  float v[32];
  float mx = 0.f;
#pragma unroll
  for (int j = 0; j < 4; ++j) {
    bf16x8 q = *(const bf16x8*)(src + j * 512 + lane * 8);
#pragma unroll
    for (int i = 0; i < 8; ++i) {
      float f = (float)q[i];
      v[j * 8 + i] = f;
      mx = fmaxf(mx, f);
    }
  }
#pragma unroll
  for (int o = 32; o > 0; o >>= 1) mx = fmaxf(mx, __shfl_xor(mx, o));
  float s = 0.f;
#pragma unroll
  for (int i = 0; i < 32; ++i) {
    v[i] = __expf(v[i] - mx);
    s += v[i];
  }
#pragma unroll
  for (int o = 32; o > 0; o >>= 1) s += __shfl_xor(s, o);
  float inv = 1.f / s;
#pragma unroll
  for (int j = 0; j < 4; ++j) {
    bf16x8 q;
#pragma unroll
    for (int i = 0; i < 8; ++i) q[i] = (__bf16)(v[j * 8 + i] * inv);
    *(bf16x8*)(dst + j * 512 + lane * 8) = q;
  }
}

// ---------------------------------------------------------------------------
// bf16 transpose per z-slice: dst[z][c][r] = src[z][r][c], 64x64 tiles
__global__ __launch_bounds__(256) void transpose_b(const __bf16* __restrict__ src,
                                                   __bf16* __restrict__ dst) {
  const int z = blockIdx.z;
  const int r0 = blockIdx.x * 64, c0 = blockIdx.y * 64;
  const int tid = threadIdx.x;
  const size_t NN2 = (size_t)NNODE * NNODE;
  __shared__ float t[64][65];
  const int vr = tid >> 2, cg = (tid & 3) * 16;
  const __bf16* p = src + (size_t)z * NN2 + (size_t)(r0 + vr) * NNODE + c0 + cg;
  bf16x8 q0 = ((const bf16x8*)p)[0];
  bf16x8 q1 = ((const bf16x8*)p)[1];
#pragma unroll
  for (int i = 0; i < 8; ++i) {
    t[vr][cg + i] = (float)q0[i];
    t[vr][cg + 8 + i] = (float)q1[i];
  }
  __syncthreads();
#pragma unroll
  for (int jr = 0; jr < 16; ++jr) {
    int c = jr * 4 + (tid >> 6);
    int v = tid & 63;
    dst[(size_t)z * NN2 + (size_t)(c0 + c) * NNODE + r0 + v] = (__bf16)t[v][c];
  }
}

// ---------------------------------------------------------------------------
// dst[i] = wp*(s0+s1)[i] + (wadp/4)*(s2+s3+s4+s5)[i], slices at src + z*NN2
__global__ __launch_bounds__(256) void wsum6(const __bf16* __restrict__ src,
                                             __bf16* __restrict__ dst,
                                             const float* __restrict__ wpre,
                                             const float* __restrict__ wadp) {
  const size_t NN2 = (size_t)NNODE * NNODE;
  size_t i = ((size_t)blockIdx.x * 256 + threadIdx.x) * 8;
  const float wp = *wpre, wa = *wadp * 0.25f;
  bf16x8 a0 = *(const bf16x8*)(src + i);
  bf16x8 a1 = *(const bf16x8*)(src + NN2 + i);
  bf16x8 a2 = *(const bf16x8*)(src + 2 * NN2 + i);
  bf16x8 a3 = *(const bf16x8*)(src + 3 * NN2 + i);
  bf16x8 a4 = *(const bf16x8*)(src + 4 * NN2 + i);
  bf16x8 a5 = *(const bf16x8*)(src + 5 * NN2 + i);
  bf16x8 o;
#pragma unroll
  for (int j = 0; j < 8; ++j) {
    float v = wp * ((float)a0[j] + (float)a1[j]) +
              wa * ((float)a2[j] + (float)a3[j] + (float)a4[j] + (float)a5[j]);
    o[j] = (__bf16)v;
  }
  *(bf16x8*)(dst + i) = o;
}

// ---------------------------------------------------------------------------
// Wzrt[c][k]=Wz[k][c]*(k<64?s:1); Wzrt[64+c][k]=Wr[k][c]*...; Wct rows 64..127 = 0
__global__ __launch_bounds__(256) void prep_w(const float* __restrict__ Wz,
                                              const float* __restrict__ Wr,
                                              const float* __restrict__ Wc,
                                              const float* __restrict__ wpre,
                                              const float* __restrict__ wadp,
                                              __bf16* __restrict__ Wzrt,
                                              __bf16* __restrict__ Wct) {
  int idx = blockIdx.x * 256 + threadIdx.x;  // 0 .. 128*192-1
  int rr = idx / 192, k = idx % 192;
  float s = 2.f * (*wpre) + (*wadp);
  float sc = (k < 64) ? s : 1.f;
  float vz = (rr < 64) ? Wz[(size_t)k * 64 + rr] : Wr[(size_t)k * 64 + rr - 64];
  Wzrt[idx] = (__bf16)(vz * sc);
  float vc = (rr < 64) ? Wc[(size_t)k * 64 + rr] * sc : 0.f;
  Wct[idx] = (__bf16)vc;
}

// ---------------------------------------------------------------------------
// x f32 [B,N,64] -> XT bf16 [B*64, N] (XT[b*64+c][v]=x[b,v,c]) and xbf bf16 [B*N,64]
__global__ __launch_bounds__(256) void transpose_x(const float* __restrict__ x,
                                                   __bf16* __restrict__ XT,
                                                   __bf16* __restrict__ xbf) {
  const int b = blockIdx.y, v0 = blockIdx.x * 64;
  const int tid = threadIdx.x;
  __shared__ float t[64][65];
  const int vr = tid >> 2, c0 = (tid & 3) * 16;
  const float* src = x + ((size_t)b * NNODE + v0 + vr) * 64 + c0;
  __bf16* xb = xbf + ((size_t)b * NNODE + v0 + vr) * 64 + c0;
#pragma unroll
  for (int j = 0; j < 4; ++j) {
    float4 q = ((const float4*)src)[j];
    t[vr][c0 + j * 4 + 0] = q.x;
    t[vr][c0 + j * 4 + 1] = q.y;
    t[vr][c0 + j * 4 + 2] = q.z;
    t[vr][c0 + j * 4 + 3] = q.w;
    xb[j * 4 + 0] = (__bf16)q.x;
    xb[j * 4 + 1] = (__bf16)q.y;
    xb[j * 4 + 2] = (__bf16)q.z;
    xb[j * 4 + 3] = (__bf16)q.w;
  }
  __syncthreads();
#pragma unroll
  for (int jr = 0; jr < 16; ++jr) {
    int c = jr * 4 + (tid >> 6);
    int v = tid & 63;
    XT[((size_t)b * 64 + c) * NNODE + v0 + v] = (__bf16)t[v][c];
  }
}

// rx bf16 [B*N,64] -> XT bf16 [B*64, N]
__global__ __launch_bounds__(256) void transpose_rx(const __bf16* __restrict__ rx,
                                                    __bf16* __restrict__ XT) {
  const int b = blockIdx.y, v0 = blockIdx.x * 64;
  const int tid = threadIdx.x;
  __shared__ float t[64][65];
  const int vr = tid >> 2, c0 = (tid & 3) * 16;
  const __bf16* src = rx + ((size_t)b * NNODE + v0 + vr) * 64 + c0;
  bf16x8 q0 = ((const bf16x8*)src)[0];
  bf16x8 q1 = ((const bf16x8*)src)[1];
#pragma unroll
  for (int i = 0; i < 8; ++i) {
    t[vr][c0 + i] = (float)q0[i];
    t[vr][c0 + 8 + i] = (float)q1[i];
  }
  __syncthreads();
#pragma unroll
  for (int jr = 0; jr < 16; ++jr) {
    int c = jr * 4 + (tid >> 6);
    int v = tid & 63;
    XT[((size_t)b * 64 + c) * NNODE + v0 + v] = (__bf16)t[v][c];
  }
}

// ---------------------------------------------------------------------------
// 128x128 GEMM, BK=64, 4 waves (2Mx2N, 64x64/wave), LDS 64 KiB -> 2 blocks/CU.
// Single compute phase per K-tile, counted vmcnt(8), 2 barriers/K-tile.
// Same verified 3-bit XOR swizzle ([128 rows][128 B] regions; conflicts==0).
#define VMCNT0() asm volatile("s_waitcnt vmcnt(0)" ::: "memory")
#define VMCNT8() asm volatile("s_waitcnt vmcnt(8)" ::: "memory")
#define LGKMCNT0() asm volatile("s_waitcnt lgkmcnt(0)" ::: "memory")
#define BARRIER() asm volatile("s_barrier" ::: "memory")

__global__ __launch_bounds__(256, 2) void gemm_hop1(const __bf16* __restrict__ Abase,
                                                    size_t aStrideZ,
                                                    const __bf16* __restrict__ BtBase,
                                                    __bf16* __restrict__ Cbase) {
  extern __shared__ char smem[];  // 65536 B
  const int tid = threadIdx.x;
  const int w = tid >> 6, l = tid & 63;
  const int wr = w >> 1, wc = w & 1;  // 2M x 2N waves
  const size_t z = blockIdx.z;
  const int m0 = blockIdx.x * 128, n0 = blockIdx.y * 128;
  const __bf16* A = Abase + z * aStrideZ;
  const __bf16* Bt = BtBase + z * (size_t)(NNODE * NNODE);
  __bf16* C = Cbase + z * (size_t)(NNODE * NNODE);
  const int NT = NNODE / 64;  // 32 K-tiles

  // regions ([128 rows][128 B] each, 16 KiB): A[d] @ d*16384; B[d] @ 32768+d*16384
#define AREG(d) (smem + (d) * 16384)
#define BREG(d) (smem + 32768 + (d) * 16384)

  // swizzled read offsets (verified formula)
  int aoff[4][2], boff[4][2];
#pragma unroll
  for (int mi = 0; mi < 4; ++mi)
#pragma unroll
    for (int ks = 0; ks < 2; ++ks) {
      int rh = mi * 32 + wr * 16 + (l & 15);
      int lo = rh * 128 + ks * 64 + ((l >> 4) * 16);
      aoff[mi][ks] = lo ^ ((rh & 7) << 4);
    }
#pragma unroll
  for (int j = 0; j < 4; ++j)
#pragma unroll
    for (int ks = 0; ks < 2; ++ks) {
      int rh = j * 32 + wc * 16 + (l & 15);
      int lo = rh * 128 + ks * 64 + ((l >> 4) * 16);
      boff[j][ks] = lo ^ ((rh & 7) << 4);
    }

  // staging: LDS dest linear; inverse-swizzled global source column.
  // 4 waves: one gload16-call covers 32 rows (4KB); 4 calls per 128-row region.
  const int sg_row = w * 8 + (l >> 3);
  const int sg_col = (((l & 7) ^ ((l >> 3) & 7)) << 4);

#define STAGE(gbase, row0, kt, region)                                        \
  do {                                                                        \
    _Pragma("unroll")                                                         \
    for (int p = 0; p < 4; ++p) {                                             \
      const char* _g = (const char*)(gbase) +                                 \
          (size_t)((row0) + p * 32 + sg_row) * 4096 +                         \
          (size_t)(kt) * 128 + sg_col;                                        \
      gload16(_g, (region) + p * 4096 + w * 1024);                            \
    }                                                                         \
  } while (0)

  f32x4 acc[4][4] = {};
  bf16x8 af[4][2], bfr[4][2];

  // ---- prologue: tiles 0 and 1 (16 loads); wait tile0 (8 remain = tile1)
  STAGE(A, m0, 0, AREG(0));
  STAGE(Bt, n0, 0, BREG(0));
  STAGE(A, m0, 1, AREG(1));
  STAGE(Bt, n0, 1, BREG(1));
  VMCNT8();
  BARRIER();

  for (int t = 0; t < NT; ++t) {
    const int d = t & 1;
    // read all fragments of tile t
#pragma unroll
    for (int mi = 0; mi < 4; ++mi) {
      af[mi][0] = *(const bf16x8*)(AREG(d) + aoff[mi][0]);
      af[mi][1] = *(const bf16x8*)(AREG(d) + aoff[mi][1]);
    }
#pragma unroll
    for (int j = 0; j < 4; ++j) {
      bfr[j][0] = *(const bf16x8*)(BREG(d) + boff[j][0]);
      bfr[j][1] = *(const bf16x8*)(BREG(d) + boff[j][1]);
    }
    LGKMCNT0();
    BARRIER();  // all waves done reading buf[d] -> safe to overwrite
    if (t + 2 < NT) {
      STAGE(A, m0, t + 2, AREG(d));
      STAGE(Bt, n0, t + 2, BREG(d));
      VMCNT8();  // tile t+1's 8 loads landed; t+2's 8 in flight
    } else if (t + 1 < NT) {
      VMCNT0();  // tail: force t+1 landed
    }
    BARRIER();  // t+1 data globally visible before next iter's reads
    __builtin_amdgcn_s_setprio(1);
#pragma unroll
    for (int mi = 0; mi < 4; ++mi)
#pragma unroll
      for (int j = 0; j < 4; ++j)
#pragma unroll
        for (int ks = 0; ks < 2; ++ks)
          acc[mi][j] = __builtin_amdgcn_mfma_f32_16x16x32_bf16(af[mi][ks], bfr[j][ks],
                                                               acc[mi][j], 0, 0, 0);
    __builtin_amdgcn_s_setprio(0);
  }

  // ---- epilogue: frag (mi,j): row = m0+mi*32+wr*16, col = n0+j*32+wc*16
  const int crow = (l >> 4) * 4;
  const int ccol = l & 15;
#pragma unroll
  for (int mi = 0; mi < 4; ++mi)
#pragma unroll
    for (int j = 0; j < 4; ++j) {
      int r0 = m0 + mi * 32 + wr * 16 + crow;
      int cc = n0 + j * 32 + wc * 16 + ccol;
#pragma unroll
      for (int r = 0; r < 4; ++r)
        C[(size_t)(r0 + r) * NNODE + cc] = (__bf16)acc[mi][j][r];
    }
#undef STAGE
#undef AREG
#undef BREG
}

// ---------------------------------------------------------------------------
// S1[(b,w),c] = HH[0][b*64+c][w] ; S2[(b,w),c] = HH[1][b*64+c][w]
__global__ __launch_bounds__(256) void combine2(const __bf16* __restrict__ HH,
                                                __bf16* __restrict__ S1,
                                                __bf16* __restrict__ S2) {
  const int b = blockIdx.y;
  const int w0 = blockIdx.x * 64;
  const int tid = threadIdx.x;
  const size_t NN2 = (size_t)NNODE * NNODE;
  __shared__ float t1[64][65];
  __shared__ float t2[64][65];
  const int cr = tid >> 2;
  const int wg = (tid & 3) * 16;
  const __bf16* p1 = HH + (size_t)(b * 64 + cr) * NNODE + w0 + wg;
  const __bf16* p2 = HH + NN2 + (size_t)(b * 64 + cr) * NNODE + w0 + wg;
  bf16x8 q10 = ((const bf16x8*)p1)[0], q11 = ((const bf16x8*)p1)[1];
  bf16x8 q20 = ((const bf16x8*)p2)[0], q21 = ((const bf16x8*)p2)[1];
#pragma unroll
  for (int i = 0; i < 8; ++i) {
    t1[cr][wg + i] = (float)q10[i];
    t1[cr][wg + 8 + i] = (float)q11[i];
    t2[cr][wg + i] = (float)q20[i];
    t2[cr][wg + 8 + i] = (float)q21[i];
  }
  __syncthreads();
#pragma unroll
  for (int jr = 0; jr < 16; ++jr) {
    int wl = jr * 4 + (tid >> 6);
    int c = tid & 63;
    size_t o = ((size_t)b * NNODE + w0 + wl) * 64 + c;
    S1[o] = (__bf16)t1[c][wl];
    S2[o] = (__bf16)t2[c][wl];
  }
}

// ---------------------------------------------------------------------------
// Gate linear GEMM: [65536 x 192] @ Wt^T, K=192, N=128, fused epilogues.
// MODE 0: cols 0-63 -> z=sigmoid -> zbuf(f32); cols 64-127 -> r -> rx=(bf16)(r*hid)
// MODE 1: cols 0-63 -> c=tanh   -> out=(1-z)*hid+z*c (f32)
template <int MODE>
__global__ __launch_bounds__(256) void gemm_lin(const __bf16* __restrict__ Xp,
                                                const __bf16* __restrict__ S1,
                                                const __bf16* __restrict__ S2,
                                                const __bf16* __restrict__ Wt,
                                                const float* __restrict__ b0,
                                                const float* __restrict__ b1,
                                                const float* __restrict__ wpre,
                                                const float* __restrict__ wadp,
                                                const float* __restrict__ hid,
                                                float* __restrict__ zbuf,
                                                __bf16* __restrict__ rxout,
                                                float* __restrict__ outp) {
  __shared__ __bf16 As[128 * 32];
  __shared__ __bf16 Bs[128 * 32];
  const int tid = threadIdx.x;
  const int wave = tid >> 6, lane = tid & 63;
  const int wr = wave >> 1, wc = wave & 1;
  const int m0 = blockIdx.x * 128;
  const int rowA = tid >> 2;
  const int colb = (tid & 3) * 16;
  const __bf16* srcs[3] = {Xp, S1, S2};
  char* asD0 = (char*)As + wave * 1024;
  char* asD1 = (char*)As + 4096 + wave * 1024;
  char* bsD0 = (char*)Bs + wave * 1024;
  char* bsD1 = (char*)Bs + 4096 + wave * 1024;

  f32x4 acc[4][4] = {};

#pragma unroll
  for (int kt = 0; kt < 6; ++kt) {
    const __bf16* Ab = srcs[kt >> 1];
    const char* aS0 = (const char*)(Ab + (size_t)(m0 + rowA) * 64) + (kt & 1) * 64 + colb;
    const char* aS1 = (const char*)(Ab + (size_t)(m0 + rowA + 64) * 64) + (kt & 1) * 64 + colb;
    const char* bS0 = (const char*)(Wt + (size_t)rowA * 192) + kt * 64 + colb;
    const char* bS1 = (const char*)(Wt + (size_t)(rowA + 64) * 192) + kt * 64 + colb;
    gload16(aS0, asD0);
    gload16(aS1, asD1);
    gload16(bS0, bsD0);
    gload16(bS1, bsD1);
    __syncthreads();
    bf16x8 af[4], bfr[4];
#pragma unroll
    for (int mi = 0; mi < 4; ++mi)
      af[mi] = *(const bf16x8*)((const char*)As +
               ((wr * 64 + mi * 16 + (lane & 15)) * 64 + (lane >> 4) * 16));
#pragma unroll
    for (int ni = 0; ni < 4; ++ni)
      bfr[ni] = *(const bf16x8*)((const char*)Bs +
               ((wc * 64 + ni * 16 + (lane & 15)) * 64 + (lane >> 4) * 16));
#pragma unroll
    for (int mi = 0; mi < 4; ++mi)
#pragma unroll
      for (int ni = 0; ni < 4; ++ni)
        acc[mi][ni] = __builtin_amdgcn_mfma_f32_16x16x32_bf16(af[mi], bfr[ni],
                                                              acc[mi][ni], 0, 0, 0);
    __syncthreads();
  }

  const float wp = *wpre, wa = *wadp;
  const float s = 2.f * wp + wa;
  const int crow = (lane >> 4) * 4;
  const int ccol = lane & 15;
#pragma unroll
  for (int mi = 0; mi < 4; ++mi)
#pragma unroll
    for (int ni = 0; ni < 4; ++ni) {
      int r0 = m0 + wr * 64 + mi * 16 + crow;
      int col = wc * 64 + ni * 16 + ccol;
      int cf = col & 63;
#pragma unroll
      for (int r = 0; r < 4; ++r) {
        int row = r0 + r;
        float g = acc[mi][ni][r];
        if (MODE == 0) {
          if (col < 64) {
            g += s * b0[cf];
            zbuf[(size_t)row * 64 + cf] = 1.f / (1.f + __expf(-g));
          } else {
            g += s * b1[cf];
            float rv = 1.f / (1.f + __expf(-g));
            rxout[(size_t)row * 64 + cf] = (__bf16)(rv * hid[(size_t)row * 64 + cf]);
          }
        } else {
          if (col < 64) {
            g += s * b0[cf];
            float cv = 1.f - 2.f / (1.f + __expf(2.f * g));
            float zv = zbuf[(size_t)row * 64 + cf];
            float hv = hid[(size_t)row * 64 + cf];
            outp[(size_t)row * 64 + cf] = (1.f - zv) * hv + zv * cv;
          }
        }
      }
    }
}

// ---------------------------------------------------------------------------
extern "C" void kernel_launch(void* const* d_in, const int* in_sizes, int n_in,
                              void* d_out, int out_size, void* d_ws, size_t ws_size,
                              hipStream_t stream) {
  (void)in_sizes; (void)n_in; (void)out_size;
  const float* x    = (const float*)d_in[0];
  const float* A1   = (const float*)d_in[1];
  const float* A2   = (const float*)d_in[2];
  const float* E1   = (const float*)d_in[3];
  const float* E2   = (const float*)d_in[4];
  const float* Wz   = (const float*)d_in[5];
  const float* bz   = (const float*)d_in[6];
  const float* Wr   = (const float*)d_in[7];
  const float* br   = (const float*)d_in[8];
  const float* Wc   = (const float*)d_in[9];
  const float* bc   = (const float*)d_in[10];
  const float* wpre = (const float*)d_in[11];
  const float* wadp = (const float*)d_in[12];
  float* out = (float*)d_out;

  char* ws = (char*)d_ws;
  const size_t NN2 = (size_t)NNODE * NNODE;  // 4,194,304 (= B*N*D too)
  const size_t NN2B = NN2 * 2;               // bytes per bf16 slice
  __bf16* ADJ  = (__bf16*)(ws);
  __bf16* ADJT = (__bf16*)(ws + 6 * NN2B);
  __bf16* SQ   = (__bf16*)(ws + 12 * NN2B);
  __bf16* MM   = (__bf16*)(ws + 18 * NN2B);
  __bf16* XT   = (__bf16*)(ws + 20 * NN2B);
  __bf16* xbf  = (__bf16*)(ws + 21 * NN2B);
  __bf16* rx   = (__bf16*)(ws + 22 * NN2B);
  __bf16* HH   = (__bf16*)(ws);                 // over ADJ[0..1] (dead)
  __bf16* S1   = (__bf16*)(ws + 2 * NN2B);      // over ADJ[2]
  __bf16* S2   = (__bf16*)(ws + 3 * NN2B);      // over ADJ[3]
  float*  zbuf = (float*)(ws + 4 * NN2B);       // over ADJ[4..5]
  __bf16* E1p  = (__bf16*)(ws + 23 * NN2B);     // 4*2048*32
  __bf16* E2p  = E1p + 4 * NNODE * 32;
  __bf16* Wzrt = E2p + 4 * NNODE * 32;
  __bf16* Wct  = Wzrt + 128 * 192;
  if (ws_size < 23 * NN2B + 2 * 4 * NNODE * 32 * 2 + 2 * 128 * 192 * 2) return;

  __bf16* SC = SQ;  // scores live in SQ region until softmax consumes them

  // --- adjacency construction
  conv_bf16<<<4096, 256, 0, stream>>>(A1, ADJ);
  conv_bf16<<<4096, 256, 0, stream>>>(A2, ADJ + NN2);
  prep_e<<<128, 256, 0, stream>>>(E1, E2, E1p, E2p);
  score_gemm<<<dim3(16, 16, 4), 256, 0, stream>>>(E1p, E2p, SC);
  softmax_rows<<<2048, 256, 0, stream>>>(SC, ADJ + 2 * NN2);
  transpose_b<<<dim3(32, 32, 6), 256, 0, stream>>>(ADJ, ADJT);
  wsum6<<<2048, 256, 0, stream>>>(ADJ, MM, wpre, wadp);            // M1
  prep_w<<<96, 256, 0, stream>>>(Wz, Wr, Wc, wpre, wadp, Wzrt, Wct);
  transpose_x<<<dim3(32, 32), 256, 0, stream>>>(x, XT, xbf);

  // --- M2 = sum_z w_z * A_z^2  (1536 blocks = 3 rounds at 2 blocks/CU)
  gemm_hop1<<<dim3(16, 16, 6), 256, 65536, stream>>>(ADJ, NN2, ADJT, SQ);
  wsum6<<<2048, 256, 0, stream>>>(SQ, MM + NN2, wpre, wadp);       // M2

  // --- stage 1: S1 = M1 x, S2 = M2 x  (512 blocks = 1 full 2-deep round)
  gemm_hop1<<<dim3(16, 16, 2), 256, 65536, stream>>>(XT, 0, MM, HH);
  combine2<<<dim3(32, 32), 256, 0, stream>>>(HH, S1, S2);
  gemm_lin<0><<<512, 256, 0, stream>>>(xbf, S1, S2, Wzrt, bz, br, wpre, wadp,
                                       x, zbuf, rx, nullptr);

  // --- stage 2: hops on r*x
  transpose_rx<<<dim3(32, 32), 256, 0, stream>>>(rx, XT);
  gemm_hop1<<<dim3(16, 16, 2), 256, 65536, stream>>>(XT, 0, MM, HH);
  combine2<<<dim3(32, 32), 256, 0, stream>>>(HH, S1, S2);
  gemm_lin<1><<<512, 256, 0, stream>>>(rx, S1, S2, Wct, bc, nullptr, wpre, wadp,
                                       x, zbuf, nullptr, out);
}

// Round 8
// 290.175 us; speedup vs baseline: 2.2771x; 1.0478x over previous
//
#include <hip/hip_runtime.h>

#define NNODE 2048
#define NBATCH 32

typedef __attribute__((ext_vector_type(4))) float f32x4;
typedef __attribute__((ext_vector_type(8))) __bf16 bf16x8;

__device__ __forceinline__ void gload16(const void* g, void* lds) {
  __builtin_amdgcn_global_load_lds(
      (const __attribute__((address_space(1))) unsigned int*)g,
      (__attribute__((address_space(3))) unsigned int*)lds, 16, 0, 0);
}

// ---------------------------------------------------------------------------
// Repack E1,E2 [N,H,16] f32 -> [H][N][32] bf16 (K zero-padded 16->32)
__global__ __launch_bounds__(256) void prep_e(const float* __restrict__ E1,
                                              const float* __restrict__ E2,
                                              __bf16* __restrict__ E1p,
                                              __bf16* __restrict__ E2p) {
  int idx = blockIdx.x * 256 + threadIdx.x;  // 0..32767
  int cq = idx & 3;
  int n = (idx >> 2) & 2047;
  int h = idx >> 13;
  const float4 q1 = *(const float4*)(E1 + (size_t)(n * 4 + h) * 16 + cq * 4);
  const float4 q2 = *(const float4*)(E2 + (size_t)(n * 4 + h) * 16 + cq * 4);
  size_t o = ((size_t)h * NNODE + n) * 32 + cq * 4;
  E1p[o + 0] = (__bf16)q1.x; E1p[o + 1] = (__bf16)q1.y;
  E1p[o + 2] = (__bf16)q1.z; E1p[o + 3] = (__bf16)q1.w;
  E2p[o + 0] = (__bf16)q2.x; E2p[o + 1] = (__bf16)q2.y;
  E2p[o + 2] = (__bf16)q2.z; E2p[o + 3] = (__bf16)q2.w;
  size_t oz = o + 16;
  E1p[oz + 0] = (__bf16)0.f; E1p[oz + 1] = (__bf16)0.f;
  E1p[oz + 2] = (__bf16)0.f; E1p[oz + 3] = (__bf16)0.f;
  E2p[oz + 0] = (__bf16)0.f; E2p[oz + 1] = (__bf16)0.f;
  E2p[oz + 2] = (__bf16)0.f; E2p[oz + 3] = (__bf16)0.f;
}

// ---------------------------------------------------------------------------
// SC[h][w][v] = relu(E1p_h @ E2p_h^T)/4, bf16. Single K=32 MFMA step.
__global__ __launch_bounds__(256) void score_gemm(const __bf16* __restrict__ E1p,
                                                  const __bf16* __restrict__ E2p,
                                                  __bf16* __restrict__ SC) {
  __shared__ __bf16 As[128 * 32];
  __shared__ __bf16 Bs[128 * 32];
  const int tid = threadIdx.x;
  const int wave = tid >> 6, lane = tid & 63;
  const int wr = wave >> 1, wc = wave & 1;
  const int h = blockIdx.z;
  const int m0 = blockIdx.x * 128, n0 = blockIdx.y * 128;
  const __bf16* A = E1p + (size_t)h * NNODE * 32;
  const __bf16* Bt = E2p + (size_t)h * NNODE * 32;
  const int rowA = tid >> 2;
  const int colb = (tid & 3) * 16;
  gload16((const char*)(A + (size_t)(m0 + rowA) * 32) + colb, (char*)As + wave * 1024);
  gload16((const char*)(A + (size_t)(m0 + rowA + 64) * 32) + colb, (char*)As + 4096 + wave * 1024);
  gload16((const char*)(Bt + (size_t)(n0 + rowA) * 32) + colb, (char*)Bs + wave * 1024);
  gload16((const char*)(Bt + (size_t)(n0 + rowA + 64) * 32) + colb, (char*)Bs + 4096 + wave * 1024);
  __syncthreads();

  f32x4 acc[4][4] = {};
  bf16x8 af[4], bfr[4];
#pragma unroll
  for (int mi = 0; mi < 4; ++mi)
    af[mi] = *(const bf16x8*)((const char*)As +
             ((wr * 64 + mi * 16 + (lane & 15)) * 64 + (lane >> 4) * 16));
#pragma unroll
  for (int ni = 0; ni < 4; ++ni)
    bfr[ni] = *(const bf16x8*)((const char*)Bs +
             ((wc * 64 + ni * 16 + (lane & 15)) * 64 + (lane >> 4) * 16));
#pragma unroll
  for (int mi = 0; mi < 4; ++mi)
#pragma unroll
    for (int ni = 0; ni < 4; ++ni)
      acc[mi][ni] = __builtin_amdgcn_mfma_f32_16x16x32_bf16(af[mi], bfr[ni],
                                                            acc[mi][ni], 0, 0, 0);

  const int crow = (lane >> 4) * 4;
  const int ccol = lane & 15;
#pragma unroll
  for (int mi = 0; mi < 4; ++mi)
#pragma unroll
    for (int ni = 0; ni < 4; ++ni) {
      int r0 = m0 + wr * 64 + mi * 16 + crow;
      int cc = n0 + wc * 64 + ni * 16 + ccol;
#pragma unroll
      for (int r = 0; r < 4; ++r) {
        float val = fmaxf(acc[mi][ni][r], 0.f) * 0.25f;
        SC[((size_t)h * NNODE + r0 + r) * NNODE + cc] = (__bf16)val;
      }
    }
}

// ---------------------------------------------------------------------------
// Row softmax over v: one wave per row of SC [8192 x 2048] bf16 -> adjh bf16
__global__ __launch_bounds__(256) void softmax_rows(const __bf16* __restrict__ SC,
                                                    __bf16* __restrict__ adjh) {
  const int tid = threadIdx.x;
  const int wave = tid >> 6, lane = tid & 63;
  const size_t row = (size_t)blockIdx.x * 4 + wave;
  const __bf16* src = SC + row * NNODE;
  __bf16* dst = adjh + row * NNODE;
  float v[32];
  float mx = 0.f;
#pragma unroll
  for (int j = 0; j < 4; ++j) {
    bf16x8 q = *(const bf16x8*)(src + j * 512 + lane * 8);
#pragma unroll
    for (int i = 0; i < 8; ++i) {
      float f = (float)q[i];
      v[j * 8 + i] = f;
      mx = fmaxf(mx, f);
    }
  }
#pragma unroll
  for (int o = 32; o > 0; o >>= 1) mx = fmaxf(mx, __shfl_xor(mx, o));
  float s = 0.f;
#pragma unroll
  for (int i = 0; i < 32; ++i) {
    v[i] = __expf(v[i] - mx);
    s += v[i];
  }
#pragma unroll
  for (int o = 32; o > 0; o >>= 1) s += __shfl_xor(s, o);
  float inv = 1.f / s;
#pragma unroll
  for (int j = 0; j < 4; ++j) {
    bf16x8 q;
#pragma unroll
    for (int i = 0; i < 8; ++i) q[i] = (__bf16)(v[j * 8 + i] * inv);
    *(bf16x8*)(dst + j * 512 + lane * 8) = q;
  }
}

// ---------------------------------------------------------------------------
// Fused adjacency prep. Per 64x64 tile (r0,c0), loop z=0..5:
//   z<2 : read A{1,2} f32, write ADJ[z] bf16
//   z>=2: read ADJ[z] (softmax output)
//   write ADJT[z][c][r] = (bf16)(w_z * v[r][c])   (w-scaled transpose)
//   accumulate M1[r][c] += w_z * v[r][c]          (register accum, direct)
__global__ __launch_bounds__(256) void prep_adj(const float* __restrict__ A1,
                                                const float* __restrict__ A2,
                                                __bf16* __restrict__ ADJ,
                                                __bf16* __restrict__ ADJT,
                                                __bf16* __restrict__ M1,
                                                const float* __restrict__ wpre,
                                                const float* __restrict__ wadp) {
  const int r0 = blockIdx.x * 64, c0 = blockIdx.y * 64;
  const int tid = threadIdx.x;
  const size_t NN2 = (size_t)NNODE * NNODE;
  const float wp = *wpre, wa = *wadp * 0.25f;
  __shared__ float t[64][65];
  const int vr = tid >> 2, cg = (tid & 3) * 16;
  float m1acc[16] = {};

  for (int z = 0; z < 6; ++z) {
    const float wz = (z < 2) ? wp : wa;
    float vv[16];
    if (z < 2) {
      const float* src = (z == 0 ? A1 : A2) + (size_t)(r0 + vr) * NNODE + c0 + cg;
#pragma unroll
      for (int j = 0; j < 4; ++j) {
        float4 q = ((const float4*)src)[j];
        vv[j * 4 + 0] = q.x; vv[j * 4 + 1] = q.y;
        vv[j * 4 + 2] = q.z; vv[j * 4 + 3] = q.w;
      }
      __bf16* q = ADJ + (size_t)z * NN2 + (size_t)(r0 + vr) * NNODE + c0 + cg;
      bf16x8 o0, o1;
#pragma unroll
      for (int i = 0; i < 8; ++i) { o0[i] = (__bf16)vv[i]; o1[i] = (__bf16)vv[8 + i]; }
      ((bf16x8*)q)[0] = o0;
      ((bf16x8*)q)[1] = o1;
    } else {
      const __bf16* p = ADJ + (size_t)z * NN2 + (size_t)(r0 + vr) * NNODE + c0 + cg;
      bf16x8 q0 = ((const bf16x8*)p)[0];
      bf16x8 q1 = ((const bf16x8*)p)[1];
#pragma unroll
      for (int i = 0; i < 8; ++i) { vv[i] = (float)q0[i]; vv[8 + i] = (float)q1[i]; }
    }
#pragma unroll
    for (int i = 0; i < 16; ++i) {
      m1acc[i] += wz * vv[i];
      t[vr][cg + i] = vv[i];
    }
    __syncthreads();
#pragma unroll
    for (int jr = 0; jr < 16; ++jr) {
      int c = jr * 4 + (tid >> 6);
      int v = tid & 63;
      ADJT[(size_t)z * NN2 + (size_t)(c0 + c) * NNODE + r0 + v] = (__bf16)(wz * t[v][c]);
    }
    __syncthreads();
  }
  __bf16* q = M1 + (size_t)(r0 + vr) * NNODE + c0 + cg;
  bf16x8 o0, o1;
#pragma unroll
  for (int i = 0; i < 8; ++i) { o0[i] = (__bf16)m1acc[i]; o1[i] = (__bf16)m1acc[8 + i]; }
  ((bf16x8*)q)[0] = o0;
  ((bf16x8*)q)[1] = o1;
}

// ---------------------------------------------------------------------------
// Wzrt[c][k]=Wz[k][c]*(k<64?s:1); Wzrt[64+c][k]=Wr[k][c]*...; Wct rows 64..127 = 0
__global__ __launch_bounds__(256) void prep_w(const float* __restrict__ Wz,
                                              const float* __restrict__ Wr,
                                              const float* __restrict__ Wc,
                                              const float* __restrict__ wpre,
                                              const float* __restrict__ wadp,
                                              __bf16* __restrict__ Wzrt,
                                              __bf16* __restrict__ Wct) {
  int idx = blockIdx.x * 256 + threadIdx.x;  // 0 .. 128*192-1
  int rr = idx / 192, k = idx % 192;
  float s = 2.f * (*wpre) + (*wadp);
  float sc = (k < 64) ? s : 1.f;
  float vz = (rr < 64) ? Wz[(size_t)k * 64 + rr] : Wr[(size_t)k * 64 + rr - 64];
  Wzrt[idx] = (__bf16)(vz * sc);
  float vc = (rr < 64) ? Wc[(size_t)k * 64 + rr] * sc : 0.f;
  Wct[idx] = (__bf16)vc;
}

// ---------------------------------------------------------------------------
// x f32 [B,N,64] -> XT bf16 [B*64, N] (XT[b*64+c][v]=x[b,v,c]) and xbf bf16 [B*N,64]
__global__ __launch_bounds__(256) void transpose_x(const float* __restrict__ x,
                                                   __bf16* __restrict__ XT,
                                                   __bf16* __restrict__ xbf) {
  const int b = blockIdx.y, v0 = blockIdx.x * 64;
  const int tid = threadIdx.x;
  __shared__ float t[64][65];
  const int vr = tid >> 2, c0 = (tid & 3) * 16;
  const float* src = x + ((size_t)b * NNODE + v0 + vr) * 64 + c0;
  __bf16* xb = xbf + ((size_t)b * NNODE + v0 + vr) * 64 + c0;
#pragma unroll
  for (int j = 0; j < 4; ++j) {
    float4 q = ((const float4*)src)[j];
    t[vr][c0 + j * 4 + 0] = q.x;
    t[vr][c0 + j * 4 + 1] = q.y;
    t[vr][c0 + j * 4 + 2] = q.z;
    t[vr][c0 + j * 4 + 3] = q.w;
    xb[j * 4 + 0] = (__bf16)q.x;
    xb[j * 4 + 1] = (__bf16)q.y;
    xb[j * 4 + 2] = (__bf16)q.z;
    xb[j * 4 + 3] = (__bf16)q.w;
  }
  __syncthreads();
#pragma unroll
  for (int jr = 0; jr < 16; ++jr) {
    int c = jr * 4 + (tid >> 6);
    int v = tid & 63;
    XT[((size_t)b * 64 + c) * NNODE + v0 + v] = (__bf16)t[v][c];
  }
}

// rx bf16 [B*N,64] -> XT bf16 [B*64, N]
__global__ __launch_bounds__(256) void transpose_rx(const __bf16* __restrict__ rx,
                                                    __bf16* __restrict__ XT) {
  const int b = blockIdx.y, v0 = blockIdx.x * 64;
  const int tid = threadIdx.x;
  __shared__ float t[64][65];
  const int vr = tid >> 2, c0 = (tid & 3) * 16;
  const __bf16* src = rx + ((size_t)b * NNODE + v0 + vr) * 64 + c0;
  bf16x8 q0 = ((const bf16x8*)src)[0];
  bf16x8 q1 = ((const bf16x8*)src)[1];
#pragma unroll
  for (int i = 0; i < 8; ++i) {
    t[vr][c0 + i] = (float)q0[i];
    t[vr][c0 + 8 + i] = (float)q1[i];
  }
  __syncthreads();
#pragma unroll
  for (int jr = 0; jr < 16; ++jr) {
    int c = jr * 4 + (tid >> 6);
    int v = tid & 63;
    XT[((size_t)b * 64 + c) * NNODE + v0 + v] = (__bf16)t[v][c];
  }
}

// ---------------------------------------------------------------------------
// Shared GEMM machinery (R7-verified): 128x128, BK=64, 4 waves, 2 blocks/CU,
// counted vmcnt(8), 3-bit XOR swizzle (conflicts==0).
#define VMCNT0() asm volatile("s_waitcnt vmcnt(0)" ::: "memory")
#define VMCNT8() asm volatile("s_waitcnt vmcnt(8)" ::: "memory")
#define LGKMCNT0() asm volatile("s_waitcnt lgkmcnt(0)" ::: "memory")
#define BARRIER() asm volatile("s_barrier" ::: "memory")

// C_z[m][n] = sum_k A_z[m][k] * Bt_z[n][k], bf16 out (stage GEMMs)
__global__ __launch_bounds__(256, 2) void gemm_hop1(const __bf16* __restrict__ Abase,
                                                    size_t aStrideZ,
                                                    const __bf16* __restrict__ BtBase,
                                                    __bf16* __restrict__ Cbase) {
  extern __shared__ char smem[];  // 65536 B
  const int tid = threadIdx.x;
  const int w = tid >> 6, l = tid & 63;
  const int wr = w >> 1, wc = w & 1;
  const size_t z = blockIdx.z;
  const int m0 = blockIdx.x * 128, n0 = blockIdx.y * 128;
  const __bf16* A = Abase + z * aStrideZ;
  const __bf16* Bt = BtBase + z * (size_t)(NNODE * NNODE);
  __bf16* C = Cbase + z * (size_t)(NNODE * NNODE);
  const int NT = NNODE / 64;

#define AREG(d) (smem + (d) * 16384)
#define BREG(d) (smem + 32768 + (d) * 16384)

  int aoff[4][2], boff[4][2];
#pragma unroll
  for (int mi = 0; mi < 4; ++mi)
#pragma unroll
    for (int ks = 0; ks < 2; ++ks) {
      int rh = mi * 32 + wr * 16 + (l & 15);
      int lo = rh * 128 + ks * 64 + ((l >> 4) * 16);
      aoff[mi][ks] = lo ^ ((rh & 7) << 4);
    }
#pragma unroll
  for (int j = 0; j < 4; ++j)
#pragma unroll
    for (int ks = 0; ks < 2; ++ks) {
      int rh = j * 32 + wc * 16 + (l & 15);
      int lo = rh * 128 + ks * 64 + ((l >> 4) * 16);
      boff[j][ks] = lo ^ ((rh & 7) << 4);
    }

  const int sg_row = w * 8 + (l >> 3);
  const int sg_col = (((l & 7) ^ ((l >> 3) & 7)) << 4);

#define STAGE(gbase, row0, kt, region)                                        \
  do {                                                                        \
    _Pragma("unroll")                                                         \
    for (int p = 0; p < 4; ++p) {                                             \
      const char* _g = (const char*)(gbase) +                                 \
          (size_t)((row0) + p * 32 + sg_row) * 4096 +                         \
          (size_t)(kt) * 128 + sg_col;                                        \
      gload16(_g, (region) + p * 4096 + w * 1024);                            \
    }                                                                         \
  } while (0)

  f32x4 acc[4][4] = {};
  bf16x8 af[4][2], bfr[4][2];

  STAGE(A, m0, 0, AREG(0));
  STAGE(Bt, n0, 0, BREG(0));
  STAGE(A, m0, 1, AREG(1));
  STAGE(Bt, n0, 1, BREG(1));
  VMCNT8();
  BARRIER();

  for (int t = 0; t < NT; ++t) {
    const int d = t & 1;
#pragma unroll
    for (int mi = 0; mi < 4; ++mi) {
      af[mi][0] = *(const bf16x8*)(AREG(d) + aoff[mi][0]);
      af[mi][1] = *(const bf16x8*)(AREG(d) + aoff[mi][1]);
    }
#pragma unroll
    for (int j = 0; j < 4; ++j) {
      bfr[j][0] = *(const bf16x8*)(BREG(d) + boff[j][0]);
      bfr[j][1] = *(const bf16x8*)(BREG(d) + boff[j][1]);
    }
    LGKMCNT0();
    BARRIER();
    if (t + 2 < NT) {
      STAGE(A, m0, t + 2, AREG(d));
      STAGE(Bt, n0, t + 2, BREG(d));
      VMCNT8();
    } else if (t + 1 < NT) {
      VMCNT0();
    }
    BARRIER();
    __builtin_amdgcn_s_setprio(1);
#pragma unroll
    for (int mi = 0; mi < 4; ++mi)
#pragma unroll
      for (int j = 0; j < 4; ++j)
#pragma unroll
        for (int ks = 0; ks < 2; ++ks)
          acc[mi][j] = __builtin_amdgcn_mfma_f32_16x16x32_bf16(af[mi][ks], bfr[j][ks],
                                                               acc[mi][j], 0, 0, 0);
    __builtin_amdgcn_s_setprio(0);
  }

  const int crow = (l >> 4) * 4;
  const int ccol = l & 15;
#pragma unroll
  for (int mi = 0; mi < 4; ++mi)
#pragma unroll
    for (int j = 0; j < 4; ++j) {
      int r0 = m0 + mi * 32 + wr * 16 + crow;
      int cc = n0 + j * 32 + wc * 16 + ccol;
#pragma unroll
      for (int r = 0; r < 4; ++r)
        C[(size_t)(r0 + r) * NNODE + cc] = (__bf16)acc[mi][j][r];
    }
#undef STAGE
#undef AREG
#undef BREG
}

// ---------------------------------------------------------------------------
// Fused-squares: M2part[zh][m][n] = sum_{z in half} sum_k ADJ_z[m][k]*ADJT_z[n][k]
// (ADJT pre-scaled by w_z, so this accumulates w_z*A_z^2). f32 partials out.
// 96 K-tiles per block (3 z x 32). Same verified loop body as gemm_hop1.
__global__ __launch_bounds__(256, 2) void gemm_sq(const __bf16* __restrict__ ADJ,
                                                  const __bf16* __restrict__ ADJT,
                                                  float* __restrict__ M2part) {
  extern __shared__ char smem[];  // 65536 B
  const int tid = threadIdx.x;
  const int w = tid >> 6, l = tid & 63;
  const int wr = w >> 1, wc = w & 1;
  const int zb = blockIdx.z * 3;
  const int m0 = blockIdx.x * 128, n0 = blockIdx.y * 128;
  const size_t NN2 = (size_t)NNODE * NNODE;
  float* Cp = M2part + (size_t)blockIdx.z * NN2;
  const int NTT = 96;  // 3 z * 32 K-tiles

#define AREG(d) (smem + (d) * 16384)
#define BREG(d) (smem + 32768 + (d) * 16384)

  int aoff[4][2], boff[4][2];
#pragma unroll
  for (int mi = 0; mi < 4; ++mi)
#pragma unroll
    for (int ks = 0; ks < 2; ++ks) {
      int rh = mi * 32 + wr * 16 + (l & 15);
      int lo = rh * 128 + ks * 64 + ((l >> 4) * 16);
      aoff[mi][ks] = lo ^ ((rh & 7) << 4);
    }
#pragma unroll
  for (int j = 0; j < 4; ++j)
#pragma unroll
    for (int ks = 0; ks < 2; ++ks) {
      int rh = j * 32 + wc * 16 + (l & 15);
      int lo = rh * 128 + ks * 64 + ((l >> 4) * 16);
      boff[j][ks] = lo ^ ((rh & 7) << 4);
    }

  const int sg_row = w * 8 + (l >> 3);
  const int sg_col = (((l & 7) ^ ((l >> 3) & 7)) << 4);

  // stage tile index tt -> z-slice zb + tt/32, K-offset (tt%32)*128 bytes
#define STAGE2(gbase, row0, tt, region)                                       \
  do {                                                                        \
    const char* _b = (const char*)(gbase) + (size_t)(zb + ((tt) >> 5)) * NN2 * 2; \
    _Pragma("unroll")                                                         \
    for (int p = 0; p < 4; ++p) {                                             \
      const char* _g = _b +                                                   \
          (size_t)((row0) + p * 32 + sg_row) * 4096 +                         \
          (size_t)((tt) & 31) * 128 + sg_col;                                 \
      gload16(_g, (region) + p * 4096 + w * 1024);                            \
    }                                                                         \
  } while (0)

  f32x4 acc[4][4] = {};
  bf16x8 af[4][2], bfr[4][2];

  STAGE2(ADJ, m0, 0, AREG(0));
  STAGE2(ADJT, n0, 0, BREG(0));
  STAGE2(ADJ, m0, 1, AREG(1));
  STAGE2(ADJT, n0, 1, BREG(1));
  VMCNT8();
  BARRIER();

  for (int t = 0; t < NTT; ++t) {
    const int d = t & 1;
#pragma unroll
    for (int mi = 0; mi < 4; ++mi) {
      af[mi][0] = *(const bf16x8*)(AREG(d) + aoff[mi][0]);
      af[mi][1] = *(const bf16x8*)(AREG(d) + aoff[mi][1]);
    }
#pragma unroll
    for (int j = 0; j < 4; ++j) {
      bfr[j][0] = *(const bf16x8*)(BREG(d) + boff[j][0]);
      bfr[j][1] = *(const bf16x8*)(BREG(d) + boff[j][1]);
    }
    LGKMCNT0();
    BARRIER();
    if (t + 2 < NTT) {
      STAGE2(ADJ, m0, t + 2, AREG(d));
      STAGE2(ADJT, n0, t + 2, BREG(d));
      VMCNT8();
    } else if (t + 1 < NTT) {
      VMCNT0();
    }
    BARRIER();
    __builtin_amdgcn_s_setprio(1);
#pragma unroll
    for (int mi = 0; mi < 4; ++mi)
#pragma unroll
      for (int j = 0; j < 4; ++j)
#pragma unroll
        for (int ks = 0; ks < 2; ++ks)
          acc[mi][j] = __builtin_amdgcn_mfma_f32_16x16x32_bf16(af[mi][ks], bfr[j][ks],
                                                               acc[mi][j], 0, 0, 0);
    __builtin_amdgcn_s_setprio(0);
  }

  const int crow = (l >> 4) * 4;
  const int ccol = l & 15;
#pragma unroll
  for (int mi = 0; mi < 4; ++mi)
#pragma unroll
    for (int j = 0; j < 4; ++j) {
      int r0 = m0 + mi * 32 + wr * 16 + crow;
      int cc = n0 + j * 32 + wc * 16 + ccol;
#pragma unroll
      for (int r = 0; r < 4; ++r)
        Cp[(size_t)(r0 + r) * NNODE + cc] = acc[mi][j][r];
    }
#undef STAGE2
#undef AREG
#undef BREG
}

// ---------------------------------------------------------------------------
// M2[i] = (bf16)(M2a[i] + M2b[i])
__global__ __launch_bounds__(256) void combine_m2(const float* __restrict__ M2p,
                                                  __bf16* __restrict__ M2) {
  const size_t NN2 = (size_t)NNODE * NNODE;
  size_t i = ((size_t)blockIdx.x * 256 + threadIdx.x) * 4;
  float4 a = *(const float4*)(M2p + i);
  float4 b = *(const float4*)(M2p + NN2 + i);
  M2[i + 0] = (__bf16)(a.x + b.x);
  M2[i + 1] = (__bf16)(a.y + b.y);
  M2[i + 2] = (__bf16)(a.z + b.z);
  M2[i + 3] = (__bf16)(a.w + b.w);
}

// ---------------------------------------------------------------------------
// S1[(b,w),c] = HH[0][b*64+c][w] ; S2[(b,w),c] = HH[1][b*64+c][w]
__global__ __launch_bounds__(256) void combine2(const __bf16* __restrict__ HH,
                                                __bf16* __restrict__ S1,
                                                __bf16* __restrict__ S2) {
  const int b = blockIdx.y;
  const int w0 = blockIdx.x * 64;
  const int tid = threadIdx.x;
  const size_t NN2 = (size_t)NNODE * NNODE;
  __shared__ float t1[64][65];
  __shared__ float t2[64][65];
  const int cr = tid >> 2;
  const int wg = (tid & 3) * 16;
  const __bf16* p1 = HH + (size_t)(b * 64 + cr) * NNODE + w0 + wg;
  const __bf16* p2 = HH + NN2 + (size_t)(b * 64 + cr) * NNODE + w0 + wg;
  bf16x8 q10 = ((const bf16x8*)p1)[0], q11 = ((const bf16x8*)p1)[1];
  bf16x8 q20 = ((const bf16x8*)p2)[0], q21 = ((const bf16x8*)p2)[1];
#pragma unroll
  for (int i = 0; i < 8; ++i) {
    t1[cr][wg + i] = (float)q10[i];
    t1[cr][wg + 8 + i] = (float)q11[i];
    t2[cr][wg + i] = (float)q20[i];
    t2[cr][wg + 8 + i] = (float)q21[i];
  }
  __syncthreads();
#pragma unroll
  for (int jr = 0; jr < 16; ++jr) {
    int wl = jr * 4 + (tid >> 6);
    int c = tid & 63;
    size_t o = ((size_t)b * NNODE + w0 + wl) * 64 + c;
    S1[o] = (__bf16)t1[c][wl];
    S2[o] = (__bf16)t2[c][wl];
  }
}

// ---------------------------------------------------------------------------
// Gate linear GEMM: [65536 x 192] @ Wt^T, K=192, N=128, fused epilogues.
template <int MODE>
__global__ __launch_bounds__(256) void gemm_lin(const __bf16* __restrict__ Xp,
                                                const __bf16* __restrict__ S1,
                                                const __bf16* __restrict__ S2,
                                                const __bf16* __restrict__ Wt,
                                                const float* __restrict__ b0,
                                                const float* __restrict__ b1,
                                                const float* __restrict__ wpre,
                                                const float* __restrict__ wadp,
                                                const float* __restrict__ hid,
                                                float* __restrict__ zbuf,
                                                __bf16* __restrict__ rxout,
                                                float* __restrict__ outp) {
  __shared__ __bf16 As[128 * 32];
  __shared__ __bf16 Bs[128 * 32];
  const int tid = threadIdx.x;
  const int wave = tid >> 6, lane = tid & 63;
  const int wr = wave >> 1, wc = wave & 1;
  const int m0 = blockIdx.x * 128;
  const int rowA = tid >> 2;
  const int colb = (tid & 3) * 16;
  const __bf16* srcs[3] = {Xp, S1, S2};
  char* asD0 = (char*)As + wave * 1024;
  char* asD1 = (char*)As + 4096 + wave * 1024;
  char* bsD0 = (char*)Bs + wave * 1024;
  char* bsD1 = (char*)Bs + 4096 + wave * 1024;

  f32x4 acc[4][4] = {};

#pragma unroll
  for (int kt = 0; kt < 6; ++kt) {
    const __bf16* Ab = srcs[kt >> 1];
    const char* aS0 = (const char*)(Ab + (size_t)(m0 + rowA) * 64) + (kt & 1) * 64 + colb;
    const char* aS1 = (const char*)(Ab + (size_t)(m0 + rowA + 64) * 64) + (kt & 1) * 64 + colb;
    const char* bS0 = (const char*)(Wt + (size_t)rowA * 192) + kt * 64 + colb;
    const char* bS1 = (const char*)(Wt + (size_t)(rowA + 64) * 192) + kt * 64 + colb;
    gload16(aS0, asD0);
    gload16(aS1, asD1);
    gload16(bS0, bsD0);
    gload16(bS1, bsD1);
    __syncthreads();
    bf16x8 af[4], bfr[4];
#pragma unroll
    for (int mi = 0; mi < 4; ++mi)
      af[mi] = *(const bf16x8*)((const char*)As +
               ((wr * 64 + mi * 16 + (lane & 15)) * 64 + (lane >> 4) * 16));
#pragma unroll
    for (int ni = 0; ni < 4; ++ni)
      bfr[ni] = *(const bf16x8*)((const char*)Bs +
               ((wc * 64 + ni * 16 + (lane & 15)) * 64 + (lane >> 4) * 16));
#pragma unroll
    for (int mi = 0; mi < 4; ++mi)
#pragma unroll
      for (int ni = 0; ni < 4; ++ni)
        acc[mi][ni] = __builtin_amdgcn_mfma_f32_16x16x32_bf16(af[mi], bfr[ni],
                                                              acc[mi][ni], 0, 0, 0);
    __syncthreads();
  }

  const float wp = *wpre, wa = *wadp;
  const float s = 2.f * wp + wa;
  const int crow = (lane >> 4) * 4;
  const int ccol = lane & 15;
#pragma unroll
  for (int mi = 0; mi < 4; ++mi)
#pragma unroll
    for (int ni = 0; ni < 4; ++ni) {
      int r0 = m0 + wr * 64 + mi * 16 + crow;
      int col = wc * 64 + ni * 16 + ccol;
      int cf = col & 63;
#pragma unroll
      for (int r = 0; r < 4; ++r) {
        int row = r0 + r;
        float g = acc[mi][ni][r];
        if (MODE == 0) {
          if (col < 64) {
            g += s * b0[cf];
            zbuf[(size_t)row * 64 + cf] = 1.f / (1.f + __expf(-g));
          } else {
            g += s * b1[cf];
            float rv = 1.f / (1.f + __expf(-g));
            rxout[(size_t)row * 64 + cf] = (__bf16)(rv * hid[(size_t)row * 64 + cf]);
          }
        } else {
          if (col < 64) {
            g += s * b0[cf];
            float cv = 1.f - 2.f / (1.f + __expf(2.f * g));
            float zv = zbuf[(size_t)row * 64 + cf];
            float hv = hid[(size_t)row * 64 + cf];
            outp[(size_t)row * 64 + cf] = (1.f - zv) * hv + zv * cv;
          }
        }
      }
    }
}

// ---------------------------------------------------------------------------
extern "C" void kernel_launch(void* const* d_in, const int* in_sizes, int n_in,
                              void* d_out, int out_size, void* d_ws, size_t ws_size,
                              hipStream_t stream) {
  (void)in_sizes; (void)n_in; (void)out_size;
  const float* x    = (const float*)d_in[0];
  const float* A1   = (const float*)d_in[1];
  const float* A2   = (const float*)d_in[2];
  const float* E1   = (const float*)d_in[3];
  const float* E2   = (const float*)d_in[4];
  const float* Wz   = (const float*)d_in[5];
  const float* bz   = (const float*)d_in[6];
  const float* Wr   = (const float*)d_in[7];
  const float* br   = (const float*)d_in[8];
  const float* Wc   = (const float*)d_in[9];
  const float* bc   = (const float*)d_in[10];
  const float* wpre = (const float*)d_in[11];
  const float* wadp = (const float*)d_in[12];
  float* out = (float*)d_out;

  char* ws = (char*)d_ws;
  const size_t NN2 = (size_t)NNODE * NNODE;  // 4,194,304 (= B*N*D too)
  const size_t NN2B = NN2 * 2;               // bytes per bf16 slice
  __bf16* ADJ  = (__bf16*)(ws);                 // [0,6) bf16 slices
  __bf16* ADJT = (__bf16*)(ws + 6 * NN2B);      // [6,12) w-scaled transposes
  __bf16* SC   = (__bf16*)(ws + 12 * NN2B);     // scores (4 slices), then:
  float*  M2p  = (float*)(ws + 12 * NN2B);      // f32 partials x2 = [12,16)
  __bf16* MM   = (__bf16*)(ws + 18 * NN2B);     // M1 @18, M2 @19
  __bf16* XT   = (__bf16*)(ws + 20 * NN2B);
  __bf16* xbf  = (__bf16*)(ws + 21 * NN2B);
  __bf16* rx   = (__bf16*)(ws + 22 * NN2B);
  __bf16* HH   = (__bf16*)(ws);                 // over ADJ[0..1] (dead post-sq)
  __bf16* S1   = (__bf16*)(ws + 2 * NN2B);      // over ADJ[2]
  __bf16* S2   = (__bf16*)(ws + 3 * NN2B);      // over ADJ[3]
  float*  zbuf = (float*)(ws + 4 * NN2B);       // over ADJ[4..5]
  __bf16* E1p  = (__bf16*)(ws + 23 * NN2B);
  __bf16* E2p  = E1p + 4 * NNODE * 32;
  __bf16* Wzrt = E2p + 4 * NNODE * 32;
  __bf16* Wct  = Wzrt + 128 * 192;
  if (ws_size < 23 * NN2B + 2 * 4 * NNODE * 32 * 2 + 2 * 128 * 192 * 2) return;

  // --- adjacency construction (fused)
  prep_e<<<128, 256, 0, stream>>>(E1, E2, E1p, E2p);
  score_gemm<<<dim3(16, 16, 4), 256, 0, stream>>>(E1p, E2p, SC);
  softmax_rows<<<2048, 256, 0, stream>>>(SC, ADJ + 2 * NN2);
  prep_adj<<<dim3(32, 32), 256, 0, stream>>>(A1, A2, ADJ, ADJT, MM, wpre, wadp);
  prep_w<<<96, 256, 0, stream>>>(Wz, Wr, Wc, wpre, wadp, Wzrt, Wct);
  transpose_x<<<dim3(32, 32), 256, 0, stream>>>(x, XT, xbf);

  // --- M2 = sum_z w_z A_z^2 (fused accumulate; 512 blocks = 1 full round)
  gemm_sq<<<dim3(16, 16, 2), 256, 65536, stream>>>(ADJ, ADJT, M2p);
  combine_m2<<<4096, 256, 0, stream>>>(M2p, MM + NN2);

  // --- stage 1: S1 = M1 x, S2 = M2 x (512 blocks = 1 full round)
  gemm_hop1<<<dim3(16, 16, 2), 256, 65536, stream>>>(XT, 0, MM, HH);
  combine2<<<dim3(32, 32), 256, 0, stream>>>(HH, S1, S2);
  gemm_lin<0><<<512, 256, 0, stream>>>(xbf, S1, S2, Wzrt, bz, br, wpre, wadp,
                                       x, zbuf, rx, nullptr);

  // --- stage 2: hops on r*x
  transpose_rx<<<dim3(32, 32), 256, 0, stream>>>(rx, XT);
  gemm_hop1<<<dim3(16, 16, 2), 256, 65536, stream>>>(XT, 0, MM, HH);
  combine2<<<dim3(32, 32), 256, 0, stream>>>(HH, S1, S2);
  gemm_lin<1><<<512, 256, 0, stream>>>(rx, S1, S2, Wct, bc, nullptr, wpre, wadp,
                                       x, zbuf, nullptr, out);
}

// Round 9
// 273.345 us; speedup vs baseline: 2.4173x; 1.0616x over previous
//
#include <hip/hip_runtime.h>

#define NNODE 2048
#define NBATCH 32

typedef __attribute__((ext_vector_type(4))) float f32x4;
typedef __attribute__((ext_vector_type(8))) __bf16 bf16x8;
typedef __attribute__((ext_vector_type(4))) __bf16 bf16x4;

__device__ __forceinline__ void gload16(const void* g, void* lds) {
  __builtin_amdgcn_global_load_lds(
      (const __attribute__((address_space(1))) unsigned int*)g,
      (__attribute__((address_space(3))) unsigned int*)lds, 16, 0, 0);
}

// ---------------------------------------------------------------------------
// Repack E1,E2 [N,H,16] f32 -> [H][N][32] bf16 (K zero-padded 16->32)
__global__ __launch_bounds__(256) void prep_e(const float* __restrict__ E1,
                                              const float* __restrict__ E2,
                                              __bf16* __restrict__ E1p,
                                              __bf16* __restrict__ E2p) {
  int idx = blockIdx.x * 256 + threadIdx.x;  // 0..32767
  int cq = idx & 3;
  int n = (idx >> 2) & 2047;
  int h = idx >> 13;
  const float4 q1 = *(const float4*)(E1 + (size_t)(n * 4 + h) * 16 + cq * 4);
  const float4 q2 = *(const float4*)(E2 + (size_t)(n * 4 + h) * 16 + cq * 4);
  size_t o = ((size_t)h * NNODE + n) * 32 + cq * 4;
  E1p[o + 0] = (__bf16)q1.x; E1p[o + 1] = (__bf16)q1.y;
  E1p[o + 2] = (__bf16)q1.z; E1p[o + 3] = (__bf16)q1.w;
  E2p[o + 0] = (__bf16)q2.x; E2p[o + 1] = (__bf16)q2.y;
  E2p[o + 2] = (__bf16)q2.z; E2p[o + 3] = (__bf16)q2.w;
  size_t oz = o + 16;
  E1p[oz + 0] = (__bf16)0.f; E1p[oz + 1] = (__bf16)0.f;
  E1p[oz + 2] = (__bf16)0.f; E1p[oz + 3] = (__bf16)0.f;
  E2p[oz + 0] = (__bf16)0.f; E2p[oz + 1] = (__bf16)0.f;
  E2p[oz + 2] = (__bf16)0.f; E2p[oz + 3] = (__bf16)0.f;
}

// ---------------------------------------------------------------------------
// SC[h][w][v] = relu(E1p_h @ E2p_h^T)/4, bf16. Single K=32 MFMA step.
__global__ __launch_bounds__(256) void score_gemm(const __bf16* __restrict__ E1p,
                                                  const __bf16* __restrict__ E2p,
                                                  __bf16* __restrict__ SC) {
  __shared__ __bf16 As[128 * 32];
  __shared__ __bf16 Bs[128 * 32];
  const int tid = threadIdx.x;
  const int wave = tid >> 6, lane = tid & 63;
  const int wr = wave >> 1, wc = wave & 1;
  const int h = blockIdx.z;
  const int m0 = blockIdx.x * 128, n0 = blockIdx.y * 128;
  const __bf16* A = E1p + (size_t)h * NNODE * 32;
  const __bf16* Bt = E2p + (size_t)h * NNODE * 32;
  const int rowA = tid >> 2;
  const int colb = (tid & 3) * 16;
  gload16((const char*)(A + (size_t)(m0 + rowA) * 32) + colb, (char*)As + wave * 1024);
  gload16((const char*)(A + (size_t)(m0 + rowA + 64) * 32) + colb, (char*)As + 4096 + wave * 1024);
  gload16((const char*)(Bt + (size_t)(n0 + rowA) * 32) + colb, (char*)Bs + wave * 1024);
  gload16((const char*)(Bt + (size_t)(n0 + rowA + 64) * 32) + colb, (char*)Bs + 4096 + wave * 1024);
  __syncthreads();

  f32x4 acc[4][4] = {};
  bf16x8 af[4], bfr[4];
#pragma unroll
  for (int mi = 0; mi < 4; ++mi)
    af[mi] = *(const bf16x8*)((const char*)As +
             ((wr * 64 + mi * 16 + (lane & 15)) * 64 + (lane >> 4) * 16));
#pragma unroll
  for (int ni = 0; ni < 4; ++ni)
    bfr[ni] = *(const bf16x8*)((const char*)Bs +
             ((wc * 64 + ni * 16 + (lane & 15)) * 64 + (lane >> 4) * 16));
#pragma unroll
  for (int mi = 0; mi < 4; ++mi)
#pragma unroll
    for (int ni = 0; ni < 4; ++ni)
      acc[mi][ni] = __builtin_amdgcn_mfma_f32_16x16x32_bf16(af[mi], bfr[ni],
                                                            acc[mi][ni], 0, 0, 0);

  const int crow = (lane >> 4) * 4;
  const int ccol = lane & 15;
#pragma unroll
  for (int mi = 0; mi < 4; ++mi)
#pragma unroll
    for (int ni = 0; ni < 4; ++ni) {
      int r0 = m0 + wr * 64 + mi * 16 + crow;
      int cc = n0 + wc * 64 + ni * 16 + ccol;
#pragma unroll
      for (int r = 0; r < 4; ++r) {
        float val = fmaxf(acc[mi][ni][r], 0.f) * 0.25f;
        SC[((size_t)h * NNODE + r0 + r) * NNODE + cc] = (__bf16)val;
      }
    }
}

// ---------------------------------------------------------------------------
// Row softmax over v: one wave per row of SC [8192 x 2048] bf16 -> adjh bf16
__global__ __launch_bounds__(256) void softmax_rows(const __bf16* __restrict__ SC,
                                                    __bf16* __restrict__ adjh) {
  const int tid = threadIdx.x;
  const int wave = tid >> 6, lane = tid & 63;
  const size_t row = (size_t)blockIdx.x * 4 + wave;
  const __bf16* src = SC + row * NNODE;
  __bf16* dst = adjh + row * NNODE;
  float v[32];
  float mx = 0.f;
#pragma unroll
  for (int j = 0; j < 4; ++j) {
    bf16x8 q = *(const bf16x8*)(src + j * 512 + lane * 8);
#pragma unroll
    for (int i = 0; i < 8; ++i) {
      float f = (float)q[i];
      v[j * 8 + i] = f;
      mx = fmaxf(mx, f);
    }
  }
#pragma unroll
  for (int o = 32; o > 0; o >>= 1) mx = fmaxf(mx, __shfl_xor(mx, o));
  float s = 0.f;
#pragma unroll
  for (int i = 0; i < 32; ++i) {
    v[i] = __expf(v[i] - mx);
    s += v[i];
  }
#pragma unroll
  for (int o = 32; o > 0; o >>= 1) s += __shfl_xor(s, o);
  float inv = 1.f / s;
#pragma unroll
  for (int j = 0; j < 4; ++j) {
    bf16x8 q;
#pragma unroll
    for (int i = 0; i < 8; ++i) q[i] = (__bf16)(v[j * 8 + i] * inv);
    *(bf16x8*)(dst + j * 512 + lane * 8) = q;
  }
}

// ---------------------------------------------------------------------------
// Fused adjacency prep: ADJ bf16, w-scaled ADJT, M1 accum. (R8-verified)
__global__ __launch_bounds__(256) void prep_adj(const float* __restrict__ A1,
                                                const float* __restrict__ A2,
                                                __bf16* __restrict__ ADJ,
                                                __bf16* __restrict__ ADJT,
                                                __bf16* __restrict__ M1,
                                                const float* __restrict__ wpre,
                                                const float* __restrict__ wadp) {
  const int r0 = blockIdx.x * 64, c0 = blockIdx.y * 64;
  const int tid = threadIdx.x;
  const size_t NN2 = (size_t)NNODE * NNODE;
  const float wp = *wpre, wa = *wadp * 0.25f;
  __shared__ float t[64][65];
  const int vr = tid >> 2, cg = (tid & 3) * 16;
  float m1acc[16] = {};

  for (int z = 0; z < 6; ++z) {
    const float wz = (z < 2) ? wp : wa;
    float vv[16];
    if (z < 2) {
      const float* src = (z == 0 ? A1 : A2) + (size_t)(r0 + vr) * NNODE + c0 + cg;
#pragma unroll
      for (int j = 0; j < 4; ++j) {
        float4 q = ((const float4*)src)[j];
        vv[j * 4 + 0] = q.x; vv[j * 4 + 1] = q.y;
        vv[j * 4 + 2] = q.z; vv[j * 4 + 3] = q.w;
      }
      __bf16* q = ADJ + (size_t)z * NN2 + (size_t)(r0 + vr) * NNODE + c0 + cg;
      bf16x8 o0, o1;
#pragma unroll
      for (int i = 0; i < 8; ++i) { o0[i] = (__bf16)vv[i]; o1[i] = (__bf16)vv[8 + i]; }
      ((bf16x8*)q)[0] = o0;
      ((bf16x8*)q)[1] = o1;
    } else {
      const __bf16* p = ADJ + (size_t)z * NN2 + (size_t)(r0 + vr) * NNODE + c0 + cg;
      bf16x8 q0 = ((const bf16x8*)p)[0];
      bf16x8 q1 = ((const bf16x8*)p)[1];
#pragma unroll
      for (int i = 0; i < 8; ++i) { vv[i] = (float)q0[i]; vv[8 + i] = (float)q1[i]; }
    }
#pragma unroll
    for (int i = 0; i < 16; ++i) {
      m1acc[i] += wz * vv[i];
      t[vr][cg + i] = vv[i];
    }
    __syncthreads();
#pragma unroll
    for (int jr = 0; jr < 16; ++jr) {
      int c = jr * 4 + (tid >> 6);
      int v = tid & 63;
      ADJT[(size_t)z * NN2 + (size_t)(c0 + c) * NNODE + r0 + v] = (__bf16)(wz * t[v][c]);
    }
    __syncthreads();
  }
  __bf16* q = M1 + (size_t)(r0 + vr) * NNODE + c0 + cg;
  bf16x8 o0, o1;
#pragma unroll
  for (int i = 0; i < 8; ++i) { o0[i] = (__bf16)m1acc[i]; o1[i] = (__bf16)m1acc[8 + i]; }
  ((bf16x8*)q)[0] = o0;
  ((bf16x8*)q)[1] = o1;
}

// ---------------------------------------------------------------------------
// Wzrt[c][k]=Wz[k][c]*(k<64?s:1); Wzrt[64+c][k]=Wr[k][c]*...; Wct rows 64..127 = 0
__global__ __launch_bounds__(256) void prep_w(const float* __restrict__ Wz,
                                              const float* __restrict__ Wr,
                                              const float* __restrict__ Wc,
                                              const float* __restrict__ wpre,
                                              const float* __restrict__ wadp,
                                              __bf16* __restrict__ Wzrt,
                                              __bf16* __restrict__ Wct) {
  int idx = blockIdx.x * 256 + threadIdx.x;  // 0 .. 128*192-1
  int rr = idx / 192, k = idx % 192;
  float s = 2.f * (*wpre) + (*wadp);
  float sc = (k < 64) ? s : 1.f;
  float vz = (rr < 64) ? Wz[(size_t)k * 64 + rr] : Wr[(size_t)k * 64 + rr - 64];
  Wzrt[idx] = (__bf16)(vz * sc);
  float vc = (rr < 64) ? Wc[(size_t)k * 64 + rr] * sc : 0.f;
  Wct[idx] = (__bf16)vc;
}

// ---------------------------------------------------------------------------
// x f32 [B,N,64] -> XT bf16 [B*64, N] and xbf bf16 [B*N,64]
__global__ __launch_bounds__(256) void transpose_x(const float* __restrict__ x,
                                                   __bf16* __restrict__ XT,
                                                   __bf16* __restrict__ xbf) {
  const int b = blockIdx.y, v0 = blockIdx.x * 64;
  const int tid = threadIdx.x;
  __shared__ float t[64][65];
  const int vr = tid >> 2, c0 = (tid & 3) * 16;
  const float* src = x + ((size_t)b * NNODE + v0 + vr) * 64 + c0;
  __bf16* xb = xbf + ((size_t)b * NNODE + v0 + vr) * 64 + c0;
#pragma unroll
  for (int j = 0; j < 4; ++j) {
    float4 q = ((const float4*)src)[j];
    t[vr][c0 + j * 4 + 0] = q.x;
    t[vr][c0 + j * 4 + 1] = q.y;
    t[vr][c0 + j * 4 + 2] = q.z;
    t[vr][c0 + j * 4 + 3] = q.w;
    xb[j * 4 + 0] = (__bf16)q.x;
    xb[j * 4 + 1] = (__bf16)q.y;
    xb[j * 4 + 2] = (__bf16)q.z;
    xb[j * 4 + 3] = (__bf16)q.w;
  }
  __syncthreads();
#pragma unroll
  for (int jr = 0; jr < 16; ++jr) {
    int c = jr * 4 + (tid >> 6);
    int v = tid & 63;
    XT[((size_t)b * 64 + c) * NNODE + v0 + v] = (__bf16)t[v][c];
  }
}

// rx bf16 [B*N,64] -> XT bf16 [B*64, N]
__global__ __launch_bounds__(256) void transpose_rx(const __bf16* __restrict__ rx,
                                                    __bf16* __restrict__ XT) {
  const int b = blockIdx.y, v0 = blockIdx.x * 64;
  const int tid = threadIdx.x;
  __shared__ float t[64][65];
  const int vr = tid >> 2, c0 = (tid & 3) * 16;
  const __bf16* src = rx + ((size_t)b * NNODE + v0 + vr) * 64 + c0;
  bf16x8 q0 = ((const bf16x8*)src)[0];
  bf16x8 q1 = ((const bf16x8*)src)[1];
#pragma unroll
  for (int i = 0; i < 8; ++i) {
    t[vr][c0 + i] = (float)q0[i];
    t[vr][c0 + 8 + i] = (float)q1[i];
  }
  __syncthreads();
#pragma unroll
  for (int jr = 0; jr < 16; ++jr) {
    int c = jr * 4 + (tid >> 6);
    int v = tid & 63;
    XT[((size_t)b * 64 + c) * NNODE + v0 + v] = (__bf16)t[v][c];
  }
}

// ---------------------------------------------------------------------------
// Shared GEMM machinery (R7-verified): 128x128, BK=64, 4 waves, 2 blocks/CU,
// counted vmcnt(8), 3-bit XOR swizzle (conflicts==0). + XCD-chunked block
// swizzle (bijective; 512 blocks = 8 XCD x 64).
#define VMCNT0() asm volatile("s_waitcnt vmcnt(0)" ::: "memory")
#define VMCNT8() asm volatile("s_waitcnt vmcnt(8)" ::: "memory")
#define LGKMCNT0() asm volatile("s_waitcnt lgkmcnt(0)" ::: "memory")
#define BARRIER() asm volatile("s_barrier" ::: "memory")

// Fused-squares: M2part[zh] = sum_{z in half} ADJ_z @ ADJT_z^T (ADJT w-scaled),
// f32 partials. 96 K-tiles/block.
__global__ __launch_bounds__(256, 2) void gemm_sq(const __bf16* __restrict__ ADJ,
                                                  const __bf16* __restrict__ ADJT,
                                                  float* __restrict__ M2part) {
  extern __shared__ char smem[];  // 65536 B
  const int tid = threadIdx.x;
  const int w = tid >> 6, l = tid & 63;
  const int wr = w >> 1, wc = w & 1;
  const size_t NN2 = (size_t)NNODE * NNODE;
  // XCD-chunked swizzle: each XCD gets 64 contiguous tiles (16 bx x 4 by, 1 z)
  int lin = blockIdx.x + 16 * blockIdx.y + 256 * blockIdx.z;
  int nlin = (lin & 7) * 64 + (lin >> 3);
  const int m0 = (nlin & 15) * 128, n0 = ((nlin >> 4) & 15) * 128;
  const int zh = nlin >> 8;
  const int zb = zh * 3;
  float* Cp = M2part + (size_t)zh * NN2;
  const int NTT = 96;  // 3 z * 32 K-tiles

#define AREG(d) (smem + (d) * 16384)
#define BREG(d) (smem + 32768 + (d) * 16384)

  int aoff[4][2], boff[4][2];
#pragma unroll
  for (int mi = 0; mi < 4; ++mi)
#pragma unroll
    for (int ks = 0; ks < 2; ++ks) {
      int rh = mi * 32 + wr * 16 + (l & 15);
      int lo = rh * 128 + ks * 64 + ((l >> 4) * 16);
      aoff[mi][ks] = lo ^ ((rh & 7) << 4);
    }
#pragma unroll
  for (int j = 0; j < 4; ++j)
#pragma unroll
    for (int ks = 0; ks < 2; ++ks) {
      int rh = j * 32 + wc * 16 + (l & 15);
      int lo = rh * 128 + ks * 64 + ((l >> 4) * 16);
      boff[j][ks] = lo ^ ((rh & 7) << 4);
    }

  const int sg_row = w * 8 + (l >> 3);
  const int sg_col = (((l & 7) ^ ((l >> 3) & 7)) << 4);

#define STAGE2(gbase, row0, tt, region)                                       \
  do {                                                                        \
    const char* _b = (const char*)(gbase) + (size_t)(zb + ((tt) >> 5)) * NN2 * 2; \
    _Pragma("unroll")                                                         \
    for (int p = 0; p < 4; ++p) {                                             \
      const char* _g = _b +                                                   \
          (size_t)((row0) + p * 32 + sg_row) * 4096 +                         \
          (size_t)((tt) & 31) * 128 + sg_col;                                 \
      gload16(_g, (region) + p * 4096 + w * 1024);                            \
    }                                                                         \
  } while (0)

  f32x4 acc[4][4] = {};
  bf16x8 af[4][2], bfr[4][2];

  STAGE2(ADJ, m0, 0, AREG(0));
  STAGE2(ADJT, n0, 0, BREG(0));
  STAGE2(ADJ, m0, 1, AREG(1));
  STAGE2(ADJT, n0, 1, BREG(1));
  VMCNT8();
  BARRIER();

  for (int t = 0; t < NTT; ++t) {
    const int d = t & 1;
#pragma unroll
    for (int mi = 0; mi < 4; ++mi) {
      af[mi][0] = *(const bf16x8*)(AREG(d) + aoff[mi][0]);
      af[mi][1] = *(const bf16x8*)(AREG(d) + aoff[mi][1]);
    }
#pragma unroll
    for (int j = 0; j < 4; ++j) {
      bfr[j][0] = *(const bf16x8*)(BREG(d) + boff[j][0]);
      bfr[j][1] = *(const bf16x8*)(BREG(d) + boff[j][1]);
    }
    LGKMCNT0();
    BARRIER();
    if (t + 2 < NTT) {
      STAGE2(ADJ, m0, t + 2, AREG(d));
      STAGE2(ADJT, n0, t + 2, BREG(d));
      VMCNT8();
    } else if (t + 1 < NTT) {
      VMCNT0();
    }
    BARRIER();
    __builtin_amdgcn_s_setprio(1);
#pragma unroll
    for (int mi = 0; mi < 4; ++mi)
#pragma unroll
      for (int j = 0; j < 4; ++j)
#pragma unroll
        for (int ks = 0; ks < 2; ++ks)
          acc[mi][j] = __builtin_amdgcn_mfma_f32_16x16x32_bf16(af[mi][ks], bfr[j][ks],
                                                               acc[mi][j], 0, 0, 0);
    __builtin_amdgcn_s_setprio(0);
  }

  const int crow = (l >> 4) * 4;
  const int ccol = l & 15;
#pragma unroll
  for (int mi = 0; mi < 4; ++mi)
#pragma unroll
    for (int j = 0; j < 4; ++j) {
      int r0 = m0 + mi * 32 + wr * 16 + crow;
      int cc = n0 + j * 32 + wc * 16 + ccol;
#pragma unroll
      for (int r = 0; r < 4; ++r)
        Cp[(size_t)(r0 + r) * NNODE + cc] = acc[mi][j][r];
    }
#undef STAGE2
#undef AREG
#undef BREG
}

// ---------------------------------------------------------------------------
// Stage GEMM with fused transposed epilogue:
//   C[m][n] = sum_k XT[m][k] * MM_z[n][k], m=(b,c) -> writes S_z[(b,n),c]
//   directly via LDS transpose (no HH buffer, no combine2 pass).
__global__ __launch_bounds__(256, 2) void gemm_hop1s(const __bf16* __restrict__ XT,
                                                     const __bf16* __restrict__ MMb,
                                                     __bf16* __restrict__ S1,
                                                     __bf16* __restrict__ S2) {
  extern __shared__ char smem[];  // 65536 B
  const int tid = threadIdx.x;
  const int w = tid >> 6, l = tid & 63;
  const int wr = w >> 1, wc = w & 1;
  const size_t NN2 = (size_t)NNODE * NNODE;
  int lin = blockIdx.x + 16 * blockIdx.y + 256 * blockIdx.z;
  int nlin = (lin & 7) * 64 + (lin >> 3);
  const int m0 = (nlin & 15) * 128, n0 = ((nlin >> 4) & 15) * 128;
  const int z = nlin >> 8;
  const __bf16* A = XT;
  const __bf16* Bt = MMb + (size_t)z * NN2;
  const int NT = NNODE / 64;

#define AREG(d) (smem + (d) * 16384)
#define BREG(d) (smem + 32768 + (d) * 16384)

  int aoff[4][2], boff[4][2];
#pragma unroll
  for (int mi = 0; mi < 4; ++mi)
#pragma unroll
    for (int ks = 0; ks < 2; ++ks) {
      int rh = mi * 32 + wr * 16 + (l & 15);
      int lo = rh * 128 + ks * 64 + ((l >> 4) * 16);
      aoff[mi][ks] = lo ^ ((rh & 7) << 4);
    }
#pragma unroll
  for (int j = 0; j < 4; ++j)
#pragma unroll
    for (int ks = 0; ks < 2; ++ks) {
      int rh = j * 32 + wc * 16 + (l & 15);
      int lo = rh * 128 + ks * 64 + ((l >> 4) * 16);
      boff[j][ks] = lo ^ ((rh & 7) << 4);
    }

  const int sg_row = w * 8 + (l >> 3);
  const int sg_col = (((l & 7) ^ ((l >> 3) & 7)) << 4);

#define STAGE(gbase, row0, kt, region)                                        \
  do {                                                                        \
    _Pragma("unroll")                                                         \
    for (int p = 0; p < 4; ++p) {                                             \
      const char* _g = (const char*)(gbase) +                                 \
          (size_t)((row0) + p * 32 + sg_row) * 4096 +                         \
          (size_t)(kt) * 128 + sg_col;                                        \
      gload16(_g, (region) + p * 4096 + w * 1024);                            \
    }                                                                         \
  } while (0)

  f32x4 acc[4][4] = {};
  bf16x8 af[4][2], bfr[4][2];

  STAGE(A, m0, 0, AREG(0));
  STAGE(Bt, n0, 0, BREG(0));
  STAGE(A, m0, 1, AREG(1));
  STAGE(Bt, n0, 1, BREG(1));
  VMCNT8();
  BARRIER();

  for (int t = 0; t < NT; ++t) {
    const int d = t & 1;
#pragma unroll
    for (int mi = 0; mi < 4; ++mi) {
      af[mi][0] = *(const bf16x8*)(AREG(d) + aoff[mi][0]);
      af[mi][1] = *(const bf16x8*)(AREG(d) + aoff[mi][1]);
    }
#pragma unroll
    for (int j = 0; j < 4; ++j) {
      bfr[j][0] = *(const bf16x8*)(BREG(d) + boff[j][0]);
      bfr[j][1] = *(const bf16x8*)(BREG(d) + boff[j][1]);
    }
    LGKMCNT0();
    BARRIER();
    if (t + 2 < NT) {
      STAGE(A, m0, t + 2, AREG(d));
      STAGE(Bt, n0, t + 2, BREG(d));
      VMCNT8();
    } else if (t + 1 < NT) {
      VMCNT0();
    }
    BARRIER();
    __builtin_amdgcn_s_setprio(1);
#pragma unroll
    for (int mi = 0; mi < 4; ++mi)
#pragma unroll
      for (int j = 0; j < 4; ++j)
#pragma unroll
        for (int ks = 0; ks < 2; ++ks)
          acc[mi][j] = __builtin_amdgcn_mfma_f32_16x16x32_bf16(af[mi][ks], bfr[j][ks],
                                                               acc[mi][j], 0, 0, 0);
    __builtin_amdgcn_s_setprio(0);
  }

  // ---- epilogue: LDS transpose T[n][m] (256 B rows, slot-XOR swizzle),
  // then coalesced write S_z[(b, n0+n)*64 + c]. All LDS reads of the K-loop
  // completed before the last barrier, so T can overwrite staging regions.
  {
    const int crow = (l >> 4) * 4;
    const int ccol = l & 15;
    char* T = smem;  // 128 x 256 B = 32 KiB
#pragma unroll
    for (int mi = 0; mi < 4; ++mi)
#pragma unroll
      for (int j = 0; j < 4; ++j) {
        int ml = mi * 32 + wr * 16 + crow;   // m_local (4 consecutive rows)
        int nl = j * 32 + wc * 16 + ccol;    // n_local
        bf16x4 v;
#pragma unroll
        for (int r = 0; r < 4; ++r) v[r] = (__bf16)acc[mi][j][r];
        *(bf16x4*)(T + nl * 256 + ((ml * 2) ^ ((nl & 7) << 4))) = v;
      }
    __syncthreads();
    __bf16* dst = z ? S2 : S1;
    const int bA = m0 >> 6;  // first batch of this m-tile (128 rows = 2 batches)
#pragma unroll
    for (int it = 0; it < 4; ++it) {
      int nl = (tid >> 3) + it * 32;
      int seg = tid & 7;               // m_local block of 16: [seg*16, seg*16+16)
      int xorv = (nl & 7) << 4;
      const char* src = T + nl * 256;
      bf16x8 v0 = *(const bf16x8*)(src + ((seg * 32) ^ xorv));
      bf16x8 v1 = *(const bf16x8*)(src + ((seg * 32 + 16) ^ xorv));
      int b = bA + (seg >> 2);
      size_t o = ((size_t)b * NNODE + n0 + nl) * 64 + (seg & 3) * 16;
      *(bf16x8*)(dst + o) = v0;
      *(bf16x8*)(dst + o + 8) = v1;
    }
  }
#undef STAGE
#undef AREG
#undef BREG
}

// ---------------------------------------------------------------------------
// M2[i] = (bf16)(M2a[i] + M2b[i])
__global__ __launch_bounds__(256) void combine_m2(const float* __restrict__ M2p,
                                                  __bf16* __restrict__ M2) {
  const size_t NN2 = (size_t)NNODE * NNODE;
  size_t i = ((size_t)blockIdx.x * 256 + threadIdx.x) * 4;
  float4 a = *(const float4*)(M2p + i);
  float4 b = *(const float4*)(M2p + NN2 + i);
  M2[i + 0] = (__bf16)(a.x + b.x);
  M2[i + 1] = (__bf16)(a.y + b.y);
  M2[i + 2] = (__bf16)(a.z + b.z);
  M2[i + 3] = (__bf16)(a.w + b.w);
}

// ---------------------------------------------------------------------------
// Gate linear GEMM: [65536 x 192] @ Wt^T, K=192, N=128, fused epilogues.
template <int MODE>
__global__ __launch_bounds__(256) void gemm_lin(const __bf16* __restrict__ Xp,
                                                const __bf16* __restrict__ S1,
                                                const __bf16* __restrict__ S2,
                                                const __bf16* __restrict__ Wt,
                                                const float* __restrict__ b0,
                                                const float* __restrict__ b1,
                                                const float* __restrict__ wpre,
                                                const float* __restrict__ wadp,
                                                const float* __restrict__ hid,
                                                float* __restrict__ zbuf,
                                                __bf16* __restrict__ rxout,
                                                float* __restrict__ outp) {
  __shared__ __bf16 As[128 * 32];
  __shared__ __bf16 Bs[128 * 32];
  const int tid = threadIdx.x;
  const int wave = tid >> 6, lane = tid & 63;
  const int wr = wave >> 1, wc = wave & 1;
  const int m0 = blockIdx.x * 128;
  const int rowA = tid >> 2;
  const int colb = (tid & 3) * 16;
  const __bf16* srcs[3] = {Xp, S1, S2};
  char* asD0 = (char*)As + wave * 1024;
  char* asD1 = (char*)As + 4096 + wave * 1024;
  char* bsD0 = (char*)Bs + wave * 1024;
  char* bsD1 = (char*)Bs + 4096 + wave * 1024;

  f32x4 acc[4][4] = {};

#pragma unroll
  for (int kt = 0; kt < 6; ++kt) {
    const __bf16* Ab = srcs[kt >> 1];
    const char* aS0 = (const char*)(Ab + (size_t)(m0 + rowA) * 64) + (kt & 1) * 64 + colb;
    const char* aS1 = (const char*)(Ab + (size_t)(m0 + rowA + 64) * 64) + (kt & 1) * 64 + colb;
    const char* bS0 = (const char*)(Wt + (size_t)rowA * 192) + kt * 64 + colb;
    const char* bS1 = (const char*)(Wt + (size_t)(rowA + 64) * 192) + kt * 64 + colb;
    gload16(aS0, asD0);
    gload16(aS1, asD1);
    gload16(bS0, bsD0);
    gload16(bS1, bsD1);
    __syncthreads();
    bf16x8 af[4], bfr[4];
#pragma unroll
    for (int mi = 0; mi < 4; ++mi)
      af[mi] = *(const bf16x8*)((const char*)As +
               ((wr * 64 + mi * 16 + (lane & 15)) * 64 + (lane >> 4) * 16));
#pragma unroll
    for (int ni = 0; ni < 4; ++ni)
      bfr[ni] = *(const bf16x8*)((const char*)Bs +
               ((wc * 64 + ni * 16 + (lane & 15)) * 64 + (lane >> 4) * 16));
#pragma unroll
    for (int mi = 0; mi < 4; ++mi)
#pragma unroll
      for (int ni = 0; ni < 4; ++ni)
        acc[mi][ni] = __builtin_amdgcn_mfma_f32_16x16x32_bf16(af[mi], bfr[ni],
                                                              acc[mi][ni], 0, 0, 0);
    __syncthreads();
  }

  const float wp = *wpre, wa = *wadp;
  const float s = 2.f * wp + wa;
  const int crow = (lane >> 4) * 4;
  const int ccol = lane & 15;
#pragma unroll
  for (int mi = 0; mi < 4; ++mi)
#pragma unroll
    for (int ni = 0; ni < 4; ++ni) {
      int r0 = m0 + wr * 64 + mi * 16 + crow;
      int col = wc * 64 + ni * 16 + ccol;
      int cf = col & 63;
#pragma unroll
      for (int r = 0; r < 4; ++r) {
        int row = r0 + r;
        float g = acc[mi][ni][r];
        if (MODE == 0) {
          if (col < 64) {
            g += s * b0[cf];
            zbuf[(size_t)row * 64 + cf] = 1.f / (1.f + __expf(-g));
          } else {
            g += s * b1[cf];
            float rv = 1.f / (1.f + __expf(-g));
            rxout[(size_t)row * 64 + cf] = (__bf16)(rv * hid[(size_t)row * 64 + cf]);
          }
        } else {
          if (col < 64) {
            g += s * b0[cf];
            float cv = 1.f - 2.f / (1.f + __expf(2.f * g));
            float zv = zbuf[(size_t)row * 64 + cf];
            float hv = hid[(size_t)row * 64 + cf];
            outp[(size_t)row * 64 + cf] = (1.f - zv) * hv + zv * cv;
          }
        }
      }
    }
}

// ---------------------------------------------------------------------------
extern "C" void kernel_launch(void* const* d_in, const int* in_sizes, int n_in,
                              void* d_out, int out_size, void* d_ws, size_t ws_size,
                              hipStream_t stream) {
  (void)in_sizes; (void)n_in; (void)out_size;
  const float* x    = (const float*)d_in[0];
  const float* A1   = (const float*)d_in[1];
  const float* A2   = (const float*)d_in[2];
  const float* E1   = (const float*)d_in[3];
  const float* E2   = (const float*)d_in[4];
  const float* Wz   = (const float*)d_in[5];
  const float* bz   = (const float*)d_in[6];
  const float* Wr   = (const float*)d_in[7];
  const float* br   = (const float*)d_in[8];
  const float* Wc   = (const float*)d_in[9];
  const float* bc   = (const float*)d_in[10];
  const float* wpre = (const float*)d_in[11];
  const float* wadp = (const float*)d_in[12];
  float* out = (float*)d_out;

  char* ws = (char*)d_ws;
  const size_t NN2 = (size_t)NNODE * NNODE;  // 4,194,304 (= B*N*D too)
  const size_t NN2B = NN2 * 2;               // bytes per bf16 slice
  __bf16* ADJ  = (__bf16*)(ws);                 // [0,6) bf16 slices
  __bf16* ADJT = (__bf16*)(ws + 6 * NN2B);      // [6,12) w-scaled transposes
  __bf16* SC   = (__bf16*)(ws + 12 * NN2B);     // scores (4 slices), then:
  float*  M2p  = (float*)(ws + 12 * NN2B);      // f32 partials x2 = [12,16)
  __bf16* MM   = (__bf16*)(ws + 18 * NN2B);     // M1 @18, M2 @19
  __bf16* XT   = (__bf16*)(ws + 20 * NN2B);
  __bf16* xbf  = (__bf16*)(ws + 21 * NN2B);
  __bf16* rx   = (__bf16*)(ws + 22 * NN2B);
  __bf16* S1   = (__bf16*)(ws + 2 * NN2B);      // over ADJ[2] (dead post-sq)
  __bf16* S2   = (__bf16*)(ws + 3 * NN2B);      // over ADJ[3]
  float*  zbuf = (float*)(ws + 4 * NN2B);       // over ADJ[4..5]
  __bf16* E1p  = (__bf16*)(ws + 23 * NN2B);
  __bf16* E2p  = E1p + 4 * NNODE * 32;
  __bf16* Wzrt = E2p + 4 * NNODE * 32;
  __bf16* Wct  = Wzrt + 128 * 192;
  if (ws_size < 23 * NN2B + 2 * 4 * NNODE * 32 * 2 + 2 * 128 * 192 * 2) return;

  // --- adjacency construction (fused)
  prep_e<<<128, 256, 0, stream>>>(E1, E2, E1p, E2p);
  score_gemm<<<dim3(16, 16, 4), 256, 0, stream>>>(E1p, E2p, SC);
  softmax_rows<<<2048, 256, 0, stream>>>(SC, ADJ + 2 * NN2);
  prep_adj<<<dim3(32, 32), 256, 0, stream>>>(A1, A2, ADJ, ADJT, MM, wpre, wadp);
  prep_w<<<96, 256, 0, stream>>>(Wz, Wr, Wc, wpre, wadp, Wzrt, Wct);
  transpose_x<<<dim3(32, 32), 256, 0, stream>>>(x, XT, xbf);

  // --- M2 = sum_z w_z A_z^2 (fused accumulate; 512 blocks, XCD-chunked)
  gemm_sq<<<dim3(16, 16, 2), 256, 65536, stream>>>(ADJ, ADJT, M2p);
  combine_m2<<<4096, 256, 0, stream>>>(M2p, MM + NN2);

  // --- stage 1: S1 = M1 x, S2 = M2 x (fused transposed epilogue)
  gemm_hop1s<<<dim3(16, 16, 2), 256, 65536, stream>>>(XT, MM, S1, S2);
  gemm_lin<0><<<512, 256, 0, stream>>>(xbf, S1, S2, Wzrt, bz, br, wpre, wadp,
                                       x, zbuf, rx, nullptr);

  // --- stage 2: hops on r*x
  transpose_rx<<<dim3(32, 32), 256, 0, stream>>>(rx, XT);
  gemm_hop1s<<<dim3(16, 16, 2), 256, 65536, stream>>>(XT, MM, S1, S2);
  gemm_lin<1><<<512, 256, 0, stream>>>(rx, S1, S2, Wct, bc, nullptr, wpre, wadp,
                                       x, zbuf, nullptr, out);
}